// Round 5
// baseline (1272.054 us; speedup 1.0000x reference)
//
#include <hip/hip_runtime.h>

typedef unsigned short u16;
typedef __bf16 bf16x8 __attribute__((ext_vector_type(8)));
typedef float floatx4 __attribute__((ext_vector_type(4)));

__device__ inline u16 f2bf(float f) {
    unsigned int u = __float_as_uint(f);
    unsigned int r = (u + 0x7FFFu + ((u >> 16) & 1u)) >> 16;
    return (u16)r;
}
__device__ inline float bf2f(u16 h) {
    return __uint_as_float(((unsigned int)h) << 16);
}

// ---------------------------------------------------------------------------
// Layer 0: direct conv 3->64, 32x32.
// ---------------------------------------------------------------------------
__global__ __launch_bounds__(256) void conv0_kernel(
    const float* __restrict__ x, const float* __restrict__ w,
    const float* __restrict__ bias, u16* __restrict__ out)
{
    __shared__ __align__(16) float xs[3][6][36];
    const int t  = threadIdx.x;
    const int b  = blockIdx.x >> 3;
    const int y0 = (blockIdx.x & 7) * 4;

    for (int i = t; i < 3 * 6 * 36; i += 256) {
        int ci  = i / 216;
        int rem = i % 216;
        int r   = rem / 36;
        int c   = rem % 36;
        int gy  = y0 - 1 + r;
        int gx  = c - 1;
        float v = 0.f;
        if ((unsigned)gy < 32u && (unsigned)gx < 32u)
            v = x[((b * 3 + ci) * 32 + gy) * 32 + gx];
        xs[ci][r][c] = v;
    }
    const int lane = t & 63;
    const int wv   = t >> 6;
    float wr[27];
    #pragma unroll
    for (int k = 0; k < 27; k++) wr[k] = w[lane * 27 + k];
    const float bz = bias[lane];
    __syncthreads();

    const int y = y0 + wv;
    u16* orow = out + ((size_t)(b * 1024 + y * 32) * 64) + lane;
    for (int xg = 0; xg < 32; xg += 4) {
        float a0 = bz, a1 = bz, a2 = bz, a3 = bz;
        #pragma unroll
        for (int ci = 0; ci < 3; ci++) {
            #pragma unroll
            for (int rr = 0; rr < 3; rr++) {
                const float* row = &xs[ci][wv + rr][0];
                float4 c03 = *(const float4*)(row + xg);
                float2 c45 = *(const float2*)(row + xg + 4);
                float w0 = wr[ci * 9 + rr * 3 + 0];
                float w1 = wr[ci * 9 + rr * 3 + 1];
                float w2 = wr[ci * 9 + rr * 3 + 2];
                a0 += c03.x * w0 + c03.y * w1 + c03.z * w2;
                a1 += c03.y * w0 + c03.z * w1 + c03.w * w2;
                a2 += c03.z * w0 + c03.w * w1 + c45.x * w2;
                a3 += c03.w * w0 + c45.x * w1 + c45.y * w2;
            }
        }
        orow[(xg + 0) * 64] = f2bf(fmaxf(a0, 0.f));
        orow[(xg + 1) * 64] = f2bf(fmaxf(a1, 0.f));
        orow[(xg + 2) * 64] = f2bf(fmaxf(a2, 0.f));
        orow[(xg + 3) * 64] = f2bf(fmaxf(a3, 0.f));
    }
}

// ---------------------------------------------------------------------------
__global__ void repack_w(const float* __restrict__ w, u16* __restrict__ wt,
                         int Cin, int total)
{
    int i = blockIdx.x * 256 + threadIdx.x;
    if (i >= total) return;
    int ci = i % Cin;
    int rest = i / Cin;
    int s = rest % 9;
    int co = rest / 9;
    wt[i] = f2bf(w[(co * Cin + ci) * 9 + s]);
}

__global__ void repack_lin(const float* __restrict__ w, u16* __restrict__ wt,
                           int K, int N, int total)
{
    int i = blockIdx.x * 256 + threadIdx.x;
    if (i >= total) return;
    int n = i % N, k = i / N;
    wt[(size_t)n * K + k] = f2bf(w[(size_t)k * N + n]);
}

// ---------------------------------------------------------------------------
// Conv shift-GEMM, bf16 MFMA 16x16x32, register prefetch + double-buffered
// LDS + optional split-K (fp32 partials) + LDS-bounce coalesced epilogue.
// ---------------------------------------------------------------------------
template <int BN>
__global__ __launch_bounds__(256) void conv_gemm(
    const u16* __restrict__ in, const u16* __restrict__ wt,
    const float* __restrict__ bias, u16* __restrict__ out,
    float* __restrict__ partial, size_t pstride,
    int H, int Cin, int Cout, int logHW, int logW, int splitN)
{
    constexpr int BM = 128, BK = 64;
    constexpr int NT   = BN / 32;
    constexpr int NB_A = 4;
    constexpr int NB_B = BN * 8 / 256;
    __shared__ u16 smem[2 * BM * BK + 2 * BN * BK];
    u16* const Asb = smem;                      // 2 buffers of BM*BK
    u16* const Bsb = smem + 2 * BM * BK;        // 2 buffers of BN*BK

    const int Nblocks = Cout / BN;
    const int bid  = blockIdx.x;
    const int sp   = bid % splitN;
    const int tile = bid / splitN;
    const int m0 = (tile / Nblocks) * BM;
    const int n0 = (tile % Nblocks) * BN;

    const int t    = threadIdx.x;
    const int lane = t & 63;
    const int wave = t >> 6;
    const int quad = lane >> 4;
    const int l16  = lane & 15;
    const int wm   = wave >> 1;
    const int wn   = wave & 1;
    const int W    = H;
    const int HW   = 1 << logHW;
    const int col8 = t & 7;
    const int r0   = t >> 3;

    int ab_y[NB_A], ab_x[NB_A], ab_p[NB_A];
    #pragma unroll
    for (int j = 0; j < NB_A; j++) {
        int m  = m0 + r0 + 32 * j;
        int b  = m >> logHW;
        int rm = m & (HW - 1);
        int y  = rm >> logW;
        int xx = rm & (W - 1);
        ab_y[j] = y;
        ab_x[j] = xx;
        ab_p[j] = ((b * H + y) * W + xx) * Cin + col8 * 8;
    }
    int bb_p[NB_B];
    #pragma unroll
    for (int j = 0; j < NB_B; j++)
        bb_p[j] = (n0 + r0 + 32 * j) * 9 * Cin + col8 * 8;

    const int KB  = Cin >> 6;
    const int T   = 9 * KB;
    const int len = T / splitN;
    const int it0 = sp * len;
    int s_cur  = it0 / KB;
    int kb_cur = (it0 % KB) * BK;

    uint4 ar[NB_A], br[NB_B];

    auto prefetch = [&](int s, int kb) {
        int dy  = s / 3 - 1;
        int dx  = s % 3 - 1;
        int off = (dy * W + dx) * Cin + kb;
        #pragma unroll
        for (int j = 0; j < NB_A; j++) {
            bool v = ((unsigned)(ab_y[j] + dy) < (unsigned)H) &&
                     ((unsigned)(ab_x[j] + dx) < (unsigned)W);
            uint4 val = make_uint4(0u, 0u, 0u, 0u);
            if (v) val = *(const uint4*)(in + ab_p[j] + off);
            ar[j] = val;
        }
        int offb = s * Cin + kb;
        #pragma unroll
        for (int j = 0; j < NB_B; j++)
            br[j] = *(const uint4*)(wt + bb_p[j] + offb);
    };
    auto advance = [&]() {
        kb_cur += BK;
        if (kb_cur == Cin) { kb_cur = 0; s_cur++; }
    };
    auto store_tiles = [&](int bsel) {
        u16* As = Asb + bsel * BM * BK;
        u16* Bs = Bsb + bsel * BN * BK;
        #pragma unroll
        for (int j = 0; j < NB_A; j++) {
            int row = r0 + 32 * j;
            *(uint4*)(As + row * 64 + ((col8 ^ (row & 7)) * 8)) = ar[j];
        }
        #pragma unroll
        for (int j = 0; j < NB_B; j++) {
            int row = r0 + 32 * j;
            *(uint4*)(Bs + row * 64 + ((col8 ^ (row & 7)) * 8)) = br[j];
        }
    };

    floatx4 acc[4][NT];
    #pragma unroll
    for (int i = 0; i < 4; i++)
        #pragma unroll
        for (int j = 0; j < NT; j++)
            acc[i][j] = (floatx4){0.f, 0.f, 0.f, 0.f};

    prefetch(s_cur, kb_cur);
    advance();
    store_tiles(0);
    int cur = 0;
    for (int it = 0; it < len; it++) {
        __syncthreads();
        if (it + 1 < len) { prefetch(s_cur, kb_cur); advance(); }
        u16* As = Asb + cur * BM * BK;
        u16* Bs = Bsb + cur * BN * BK;
        #pragma unroll
        for (int kk = 0; kk < BK; kk += 32) {
            bf16x8 af[4], bfv[NT];
            #pragma unroll
            for (int mt = 0; mt < 4; mt++) {
                int row = wm * 64 + mt * 16 + l16;
                int cb  = (kk >> 3) + quad;
                af[mt] = *(const bf16x8*)(As + row * 64 + ((cb ^ (row & 7)) * 8));
            }
            #pragma unroll
            for (int nt = 0; nt < NT; nt++) {
                int row = wn * (BN / 2) + nt * 16 + l16;
                int cb  = (kk >> 3) + quad;
                bfv[nt] = *(const bf16x8*)(Bs + row * 64 + ((cb ^ (row & 7)) * 8));
            }
            #pragma unroll
            for (int mt = 0; mt < 4; mt++)
                #pragma unroll
                for (int nt = 0; nt < NT; nt++)
                    acc[mt][nt] = __builtin_amdgcn_mfma_f32_16x16x32_bf16(
                        af[mt], bfv[nt], acc[mt][nt], 0, 0, 0);
        }
        if (it + 1 < len) store_tiles(cur ^ 1);
        cur ^= 1;
    }

    if (splitN > 1) {
        // fp32 partials: quads write 64B contiguous - acceptable
        float* pout = partial + (size_t)sp * pstride;
        #pragma unroll
        for (int mt = 0; mt < 4; mt++)
            #pragma unroll
            for (int nt = 0; nt < NT; nt++)
                #pragma unroll
                for (int r = 0; r < 4; r++) {
                    int mg = m0 + wm * 64 + mt * 16 + quad * 4 + r;
                    int ng = n0 + wn * (BN / 2) + nt * 16 + l16;
                    pout[(size_t)mg * Cout + ng] = acc[mt][nt][r];
                }
        return;
    }

    // ---- coalesced epilogue: bf16 convert -> LDS bounce -> ushort8 stores
    __syncthreads();                 // K-loop LDS reads complete
    constexpr int LDE = BN + 8;      // u16 row stride, +16B pad
    u16* eb = smem;
    #pragma unroll
    for (int mt = 0; mt < 4; mt++) {
        #pragma unroll
        for (int nt = 0; nt < NT; nt++) {
            int colL = wn * (BN / 2) + nt * 16 + l16;
            float bz = bias[n0 + colL];
            #pragma unroll
            for (int r = 0; r < 4; r++) {
                int rowL = wm * 64 + mt * 16 + quad * 4 + r;
                eb[rowL * LDE + colL] = f2bf(fmaxf(acc[mt][nt][r] + bz, 0.f));
            }
        }
    }
    __syncthreads();
    constexpr int CPR = BN / 8;              // 16B chunks per row
    constexpr int NIT = BM * BN / 8 / 256;   // chunks per thread
    #pragma unroll
    for (int j = 0; j < NIT; j++) {
        int c   = t + 256 * j;
        int row = c / CPR;
        int c8  = c % CPR;
        uint4 v = *(const uint4*)(eb + row * LDE + c8 * 8);
        *(uint4*)(out + (size_t)(m0 + row) * Cout + n0 + c8 * 8) = v;
    }
}

// sum split partials + bias + relu -> bf16 NHWC
__global__ void reduce_split(const float* __restrict__ partial,
                             const float* __restrict__ bias, u16* __restrict__ out,
                             int MN, int N, int splitN, size_t pstride)
{
    int i4 = (blockIdx.x * 256 + threadIdx.x) * 4;
    if (i4 >= MN) return;
    float4 s = *(const float4*)(partial + i4);
    for (int sp = 1; sp < splitN; sp++) {
        float4 p = *(const float4*)(partial + (size_t)sp * pstride + i4);
        s.x += p.x; s.y += p.y; s.z += p.z; s.w += p.w;
    }
    int n = i4 & (N - 1);
    ushort4 o;
    o.x = f2bf(fmaxf(s.x + bias[n + 0], 0.f));
    o.y = f2bf(fmaxf(s.y + bias[n + 1], 0.f));
    o.z = f2bf(fmaxf(s.z + bias[n + 2], 0.f));
    o.w = f2bf(fmaxf(s.w + bias[n + 3], 0.f));
    *(ushort4*)(out + i4) = o;
}

// ---------------------------------------------------------------------------
// Generic small GEMM: out[M,N] = act(A[M,K](bf16) @ Bt[N,K](bf16)^T + bias)
// ---------------------------------------------------------------------------
template <bool RELU, bool OUTBF>
__global__ __launch_bounds__(256) void gemm64(
    const u16* __restrict__ A, const u16* __restrict__ Bt,
    const float* __restrict__ bias, void* __restrict__ outv,
    int M, int N, int K)
{
    constexpr int LDP = 72;
    __shared__ u16 As[64 * LDP];
    __shared__ u16 Bs[64 * LDP];

    const int nb = N >> 6;
    const int m0 = (blockIdx.x / nb) * 64;
    const int n0 = (blockIdx.x % nb) * 64;
    const int t = threadIdx.x, lane = t & 63, wave = t >> 6;
    const int quad = lane >> 4, l16 = lane & 15;
    const int wm = wave >> 1, wn = wave & 1;
    const int col8 = t & 7, r0 = t >> 3;

    floatx4 acc[2][2];
    #pragma unroll
    for (int i = 0; i < 2; i++)
        #pragma unroll
        for (int j = 0; j < 2; j++)
            acc[i][j] = (floatx4){0.f, 0.f, 0.f, 0.f};

    for (int kb = 0; kb < K; kb += 64) {
        #pragma unroll
        for (int j = 0; j < 2; j++) {
            int row = r0 + 32 * j;
            *(uint4*)(As + row * LDP + col8 * 8) =
                *(const uint4*)(A + (size_t)(m0 + row) * K + kb + col8 * 8);
            *(uint4*)(Bs + row * LDP + col8 * 8) =
                *(const uint4*)(Bt + (size_t)(n0 + row) * K + kb + col8 * 8);
        }
        __syncthreads();
        #pragma unroll
        for (int kk = 0; kk < 64; kk += 32) {
            bf16x8 af[2], bfv[2];
            #pragma unroll
            for (int mt = 0; mt < 2; mt++)
                af[mt] = *(const bf16x8*)(As + (wm * 32 + mt * 16 + l16) * LDP + kk + quad * 8);
            #pragma unroll
            for (int nt = 0; nt < 2; nt++)
                bfv[nt] = *(const bf16x8*)(Bs + (wn * 32 + nt * 16 + l16) * LDP + kk + quad * 8);
            #pragma unroll
            for (int mt = 0; mt < 2; mt++)
                #pragma unroll
                for (int nt = 0; nt < 2; nt++)
                    acc[mt][nt] = __builtin_amdgcn_mfma_f32_16x16x32_bf16(
                        af[mt], bfv[nt], acc[mt][nt], 0, 0, 0);
        }
        __syncthreads();
    }
    #pragma unroll
    for (int mt = 0; mt < 2; mt++) {
        #pragma unroll
        for (int nt = 0; nt < 2; nt++) {
            #pragma unroll
            for (int r = 0; r < 4; r++) {
                int mg = m0 + wm * 32 + mt * 16 + quad * 4 + r;
                int ng = n0 + wn * 32 + nt * 16 + l16;
                float v = acc[mt][nt][r] + bias[ng];
                if (RELU) v = fmaxf(v, 0.f);
                if (OUTBF) ((u16*)outv)[(size_t)mg * N + ng] = f2bf(v);
                else       ((float*)outv)[(size_t)mg * N + ng] = v;
            }
        }
    }
}

// ---------------------------------------------------------------------------
__global__ __launch_bounds__(256) void graph_tile(
    const float* __restrict__ low, const int* __restrict__ target,
    float* __restrict__ gpre, float* __restrict__ ggt)
{
    __shared__ float Al[64 * 132];
    __shared__ float Bl[128 * 68];
    const int t = threadIdx.x;
    const int gr0 = (blockIdx.x >> 3) * 64;
    const int gc0 = (blockIdx.x & 7) * 64;

    #pragma unroll
    for (int j = 0; j < 32; j++) {
        int flat = t + 256 * j;
        int k = flat & 127;
        int rc = flat >> 7;
        Al[rc * 132 + k] = low[(size_t)(gr0 + rc) * 128 + k];
        Bl[k * 68 + rc]  = low[(size_t)(gc0 + rc) * 128 + k];
    }
    __syncthreads();

    const int tx = t & 15, ty = t >> 4;
    float acc[4][4];
    #pragma unroll
    for (int r = 0; r < 4; r++)
        #pragma unroll
        for (int c = 0; c < 4; c++) acc[r][c] = 0.f;

    for (int k = 0; k < 128; k++) {
        float a[4], b[4];
        #pragma unroll
        for (int r = 0; r < 4; r++) a[r] = Al[(ty * 4 + r) * 132 + k];
        #pragma unroll
        for (int c = 0; c < 4; c++) b[c] = Bl[k * 68 + tx * 4 + c];
        #pragma unroll
        for (int r = 0; r < 4; r++)
            #pragma unroll
            for (int c = 0; c < 4; c++) acc[r][c] += a[r] * b[c];
    }
    #pragma unroll
    for (int r = 0; r < 4; r++) {
        int row = gr0 + ty * 4 + r;
        int tr  = target[row];
        float4 gp, gg;
        float* pp = (float*)&gp;
        float* gg_ = (float*)&gg;
        #pragma unroll
        for (int c = 0; c < 4; c++) {
            pp[c]  = 1.f / (1.f + __expf(-acc[r][c]));
            gg_[c] = (tr == target[gc0 + tx * 4 + c]) ? 1.f : 0.f;
        }
        *(float4*)(gpre + (size_t)row * 512 + gc0 + tx * 4) = gp;
        *(float4*)(ggt  + (size_t)row * 512 + gc0 + tx * 4) = gg;
    }
}

// ---------------------------------------------------------------------------
__global__ __launch_bounds__(256) void cls_kernel(
    const u16* __restrict__ feat, const float* __restrict__ w,
    const float* __restrict__ bias, float* __restrict__ out)
{
    __shared__ float ws[5120];
    const int t = threadIdx.x;
    for (int i = t; i < 5120; i += 256) ws[i] = w[i];
    __syncthreads();
    const int lane = t & 63;
    const int row  = blockIdx.x * 4 + (t >> 6);
    float a[10];
    #pragma unroll
    for (int j = 0; j < 10; j++) a[j] = 0.f;
    #pragma unroll
    for (int i = 0; i < 8; i++) {
        int k = i * 64 + lane;
        float f = bf2f(feat[(size_t)row * 512 + k]);
        #pragma unroll
        for (int j = 0; j < 10; j++) a[j] += f * ws[k * 10 + j];
    }
    #pragma unroll
    for (int j = 0; j < 10; j++)
        #pragma unroll
        for (int off = 32; off > 0; off >>= 1)
            a[j] += __shfl_down(a[j], off, 64);
    if (lane == 0) {
        #pragma unroll
        for (int j = 0; j < 10; j++) out[row * 10 + j] = a[j] + bias[j];
    }
}

// ---------------------------------------------------------------------------
__global__ void pool2(const u16* __restrict__ in, u16* __restrict__ out,
                      int Hout, int C, int total)
{
    int i = blockIdx.x * 256 + threadIdx.x;
    if (i >= total) return;
    int c = i % C;
    int rest = i / C;
    int x = rest % Hout; rest /= Hout;
    int y = rest % Hout;
    int b = rest / Hout;
    int Hin = Hout * 2;
    const u16* p = in + ((size_t)((b * Hin + 2 * y) * Hin + 2 * x) * C + c);
    float v0 = bf2f(p[0]);
    float v1 = bf2f(p[C]);
    float v2 = bf2f(p[(size_t)Hin * C]);
    float v3 = bf2f(p[(size_t)Hin * C + C]);
    out[i] = f2bf(fmaxf(fmaxf(v0, v1), fmaxf(v2, v3)));
}

// ---------------------------------------------------------------------------
extern "C" void kernel_launch(void* const* d_in, const int* in_sizes, int n_in,
                              void* d_out, int out_size, void* d_ws, size_t ws_size,
                              hipStream_t stream)
{
    const float* x      = (const float*)d_in[0];
    const int*   target = (const int*)d_in[1];
    const float* conv_w[13];
    const float* conv_b[13];
    for (int i = 0; i < 13; i++) {
        conv_w[i] = (const float*)d_in[2 + 2 * i];
        conv_b[i] = (const float*)d_in[3 + 2 * i];
    }
    const float* lin1_w = (const float*)d_in[28];
    const float* lin1_b = (const float*)d_in[29];
    const float* lin2_w = (const float*)d_in[30];
    const float* lin2_b = (const float*)d_in[31];
    const float* cls_w  = (const float*)d_in[32];
    const float* cls_b  = (const float*)d_in[33];
    float* out = (float*)d_out;

    static const int cin_arr[13]  = {3, 64, 64, 128, 128, 256, 256, 256, 512, 512, 512, 512, 512};
    static const int cout_arr[13] = {64, 64, 128, 128, 256, 256, 256, 512, 512, 512, 512, 512, 512};

    char* ws = (char*)d_ws;
    size_t off = 0;
    char* R0raw = ws + off; off += (size_t)512 * 32 * 32 * 64 * 2;
    char* R1raw = ws + off; off += (size_t)512 * 32 * 32 * 64 * 2;
    u16* R0 = (u16*)R0raw;
    u16* R1 = (u16*)R1raw;
    float* P0 = (float*)(R0raw + 33554432);   // split-K partials alias upper half
    float* P1 = (float*)(R1raw + 33554432);
    u16* wt[13];
    for (int i = 1; i < 13; i++) {
        wt[i] = (u16*)(ws + off);
        off += (size_t)cout_arr[i] * 9 * cin_arr[i] * 2;
    }
    u16* wtl1 = (u16*)(ws + off); off += (size_t)256 * 512 * 2;
    u16* wtl2 = (u16*)(ws + off); off += (size_t)128 * 256 * 2;
    u16* hbuf = (u16*)(ws + off); off += (size_t)512 * 256 * 2;
    float* lowbuf = (float*)(ws + off); off += (size_t)512 * 128 * 4;

    for (int i = 1; i < 13; i++) {
        int total = cout_arr[i] * 9 * cin_arr[i];
        repack_w<<<(total + 255) / 256, 256, 0, stream>>>(conv_w[i], wt[i], cin_arr[i], total);
    }
    repack_lin<<<(512 * 256) / 256, 256, 0, stream>>>(lin1_w, wtl1, 512, 256, 512 * 256);
    repack_lin<<<(256 * 128) / 256, 256, 0, stream>>>(lin2_w, wtl2, 256, 128, 256 * 128);

    conv0_kernel<<<512 * 8, 256, 0, stream>>>(x, conv_w[0], conv_b[0], R0);

    auto launch_conv = [&](int li, int Hl, u16* inb, u16* outb, float* part, int splitN) {
        int Cin = cin_arr[li], Cout = cout_arr[li];
        int M = 512 * Hl * Hl;
        int logW = __builtin_ctz(Hl);
        int logHW = 2 * logW;
        size_t pstride = (size_t)M * Cout;
        if (Cout >= 128) {
            int grid = (M / 128) * (Cout / 128) * splitN;
            conv_gemm<128><<<grid, 256, 0, stream>>>(
                inb, wt[li], conv_b[li], outb, part, pstride,
                Hl, Cin, Cout, logHW, logW, splitN);
        } else {
            int grid = (M / 128) * (Cout / 64) * splitN;
            conv_gemm<64><<<grid, 256, 0, stream>>>(
                inb, wt[li], conv_b[li], outb, part, pstride,
                Hl, Cin, Cout, logHW, logW, splitN);
        }
        if (splitN > 1) {
            int MN = M * Cout;
            reduce_split<<<(MN / 4 + 255) / 256, 256, 0, stream>>>(
                part, conv_b[li], outb, MN, Cout, splitN, pstride);
        }
    };
    auto launch_pool = [&](int Hout, int C, u16* inb, u16* outb) {
        int total = 512 * Hout * Hout * C;
        pool2<<<(total + 255) / 256, 256, 0, stream>>>(inb, outb, Hout, C, total);
    };

    launch_conv(1, 32, R0, R1, nullptr, 1);
    launch_pool(16, 64, R1, R0);
    launch_conv(2, 16, R0, R1, nullptr, 1);
    launch_conv(3, 16, R1, R0, nullptr, 1);
    launch_pool(8, 128, R0, R1);
    launch_conv(4, 8, R1, R0, nullptr, 1);
    launch_conv(5, 8, R0, R1, nullptr, 1);
    launch_conv(6, 8, R1, R0, nullptr, 1);
    launch_pool(4, 256, R0, R1);
    launch_conv(7, 4, R1, R0, P0, 2);
    launch_conv(8, 4, R0, R1, P1, 2);
    launch_conv(9, 4, R1, R0, P0, 2);
    launch_pool(2, 512, R0, R1);
    launch_conv(10, 2, R1, R0, P0, 8);
    launch_conv(11, 2, R0, R1, P1, 8);
    launch_conv(12, 2, R1, R0, P0, 8);
    launch_pool(1, 512, R0, R1);          // feat bf16 [512,512] in R1

    gemm64<true, true><<<(512 / 64) * (256 / 64), 256, 0, stream>>>(
        R1, wtl1, lin1_b, hbuf, 512, 256, 512);
    gemm64<false, false><<<(512 / 64) * (128 / 64), 256, 0, stream>>>(
        hbuf, wtl2, lin2_b, lowbuf, 512, 128, 256);
    graph_tile<<<64, 256, 0, stream>>>(lowbuf, target, out + 5120, out + 5120 + 262144);
    cls_kernel<<<128, 256, 0, stream>>>(R1, cls_w, cls_b, out);
}

// Round 6
// 974.551 us; speedup vs baseline: 1.3053x; 1.3053x over previous
//
#include <hip/hip_runtime.h>

typedef unsigned short u16;
typedef __bf16 bf16x8 __attribute__((ext_vector_type(8)));
typedef float floatx4 __attribute__((ext_vector_type(4)));

__device__ inline u16 f2bf(float f) {
    unsigned int u = __float_as_uint(f);
    unsigned int r = (u + 0x7FFFu + ((u >> 16) & 1u)) >> 16;
    return (u16)r;
}
__device__ inline float bf2f(u16 h) {
    return __uint_as_float(((unsigned int)h) << 16);
}

// async global->LDS, 16B per lane. LDS dest must be wave-uniform base + lane*16.
// Generic LDS pointer low 32 bits == LDS offset on gfx9+ (CK pattern).
__device__ __forceinline__ void async_copy16(u16* lds, const u16* g) {
    __builtin_amdgcn_global_load_lds(
        (const __attribute__((address_space(1))) unsigned int*)(uintptr_t)g,
        (__attribute__((address_space(3))) unsigned int*)(unsigned int)(uintptr_t)lds,
        16, 0, 0);
}

// ---------------------------------------------------------------------------
// zero the 1-px halo of a padded NHWC buffer [512][Hp][Hp][C]
// ---------------------------------------------------------------------------
__global__ void zero_halo(u16* __restrict__ buf, int Hp, int C, int total8)
{
    int i = blockIdx.x * 256 + threadIdx.x;
    if (i >= total8) return;
    int c8 = i % (C / 8);
    int p  = i / (C / 8);
    int x  = p % Hp; p /= Hp;
    int y  = p % Hp;
    int b  = p / Hp;
    if (y == 0 || y == Hp - 1 || x == 0 || x == Hp - 1) {
        uint4 z = make_uint4(0u, 0u, 0u, 0u);
        *(uint4*)(buf + ((size_t)((b * Hp + y) * Hp + x) * C) + c8 * 8) = z;
    }
}

// ---------------------------------------------------------------------------
// Layer 0: direct conv 3->64, 32x32, output PADDED NHWC [512][34][34][64]
// ---------------------------------------------------------------------------
__global__ __launch_bounds__(256) void conv0_kernel(
    const float* __restrict__ x, const float* __restrict__ w,
    const float* __restrict__ bias, u16* __restrict__ out)
{
    __shared__ __align__(16) float xs[3][6][36];
    const int t  = threadIdx.x;
    const int b  = blockIdx.x >> 3;
    const int y0 = (blockIdx.x & 7) * 4;

    for (int i = t; i < 3 * 6 * 36; i += 256) {
        int ci  = i / 216;
        int rem = i % 216;
        int r   = rem / 36;
        int c   = rem % 36;
        int gy  = y0 - 1 + r;
        int gx  = c - 1;
        float v = 0.f;
        if ((unsigned)gy < 32u && (unsigned)gx < 32u)
            v = x[((b * 3 + ci) * 32 + gy) * 32 + gx];
        xs[ci][r][c] = v;
    }
    const int lane = t & 63;
    const int wv   = t >> 6;
    float wr[27];
    #pragma unroll
    for (int k = 0; k < 27; k++) wr[k] = w[lane * 27 + k];
    const float bz = bias[lane];
    __syncthreads();

    const int y = y0 + wv;
    u16* orow = out + ((size_t)((b * 34 + y + 1) * 34 + 1) * 64) + lane;
    for (int xg = 0; xg < 32; xg += 4) {
        float a0 = bz, a1 = bz, a2 = bz, a3 = bz;
        #pragma unroll
        for (int ci = 0; ci < 3; ci++) {
            #pragma unroll
            for (int rr = 0; rr < 3; rr++) {
                const float* row = &xs[ci][wv + rr][0];
                float4 c03 = *(const float4*)(row + xg);
                float2 c45 = *(const float2*)(row + xg + 4);
                float w0 = wr[ci * 9 + rr * 3 + 0];
                float w1 = wr[ci * 9 + rr * 3 + 1];
                float w2 = wr[ci * 9 + rr * 3 + 2];
                a0 += c03.x * w0 + c03.y * w1 + c03.z * w2;
                a1 += c03.y * w0 + c03.z * w1 + c03.w * w2;
                a2 += c03.z * w0 + c03.w * w1 + c45.x * w2;
                a3 += c03.w * w0 + c45.x * w1 + c45.y * w2;
            }
        }
        orow[(xg + 0) * 64] = f2bf(fmaxf(a0, 0.f));
        orow[(xg + 1) * 64] = f2bf(fmaxf(a1, 0.f));
        orow[(xg + 2) * 64] = f2bf(fmaxf(a2, 0.f));
        orow[(xg + 3) * 64] = f2bf(fmaxf(a3, 0.f));
    }
}

// ---------------------------------------------------------------------------
__global__ void repack_w(const float* __restrict__ w, u16* __restrict__ wt,
                         int Cin, int total)
{
    int i = blockIdx.x * 256 + threadIdx.x;
    if (i >= total) return;
    int ci = i % Cin;
    int rest = i / Cin;
    int s = rest % 9;
    int co = rest / 9;
    wt[i] = f2bf(w[(co * Cin + ci) * 9 + s]);
}

__global__ void repack_lin(const float* __restrict__ w, u16* __restrict__ wt,
                           int K, int N, int total)
{
    int i = blockIdx.x * 256 + threadIdx.x;
    if (i >= total) return;
    int n = i % N, k = i / N;
    wt[(size_t)n * K + k] = f2bf(w[(size_t)k * N + n]);
}

// ---------------------------------------------------------------------------
// Conv shift-GEMM, bf16 MFMA 16x16x32. Input PADDED NHWC (zeroed halo) ->
// no predication; staging via global_load_lds (async DMA, 16B/lane), m97-style
// single-buffer 2-barrier K-loop. Optional split-K (fp32 partials, unpadded).
// Output padded or unpadded per flag.
// ---------------------------------------------------------------------------
template <int BN>
__global__ __launch_bounds__(256) void conv_gemm(
    const u16* __restrict__ in, const u16* __restrict__ wt,
    const float* __restrict__ bias, u16* __restrict__ out,
    float* __restrict__ partial, size_t pstride,
    int H, int Cin, int Cout, int logHW, int logW, int splitN, int outPad)
{
    constexpr int BM = 128, BK = 64;
    constexpr int NT   = BN / 32;
    constexpr int NB_A = 4;              // 128 rows / 32 rows-per-issue
    constexpr int NB_B = BN / 32;
    __shared__ u16 As[BM * BK];
    __shared__ u16 Bs[BN * BK];

    const int Nblocks = Cout / BN;
    const int bid  = blockIdx.x;
    const int sp   = bid % splitN;
    const int tile = bid / splitN;
    const int m0 = (tile / Nblocks) * BM;
    const int n0 = (tile % Nblocks) * BN;

    const int t    = threadIdx.x;
    const int lane = t & 63;
    const int wave = t >> 6;
    const int quad = lane >> 4;
    const int l16  = lane & 15;
    const int wm   = wave >> 1;
    const int wn   = wave & 1;
    const int W    = H;
    const int Wp   = H + 2;
    const int HW   = 1 << logHW;
    const int col8 = t & 7;
    const int r0   = t >> 3;

    // per-thread global base pointers into the padded input (center tap, kb=0)
    const u16* pA[NB_A];
    #pragma unroll
    for (int j = 0; j < NB_A; j++) {
        int m  = m0 + r0 + 32 * j;
        int b  = m >> logHW;
        int rm = m & (HW - 1);
        int y  = rm >> logW;
        int xx = rm & (W - 1);
        pA[j] = in + ((size_t)((b * Wp + y + 1) * Wp + xx + 1) * Cin + col8 * 8);
    }
    const u16* pB[NB_B];
    #pragma unroll
    for (int j = 0; j < NB_B; j++)
        pB[j] = wt + ((size_t)(n0 + r0 + 32 * j) * 9 * Cin + col8 * 8);

    const int logKB = (Cin == 64) ? 0 : (Cin == 128) ? 1 : (Cin == 256) ? 2 : 3;
    const int KB  = 1 << logKB;
    const int T   = 9 * KB;
    const int len = T / splitN;
    const int it0 = sp * len;

    u16* const ldsA = As + t * 8;     // lane-linear: t*16 bytes
    u16* const ldsB = Bs + t * 8;

    floatx4 acc[4][NT];
    #pragma unroll
    for (int i = 0; i < 4; i++)
        #pragma unroll
        for (int j = 0; j < NT; j++)
            acc[i][j] = (floatx4){0.f, 0.f, 0.f, 0.f};

    for (int it = 0; it < len; it++) {
        const int ia = it0 + it;
        const int s  = ia >> logKB;          // tap 0..8
        const int kb = (ia & (KB - 1)) << 6; // channel block
        const int dy = s / 3 - 1;
        const int dx = s % 3 - 1;
        const int ta = (dy * Wp + dx) * Cin + kb;
        const int tb = ia << 6;              // s*Cin + kb == ia*64
        #pragma unroll
        for (int j = 0; j < NB_A; j++)
            async_copy16(ldsA + j * 2048, pA[j] + ta);
        #pragma unroll
        for (int j = 0; j < NB_B; j++)
            async_copy16(ldsB + j * 2048, pB[j] + tb);
        __syncthreads();   // drains the async loads (vmcnt(0) implicit)
        #pragma unroll
        for (int kk = 0; kk < BK; kk += 32) {
            bf16x8 af[4], bfv[NT];
            #pragma unroll
            for (int mt = 0; mt < 4; mt++)
                af[mt] = *(const bf16x8*)(As + (wm * 64 + mt * 16 + l16) * 64 + kk + quad * 8);
            #pragma unroll
            for (int nt = 0; nt < NT; nt++)
                bfv[nt] = *(const bf16x8*)(Bs + (wn * (BN / 2) + nt * 16 + l16) * 64 + kk + quad * 8);
            #pragma unroll
            for (int mt = 0; mt < 4; mt++)
                #pragma unroll
                for (int nt = 0; nt < NT; nt++)
                    acc[mt][nt] = __builtin_amdgcn_mfma_f32_16x16x32_bf16(
                        af[mt], bfv[nt], acc[mt][nt], 0, 0, 0);
        }
        __syncthreads();   // protect LDS before next issue
    }

    if (splitN > 1) {
        float* pout = partial + (size_t)sp * pstride;
        #pragma unroll
        for (int mt = 0; mt < 4; mt++)
            #pragma unroll
            for (int nt = 0; nt < NT; nt++)
                #pragma unroll
                for (int r = 0; r < 4; r++) {
                    int mg = m0 + wm * 64 + mt * 16 + quad * 4 + r;
                    int ng = n0 + wn * (BN / 2) + nt * 16 + l16;
                    pout[(size_t)mg * Cout + ng] = acc[mt][nt][r];
                }
        return;
    }
    #pragma unroll
    for (int mt = 0; mt < 4; mt++) {
        #pragma unroll
        for (int r = 0; r < 4; r++) {
            int mg = m0 + wm * 64 + mt * 16 + quad * 4 + r;
            size_t obase;
            if (outPad) {
                int b  = mg >> logHW;
                int rm = mg & (HW - 1);
                int y  = rm >> logW;
                int xx = rm & (W - 1);
                obase = (size_t)((b * Wp + y + 1) * Wp + xx + 1) * Cout;
            } else {
                obase = (size_t)mg * Cout;
            }
            #pragma unroll
            for (int nt = 0; nt < NT; nt++) {
                int ng = n0 + wn * (BN / 2) + nt * 16 + l16;
                float v = acc[mt][nt][r] + bias[ng];
                out[obase + ng] = f2bf(fmaxf(v, 0.f));
            }
        }
    }
}

// sum split partials + bias + relu -> bf16 NHWC (padded out optional)
__global__ void reduce_split(const float* __restrict__ partial,
                             const float* __restrict__ bias, u16* __restrict__ out,
                             int MN, int C, int logC, int splitN, size_t pstride,
                             int H, int logHW, int logW, int outPad)
{
    int i4 = (blockIdx.x * 256 + threadIdx.x) * 4;
    if (i4 >= MN) return;
    float4 s = *(const float4*)(partial + i4);
    for (int sp = 1; sp < splitN; sp++) {
        float4 p = *(const float4*)(partial + (size_t)sp * pstride + i4);
        s.x += p.x; s.y += p.y; s.z += p.z; s.w += p.w;
    }
    int n = i4 & (C - 1);
    int m = i4 >> logC;
    size_t obase;
    if (outPad) {
        int Wp = H + 2;
        int b  = m >> logHW;
        int rm = m & ((1 << logHW) - 1);
        int y  = rm >> logW;
        int xx = rm & (H - 1);
        obase = (size_t)((b * Wp + y + 1) * Wp + xx + 1) * C;
    } else {
        obase = (size_t)m * C;
    }
    ushort4 o;
    o.x = f2bf(fmaxf(s.x + bias[n + 0], 0.f));
    o.y = f2bf(fmaxf(s.y + bias[n + 1], 0.f));
    o.z = f2bf(fmaxf(s.z + bias[n + 2], 0.f));
    o.w = f2bf(fmaxf(s.w + bias[n + 3], 0.f));
    *(ushort4*)(out + obase + n) = o;
}

// ---------------------------------------------------------------------------
// 2x2 maxpool, NHWC bf16. Input UNPADDED [B,Hin,Hin,C]; output padded optional.
// ---------------------------------------------------------------------------
__global__ void pool2(const u16* __restrict__ in, u16* __restrict__ out,
                      int Hout, int C, int total, int outPad)
{
    int i = blockIdx.x * 256 + threadIdx.x;
    if (i >= total) return;
    int c = i % C;
    int rest = i / C;
    int x = rest % Hout; rest /= Hout;
    int y = rest % Hout;
    int b = rest / Hout;
    int Hin = Hout * 2;
    const u16* p = in + ((size_t)((b * Hin + 2 * y) * Hin + 2 * x) * C + c);
    float v0 = bf2f(p[0]);
    float v1 = bf2f(p[C]);
    float v2 = bf2f(p[(size_t)Hin * C]);
    float v3 = bf2f(p[(size_t)Hin * C + C]);
    size_t oidx;
    if (outPad) {
        int Hp = Hout + 2;
        oidx = (size_t)((b * Hp + y + 1) * Hp + x + 1) * C + c;
    } else {
        oidx = (size_t)i;
    }
    out[oidx] = f2bf(fmaxf(fmaxf(v0, v1), fmaxf(v2, v3)));
}

// ---------------------------------------------------------------------------
// Generic small GEMM: out[M,N] = act(A[M,K](bf16) @ Bt[N,K](bf16)^T + bias)
// ---------------------------------------------------------------------------
template <bool RELU, bool OUTBF>
__global__ __launch_bounds__(256) void gemm64(
    const u16* __restrict__ A, const u16* __restrict__ Bt,
    const float* __restrict__ bias, void* __restrict__ outv,
    int M, int N, int K)
{
    constexpr int LDP = 72;
    __shared__ u16 As[64 * LDP];
    __shared__ u16 Bs[64 * LDP];

    const int nb = N >> 6;
    const int m0 = (blockIdx.x / nb) * 64;
    const int n0 = (blockIdx.x % nb) * 64;
    const int t = threadIdx.x, lane = t & 63, wave = t >> 6;
    const int quad = lane >> 4, l16 = lane & 15;
    const int wm = wave >> 1, wn = wave & 1;
    const int col8 = t & 7, r0 = t >> 3;

    floatx4 acc[2][2];
    #pragma unroll
    for (int i = 0; i < 2; i++)
        #pragma unroll
        for (int j = 0; j < 2; j++)
            acc[i][j] = (floatx4){0.f, 0.f, 0.f, 0.f};

    for (int kb = 0; kb < K; kb += 64) {
        #pragma unroll
        for (int j = 0; j < 2; j++) {
            int row = r0 + 32 * j;
            *(uint4*)(As + row * LDP + col8 * 8) =
                *(const uint4*)(A + (size_t)(m0 + row) * K + kb + col8 * 8);
            *(uint4*)(Bs + row * LDP + col8 * 8) =
                *(const uint4*)(Bt + (size_t)(n0 + row) * K + kb + col8 * 8);
        }
        __syncthreads();
        #pragma unroll
        for (int kk = 0; kk < 64; kk += 32) {
            bf16x8 af[2], bfv[2];
            #pragma unroll
            for (int mt = 0; mt < 2; mt++)
                af[mt] = *(const bf16x8*)(As + (wm * 32 + mt * 16 + l16) * LDP + kk + quad * 8);
            #pragma unroll
            for (int nt = 0; nt < 2; nt++)
                bfv[nt] = *(const bf16x8*)(Bs + (wn * 32 + nt * 16 + l16) * LDP + kk + quad * 8);
            #pragma unroll
            for (int mt = 0; mt < 2; mt++)
                #pragma unroll
                for (int nt = 0; nt < 2; nt++)
                    acc[mt][nt] = __builtin_amdgcn_mfma_f32_16x16x32_bf16(
                        af[mt], bfv[nt], acc[mt][nt], 0, 0, 0);
        }
        __syncthreads();
    }
    #pragma unroll
    for (int mt = 0; mt < 2; mt++) {
        #pragma unroll
        for (int nt = 0; nt < 2; nt++) {
            #pragma unroll
            for (int r = 0; r < 4; r++) {
                int mg = m0 + wm * 32 + mt * 16 + quad * 4 + r;
                int ng = n0 + wn * 32 + nt * 16 + l16;
                float v = acc[mt][nt][r] + bias[ng];
                if (RELU) v = fmaxf(v, 0.f);
                if (OUTBF) ((u16*)outv)[(size_t)mg * N + ng] = f2bf(v);
                else       ((float*)outv)[(size_t)mg * N + ng] = v;
            }
        }
    }
}

// ---------------------------------------------------------------------------
__global__ __launch_bounds__(256) void graph_tile(
    const float* __restrict__ low, const int* __restrict__ target,
    float* __restrict__ gpre, float* __restrict__ ggt)
{
    __shared__ float Al[64 * 132];
    __shared__ float Bl[128 * 68];
    const int t = threadIdx.x;
    const int gr0 = (blockIdx.x >> 3) * 64;
    const int gc0 = (blockIdx.x & 7) * 64;

    #pragma unroll
    for (int j = 0; j < 32; j++) {
        int flat = t + 256 * j;
        int k = flat & 127;
        int rc = flat >> 7;
        Al[rc * 132 + k] = low[(size_t)(gr0 + rc) * 128 + k];
        Bl[k * 68 + rc]  = low[(size_t)(gc0 + rc) * 128 + k];
    }
    __syncthreads();

    const int tx = t & 15, ty = t >> 4;
    float acc[4][4];
    #pragma unroll
    for (int r = 0; r < 4; r++)
        #pragma unroll
        for (int c = 0; c < 4; c++) acc[r][c] = 0.f;

    for (int k = 0; k < 128; k++) {
        float a[4], b[4];
        #pragma unroll
        for (int r = 0; r < 4; r++) a[r] = Al[(ty * 4 + r) * 132 + k];
        #pragma unroll
        for (int c = 0; c < 4; c++) b[c] = Bl[k * 68 + tx * 4 + c];
        #pragma unroll
        for (int r = 0; r < 4; r++)
            #pragma unroll
            for (int c = 0; c < 4; c++) acc[r][c] += a[r] * b[c];
    }
    #pragma unroll
    for (int r = 0; r < 4; r++) {
        int row = gr0 + ty * 4 + r;
        int tr  = target[row];
        float4 gp, gg;
        float* pp = (float*)&gp;
        float* gg_ = (float*)&gg;
        #pragma unroll
        for (int c = 0; c < 4; c++) {
            pp[c]  = 1.f / (1.f + __expf(-acc[r][c]));
            gg_[c] = (tr == target[gc0 + tx * 4 + c]) ? 1.f : 0.f;
        }
        *(float4*)(gpre + (size_t)row * 512 + gc0 + tx * 4) = gp;
        *(float4*)(ggt  + (size_t)row * 512 + gc0 + tx * 4) = gg;
    }
}

// ---------------------------------------------------------------------------
__global__ __launch_bounds__(256) void cls_kernel(
    const u16* __restrict__ feat, const float* __restrict__ w,
    const float* __restrict__ bias, float* __restrict__ out)
{
    __shared__ float ws[5120];
    const int t = threadIdx.x;
    for (int i = t; i < 5120; i += 256) ws[i] = w[i];
    __syncthreads();
    const int lane = t & 63;
    const int row  = blockIdx.x * 4 + (t >> 6);
    float a[10];
    #pragma unroll
    for (int j = 0; j < 10; j++) a[j] = 0.f;
    #pragma unroll
    for (int i = 0; i < 8; i++) {
        int k = i * 64 + lane;
        float f = bf2f(feat[(size_t)row * 512 + k]);
        #pragma unroll
        for (int j = 0; j < 10; j++) a[j] += f * ws[k * 10 + j];
    }
    #pragma unroll
    for (int j = 0; j < 10; j++)
        #pragma unroll
        for (int off = 32; off > 0; off >>= 1)
            a[j] += __shfl_down(a[j], off, 64);
    if (lane == 0) {
        #pragma unroll
        for (int j = 0; j < 10; j++) out[row * 10 + j] = a[j] + bias[j];
    }
}

// ---------------------------------------------------------------------------
extern "C" void kernel_launch(void* const* d_in, const int* in_sizes, int n_in,
                              void* d_out, int out_size, void* d_ws, size_t ws_size,
                              hipStream_t stream)
{
    const float* x      = (const float*)d_in[0];
    const int*   target = (const int*)d_in[1];
    const float* conv_w[13];
    const float* conv_b[13];
    for (int i = 0; i < 13; i++) {
        conv_w[i] = (const float*)d_in[2 + 2 * i];
        conv_b[i] = (const float*)d_in[3 + 2 * i];
    }
    const float* lin1_w = (const float*)d_in[28];
    const float* lin1_b = (const float*)d_in[29];
    const float* lin2_w = (const float*)d_in[30];
    const float* lin2_b = (const float*)d_in[31];
    const float* cls_w  = (const float*)d_in[32];
    const float* cls_b  = (const float*)d_in[33];
    float* out = (float*)d_out;

    static const int cin_arr[13]  = {3, 64, 64, 128, 128, 256, 256, 256, 512, 512, 512, 512, 512};
    static const int cout_arr[13] = {64, 64, 128, 128, 256, 256, 256, 512, 512, 512, 512, 512, 512};

    char* ws = (char*)d_ws;
    size_t off = 0;
    const size_t R0SZ = (size_t)512 * 34 * 34 * 64 * 2;   // 75.8 MB (max padded)
    const size_t R1SZ = (size_t)512 * 32 * 32 * 64 * 2;   // 67.1 MB
    char* R0raw = ws + off; off += R0SZ;
    char* R1raw = ws + off; off += R1SZ;
    u16* R0 = (u16*)R0raw;
    u16* R1 = (u16*)R1raw;
    float* PA = (float*)(R0raw + 20971520);   // partials alias beyond active extents
    float* PB = (float*)(R1raw + 20971520);
    u16* wt[13];
    for (int i = 1; i < 13; i++) {
        wt[i] = (u16*)(ws + off);
        off += (size_t)cout_arr[i] * 9 * cin_arr[i] * 2;
    }
    u16* wtl1 = (u16*)(ws + off); off += (size_t)256 * 512 * 2;
    u16* wtl2 = (u16*)(ws + off); off += (size_t)128 * 256 * 2;
    u16* hbuf = (u16*)(ws + off); off += (size_t)512 * 256 * 2;
    float* lowbuf = (float*)(ws + off); off += (size_t)512 * 128 * 4;

    for (int i = 1; i < 13; i++) {
        int total = cout_arr[i] * 9 * cin_arr[i];
        repack_w<<<(total + 255) / 256, 256, 0, stream>>>(conv_w[i], wt[i], cin_arr[i], total);
    }
    repack_lin<<<(512 * 256) / 256, 256, 0, stream>>>(lin1_w, wtl1, 512, 256, 512 * 256);
    repack_lin<<<(256 * 128) / 256, 256, 0, stream>>>(lin2_w, wtl2, 256, 128, 256 * 128);

    auto zh = [&](u16* buf, int Hp, int C) {
        int total8 = 512 * Hp * Hp * (C / 8);
        zero_halo<<<(total8 + 255) / 256, 256, 0, stream>>>(buf, Hp, C, total8);
    };
    auto launch_conv = [&](int li, int Hl, u16* inb, u16* outb, float* part,
                           int splitN, int outPad) {
        int Cin = cin_arr[li], Cout = cout_arr[li];
        int M = 512 * Hl * Hl;
        int logW = __builtin_ctz(Hl);
        int logHW = 2 * logW;
        size_t pstride = (size_t)M * Cout;
        if (Cout >= 128) {
            int grid = (M / 128) * (Cout / 128) * splitN;
            conv_gemm<128><<<grid, 256, 0, stream>>>(
                inb, wt[li], conv_b[li], outb, part, pstride,
                Hl, Cin, Cout, logHW, logW, splitN, outPad);
        } else {
            int grid = (M / 128) * (Cout / 64) * splitN;
            conv_gemm<64><<<grid, 256, 0, stream>>>(
                inb, wt[li], conv_b[li], outb, part, pstride,
                Hl, Cin, Cout, logHW, logW, splitN, outPad);
        }
        if (splitN > 1) {
            int MN = M * Cout;
            reduce_split<<<(MN / 4 + 255) / 256, 256, 0, stream>>>(
                part, conv_b[li], outb, MN, Cout, __builtin_ctz(Cout),
                splitN, pstride, Hl, logHW, logW, outPad);
        }
    };
    auto launch_pool = [&](int Hout, int C, u16* inb, u16* outb, int outPad) {
        int total = 512 * Hout * Hout * C;
        pool2<<<(total + 255) / 256, 256, 0, stream>>>(inb, outb, Hout, C, total, outPad);
    };

    // conv0 -> R0 padded 34^2,64
    zh(R0, 34, 64);
    conv0_kernel<<<512 * 8, 256, 0, stream>>>(x, conv_w[0], conv_b[0], R0);

    launch_conv(1, 32, R0, R1, nullptr, 1, 0);     // L1 -> R1 unpad
    zh(R0, 18, 64);
    launch_pool(16, 64, R1, R0, 1);                // P1 -> R0 pad
    zh(R1, 18, 128);
    launch_conv(2, 16, R0, R1, nullptr, 1, 1);     // L2 -> R1 pad
    launch_conv(3, 16, R1, R0, nullptr, 1, 0);     // L3 -> R0 unpad
    zh(R1, 10, 128);
    launch_pool(8, 128, R0, R1, 1);                // P2 -> R1 pad
    zh(R0, 10, 256);
    launch_conv(4, 8, R1, R0, nullptr, 1, 1);      // L4 -> R0 pad
    zh(R1, 10, 256);
    launch_conv(5, 8, R0, R1, nullptr, 1, 1);      // L5 -> R1 pad
    launch_conv(6, 8, R1, R0, nullptr, 1, 0);      // L6 -> R0 unpad
    zh(R1, 6, 256);
    launch_pool(4, 256, R0, R1, 1);                // P3 -> R1 pad
    zh(R0, 6, 512);
    launch_conv(7, 4, R1, R0, PA, 2, 1);           // L7 -> R0 pad
    zh(R1, 6, 512);
    launch_conv(8, 4, R0, R1, PB, 2, 1);           // L8 -> R1 pad
    launch_conv(9, 4, R1, R0, PA, 2, 0);           // L9 -> R0 unpad
    zh(R1, 4, 512);
    launch_pool(2, 512, R0, R1, 1);                // P4 -> R1 pad
    zh(R0, 4, 512);
    launch_conv(10, 2, R1, R0, PA, 8, 1);          // L10 -> R0 pad
    zh(R1, 4, 512);
    launch_conv(11, 2, R0, R1, PB, 8, 1);          // L11 -> R1 pad
    launch_conv(12, 2, R1, R0, PA, 8, 0);          // L12 -> R0 unpad
    launch_pool(1, 512, R0, R1, 0);                // P5 -> R1 = feat [512,512]

    gemm64<true, true><<<(512 / 64) * (256 / 64), 256, 0, stream>>>(
        R1, wtl1, lin1_b, hbuf, 512, 256, 512);
    gemm64<false, false><<<(512 / 64) * (128 / 64), 256, 0, stream>>>(
        hbuf, wtl2, lin2_b, lowbuf, 512, 128, 256);
    graph_tile<<<64, 256, 0, stream>>>(lowbuf, target, out + 5120, out + 5120 + 262144);
    cls_kernel<<<128, 256, 0, stream>>>(R1, cls_w, cls_b, out);
}

// Round 7
// 923.064 us; speedup vs baseline: 1.3781x; 1.0558x over previous
//
#include <hip/hip_runtime.h>

typedef unsigned short u16;
typedef __bf16 bf16x8 __attribute__((ext_vector_type(8)));
typedef float floatx4 __attribute__((ext_vector_type(4)));

__device__ inline u16 f2bf(float f) {
    unsigned int u = __float_as_uint(f);
    unsigned int r = (u + 0x7FFFu + ((u >> 16) & 1u)) >> 16;
    return (u16)r;
}
__device__ inline float bf2f(u16 h) {
    return __uint_as_float(((unsigned int)h) << 16);
}

// async global->LDS, 16B per lane. LDS dest must be wave-uniform base + lane*16.
__device__ __forceinline__ void async_copy16(u16* lds, const u16* g) {
    __builtin_amdgcn_global_load_lds(
        (const __attribute__((address_space(1))) unsigned int*)(uintptr_t)g,
        (__attribute__((address_space(3))) unsigned int*)(unsigned int)(uintptr_t)lds,
        16, 0, 0);
}

// ---------------------------------------------------------------------------
// zero the 1-px halo of a padded NHWC buffer [512][Hp][Hp][C]
// ---------------------------------------------------------------------------
__global__ void zero_halo(u16* __restrict__ buf, int Hp, int C, int total8)
{
    int i = blockIdx.x * 256 + threadIdx.x;
    if (i >= total8) return;
    int c8 = i % (C / 8);
    int p  = i / (C / 8);
    int x  = p % Hp; p /= Hp;
    int y  = p % Hp;
    int b  = p / Hp;
    if (y == 0 || y == Hp - 1 || x == 0 || x == Hp - 1) {
        uint4 z = make_uint4(0u, 0u, 0u, 0u);
        *(uint4*)(buf + ((size_t)((b * Hp + y) * Hp + x) * C) + c8 * 8) = z;
    }
}

// ---------------------------------------------------------------------------
// Layer 0: direct conv 3->64, 32x32, output PADDED NHWC [512][34][34][64]
// ---------------------------------------------------------------------------
__global__ __launch_bounds__(256) void conv0_kernel(
    const float* __restrict__ x, const float* __restrict__ w,
    const float* __restrict__ bias, u16* __restrict__ out)
{
    __shared__ __align__(16) float xs[3][6][36];
    const int t  = threadIdx.x;
    const int b  = blockIdx.x >> 3;
    const int y0 = (blockIdx.x & 7) * 4;

    for (int i = t; i < 3 * 6 * 36; i += 256) {
        int ci  = i / 216;
        int rem = i % 216;
        int r   = rem / 36;
        int c   = rem % 36;
        int gy  = y0 - 1 + r;
        int gx  = c - 1;
        float v = 0.f;
        if ((unsigned)gy < 32u && (unsigned)gx < 32u)
            v = x[((b * 3 + ci) * 32 + gy) * 32 + gx];
        xs[ci][r][c] = v;
    }
    const int lane = t & 63;
    const int wv   = t >> 6;
    float wr[27];
    #pragma unroll
    for (int k = 0; k < 27; k++) wr[k] = w[lane * 27 + k];
    const float bz = bias[lane];
    __syncthreads();

    const int y = y0 + wv;
    u16* orow = out + ((size_t)((b * 34 + y + 1) * 34 + 1) * 64) + lane;
    for (int xg = 0; xg < 32; xg += 4) {
        float a0 = bz, a1 = bz, a2 = bz, a3 = bz;
        #pragma unroll
        for (int ci = 0; ci < 3; ci++) {
            #pragma unroll
            for (int rr = 0; rr < 3; rr++) {
                const float* row = &xs[ci][wv + rr][0];
                float4 c03 = *(const float4*)(row + xg);
                float2 c45 = *(const float2*)(row + xg + 4);
                float w0 = wr[ci * 9 + rr * 3 + 0];
                float w1 = wr[ci * 9 + rr * 3 + 1];
                float w2 = wr[ci * 9 + rr * 3 + 2];
                a0 += c03.x * w0 + c03.y * w1 + c03.z * w2;
                a1 += c03.y * w0 + c03.z * w1 + c03.w * w2;
                a2 += c03.z * w0 + c03.w * w1 + c45.x * w2;
                a3 += c03.w * w0 + c45.x * w1 + c45.y * w2;
            }
        }
        orow[(xg + 0) * 64] = f2bf(fmaxf(a0, 0.f));
        orow[(xg + 1) * 64] = f2bf(fmaxf(a1, 0.f));
        orow[(xg + 2) * 64] = f2bf(fmaxf(a2, 0.f));
        orow[(xg + 3) * 64] = f2bf(fmaxf(a3, 0.f));
    }
}

// ---------------------------------------------------------------------------
__global__ void repack_w(const float* __restrict__ w, u16* __restrict__ wt,
                         int Cin, int total)
{
    int i = blockIdx.x * 256 + threadIdx.x;
    if (i >= total) return;
    int ci = i % Cin;
    int rest = i / Cin;
    int s = rest % 9;
    int co = rest / 9;
    wt[i] = f2bf(w[(co * Cin + ci) * 9 + s]);
}

__global__ void repack_lin(const float* __restrict__ w, u16* __restrict__ wt,
                           int K, int N, int total)
{
    int i = blockIdx.x * 256 + threadIdx.x;
    if (i >= total) return;
    int n = i % N, k = i / N;
    wt[(size_t)n * K + k] = f2bf(w[(size_t)k * N + n]);
}

// ---------------------------------------------------------------------------
// Conv shift-GEMM, bf16 MFMA 16x16x32. Padded input, global_load_lds staging
// with XOR-8 swizzle applied via the GLOBAL source permutation:
// thread (r0,col8) DMAs logical chunk (col8^(r0&7)) -> LDS slot col8.
// Fragment reads use slot cb^(l16&7): conflict-free (2-way max).
// ---------------------------------------------------------------------------
template <int BN>
__global__ __launch_bounds__(256) void conv_gemm(
    const u16* __restrict__ in, const u16* __restrict__ wt,
    const float* __restrict__ bias, u16* __restrict__ out,
    float* __restrict__ partial, size_t pstride,
    int H, int Cin, int Cout, int logHW, int logW, int splitN, int outPad)
{
    constexpr int BM = 128, BK = 64;
    constexpr int NT   = BN / 32;
    constexpr int NB_A = 4;
    constexpr int NB_B = BN / 32;
    __shared__ u16 As[BM * BK];
    __shared__ u16 Bs[BN * BK];

    const int Nblocks = Cout / BN;
    const int bid  = blockIdx.x;
    const int sp   = bid % splitN;
    const int tile = bid / splitN;
    const int m0 = (tile / Nblocks) * BM;
    const int n0 = (tile % Nblocks) * BN;

    const int t    = threadIdx.x;
    const int lane = t & 63;
    const int wave = t >> 6;
    const int quad = lane >> 4;
    const int l16  = lane & 15;
    const int wm   = wave >> 1;
    const int wn   = wave & 1;
    const int W    = H;
    const int Wp   = H + 2;
    const int HW   = 1 << logHW;
    const int col8 = t & 7;
    const int r0   = t >> 3;
    const int scol = col8 ^ (r0 & 7);     // swizzled source chunk

    // per-thread global base pointers (center tap, kb=0), swizzled channel chunk
    const u16* pA[NB_A];
    #pragma unroll
    for (int j = 0; j < NB_A; j++) {
        int m  = m0 + r0 + 32 * j;
        int b  = m >> logHW;
        int rm = m & (HW - 1);
        int y  = rm >> logW;
        int xx = rm & (W - 1);
        pA[j] = in + ((size_t)((b * Wp + y + 1) * Wp + xx + 1) * Cin + scol * 8);
    }
    const u16* pB[NB_B];
    #pragma unroll
    for (int j = 0; j < NB_B; j++)
        pB[j] = wt + ((size_t)(n0 + r0 + 32 * j) * 9 * Cin + scol * 8);

    const int logKB = (Cin == 64) ? 0 : (Cin == 128) ? 1 : (Cin == 256) ? 2 : 3;
    const int KB  = 1 << logKB;
    const int T   = 9 * KB;
    const int len = T / splitN;
    const int it0 = sp * len;

    u16* const ldsA = As + t * 8;     // lane-linear dest: t*16 bytes
    u16* const ldsB = Bs + t * 8;

    floatx4 acc[4][NT];
    #pragma unroll
    for (int i = 0; i < 4; i++)
        #pragma unroll
        for (int j = 0; j < NT; j++)
            acc[i][j] = (floatx4){0.f, 0.f, 0.f, 0.f};

    const int sw = (l16 & 7) * 8;     // read-side swizzle offset (u16 units)

    for (int it = 0; it < len; it++) {
        const int ia = it0 + it;
        const int s  = ia >> logKB;
        const int kb = (ia & (KB - 1)) << 6;
        const int dy = s / 3 - 1;
        const int dx = s % 3 - 1;
        const int ta = (dy * Wp + dx) * Cin + kb;
        const int tb = ia << 6;
        #pragma unroll
        for (int j = 0; j < NB_A; j++)
            async_copy16(ldsA + j * 2048, pA[j] + ta);
        #pragma unroll
        for (int j = 0; j < NB_B; j++)
            async_copy16(ldsB + j * 2048, pB[j] + tb);
        __syncthreads();
        #pragma unroll
        for (int kk = 0; kk < BK; kk += 32) {
            bf16x8 af[4], bfv[NT];
            int cbo = kk + quad * 8;
            #pragma unroll
            for (int mt = 0; mt < 4; mt++)
                af[mt] = *(const bf16x8*)(As + (wm * 64 + mt * 16 + l16) * 64 + (cbo ^ sw));
            #pragma unroll
            for (int nt = 0; nt < NT; nt++)
                bfv[nt] = *(const bf16x8*)(Bs + (wn * (BN / 2) + nt * 16 + l16) * 64 + (cbo ^ sw));
            #pragma unroll
            for (int mt = 0; mt < 4; mt++)
                #pragma unroll
                for (int nt = 0; nt < NT; nt++)
                    acc[mt][nt] = __builtin_amdgcn_mfma_f32_16x16x32_bf16(
                        af[mt], bfv[nt], acc[mt][nt], 0, 0, 0);
        }
        __syncthreads();
    }

    if (splitN > 1) {
        float* pout = partial + (size_t)sp * pstride;
        #pragma unroll
        for (int mt = 0; mt < 4; mt++)
            #pragma unroll
            for (int nt = 0; nt < NT; nt++)
                #pragma unroll
                for (int r = 0; r < 4; r++) {
                    int mg = m0 + wm * 64 + mt * 16 + quad * 4 + r;
                    int ng = n0 + wn * (BN / 2) + nt * 16 + l16;
                    pout[(size_t)mg * Cout + ng] = acc[mt][nt][r];
                }
        return;
    }
    #pragma unroll
    for (int mt = 0; mt < 4; mt++) {
        #pragma unroll
        for (int r = 0; r < 4; r++) {
            int mg = m0 + wm * 64 + mt * 16 + quad * 4 + r;
            size_t obase;
            if (outPad) {
                int b  = mg >> logHW;
                int rm = mg & (HW - 1);
                int y  = rm >> logW;
                int xx = rm & (W - 1);
                obase = (size_t)((b * Wp + y + 1) * Wp + xx + 1) * Cout;
            } else {
                obase = (size_t)mg * Cout;
            }
            #pragma unroll
            for (int nt = 0; nt < NT; nt++) {
                int ng = n0 + wn * (BN / 2) + nt * 16 + l16;
                float v = acc[mt][nt][r] + bias[ng];
                out[obase + ng] = f2bf(fmaxf(v, 0.f));
            }
        }
    }
}

// sum split partials + bias + relu -> bf16 NHWC (padded out optional)
__global__ void reduce_split(const float* __restrict__ partial,
                             const float* __restrict__ bias, u16* __restrict__ out,
                             int MN, int C, int logC, int splitN, size_t pstride,
                             int H, int logHW, int logW, int outPad)
{
    int i4 = (blockIdx.x * 256 + threadIdx.x) * 4;
    if (i4 >= MN) return;
    float4 s = *(const float4*)(partial + i4);
    for (int sp = 1; sp < splitN; sp++) {
        float4 p = *(const float4*)(partial + (size_t)sp * pstride + i4);
        s.x += p.x; s.y += p.y; s.z += p.z; s.w += p.w;
    }
    int n = i4 & (C - 1);
    int m = i4 >> logC;
    size_t obase;
    if (outPad) {
        int Wp = H + 2;
        int b  = m >> logHW;
        int rm = m & ((1 << logHW) - 1);
        int y  = rm >> logW;
        int xx = rm & (H - 1);
        obase = (size_t)((b * Wp + y + 1) * Wp + xx + 1) * C;
    } else {
        obase = (size_t)m * C;
    }
    ushort4 o;
    o.x = f2bf(fmaxf(s.x + bias[n + 0], 0.f));
    o.y = f2bf(fmaxf(s.y + bias[n + 1], 0.f));
    o.z = f2bf(fmaxf(s.z + bias[n + 2], 0.f));
    o.w = f2bf(fmaxf(s.w + bias[n + 3], 0.f));
    *(ushort4*)(out + obase + n) = o;
}

// ---------------------------------------------------------------------------
// 2x2 maxpool, NHWC bf16. Input UNPADDED; output padded optional.
// ---------------------------------------------------------------------------
__global__ void pool2(const u16* __restrict__ in, u16* __restrict__ out,
                      int Hout, int C, int total, int outPad)
{
    int i = blockIdx.x * 256 + threadIdx.x;
    if (i >= total) return;
    int c = i % C;
    int rest = i / C;
    int x = rest % Hout; rest /= Hout;
    int y = rest % Hout;
    int b = rest / Hout;
    int Hin = Hout * 2;
    const u16* p = in + ((size_t)((b * Hin + 2 * y) * Hin + 2 * x) * C + c);
    float v0 = bf2f(p[0]);
    float v1 = bf2f(p[C]);
    float v2 = bf2f(p[(size_t)Hin * C]);
    float v3 = bf2f(p[(size_t)Hin * C + C]);
    size_t oidx;
    if (outPad) {
        int Hp = Hout + 2;
        oidx = (size_t)((b * Hp + y + 1) * Hp + x + 1) * C + c;
    } else {
        oidx = (size_t)i;
    }
    out[oidx] = f2bf(fmaxf(fmaxf(v0, v1), fmaxf(v2, v3)));
}

// ---------------------------------------------------------------------------
// Generic small GEMM: out[M,N] = act(A[M,K](bf16) @ Bt[N,K](bf16)^T + bias)
// ---------------------------------------------------------------------------
template <bool RELU, bool OUTBF>
__global__ __launch_bounds__(256) void gemm64(
    const u16* __restrict__ A, const u16* __restrict__ Bt,
    const float* __restrict__ bias, void* __restrict__ outv,
    int M, int N, int K)
{
    constexpr int LDP = 72;
    __shared__ u16 As[64 * LDP];
    __shared__ u16 Bs[64 * LDP];

    const int nb = N >> 6;
    const int m0 = (blockIdx.x / nb) * 64;
    const int n0 = (blockIdx.x % nb) * 64;
    const int t = threadIdx.x, lane = t & 63, wave = t >> 6;
    const int quad = lane >> 4, l16 = lane & 15;
    const int wm = wave >> 1, wn = wave & 1;
    const int col8 = t & 7, r0 = t >> 3;

    floatx4 acc[2][2];
    #pragma unroll
    for (int i = 0; i < 2; i++)
        #pragma unroll
        for (int j = 0; j < 2; j++)
            acc[i][j] = (floatx4){0.f, 0.f, 0.f, 0.f};

    for (int kb = 0; kb < K; kb += 64) {
        #pragma unroll
        for (int j = 0; j < 2; j++) {
            int row = r0 + 32 * j;
            *(uint4*)(As + row * LDP + col8 * 8) =
                *(const uint4*)(A + (size_t)(m0 + row) * K + kb + col8 * 8);
            *(uint4*)(Bs + row * LDP + col8 * 8) =
                *(const uint4*)(Bt + (size_t)(n0 + row) * K + kb + col8 * 8);
        }
        __syncthreads();
        #pragma unroll
        for (int kk = 0; kk < 64; kk += 32) {
            bf16x8 af[2], bfv[2];
            #pragma unroll
            for (int mt = 0; mt < 2; mt++)
                af[mt] = *(const bf16x8*)(As + (wm * 32 + mt * 16 + l16) * LDP + kk + quad * 8);
            #pragma unroll
            for (int nt = 0; nt < 2; nt++)
                bfv[nt] = *(const bf16x8*)(Bs + (wn * 32 + nt * 16 + l16) * LDP + kk + quad * 8);
            #pragma unroll
            for (int mt = 0; mt < 2; mt++)
                #pragma unroll
                for (int nt = 0; nt < 2; nt++)
                    acc[mt][nt] = __builtin_amdgcn_mfma_f32_16x16x32_bf16(
                        af[mt], bfv[nt], acc[mt][nt], 0, 0, 0);
        }
        __syncthreads();
    }
    #pragma unroll
    for (int mt = 0; mt < 2; mt++) {
        #pragma unroll
        for (int nt = 0; nt < 2; nt++) {
            #pragma unroll
            for (int r = 0; r < 4; r++) {
                int mg = m0 + wm * 32 + mt * 16 + quad * 4 + r;
                int ng = n0 + wn * 32 + nt * 16 + l16;
                float v = acc[mt][nt][r] + bias[ng];
                if (RELU) v = fmaxf(v, 0.f);
                if (OUTBF) ((u16*)outv)[(size_t)mg * N + ng] = f2bf(v);
                else       ((float*)outv)[(size_t)mg * N + ng] = v;
            }
        }
    }
}

// ---------------------------------------------------------------------------
__global__ __launch_bounds__(256) void graph_tile(
    const float* __restrict__ low, const int* __restrict__ target,
    float* __restrict__ gpre, float* __restrict__ ggt)
{
    __shared__ float Al[64 * 132];
    __shared__ float Bl[128 * 68];
    const int t = threadIdx.x;
    const int gr0 = (blockIdx.x >> 3) * 64;
    const int gc0 = (blockIdx.x & 7) * 64;

    #pragma unroll
    for (int j = 0; j < 32; j++) {
        int flat = t + 256 * j;
        int k = flat & 127;
        int rc = flat >> 7;
        Al[rc * 132 + k] = low[(size_t)(gr0 + rc) * 128 + k];
        Bl[k * 68 + rc]  = low[(size_t)(gc0 + rc) * 128 + k];
    }
    __syncthreads();

    const int tx = t & 15, ty = t >> 4;
    float acc[4][4];
    #pragma unroll
    for (int r = 0; r < 4; r++)
        #pragma unroll
        for (int c = 0; c < 4; c++) acc[r][c] = 0.f;

    for (int k = 0; k < 128; k++) {
        float a[4], b[4];
        #pragma unroll
        for (int r = 0; r < 4; r++) a[r] = Al[(ty * 4 + r) * 132 + k];
        #pragma unroll
        for (int c = 0; c < 4; c++) b[c] = Bl[k * 68 + tx * 4 + c];
        #pragma unroll
        for (int r = 0; r < 4; r++)
            #pragma unroll
            for (int c = 0; c < 4; c++) acc[r][c] += a[r] * b[c];
    }
    #pragma unroll
    for (int r = 0; r < 4; r++) {
        int row = gr0 + ty * 4 + r;
        int tr  = target[row];
        float4 gp, gg;
        float* pp = (float*)&gp;
        float* gg_ = (float*)&gg;
        #pragma unroll
        for (int c = 0; c < 4; c++) {
            pp[c]  = 1.f / (1.f + __expf(-acc[r][c]));
            gg_[c] = (tr == target[gc0 + tx * 4 + c]) ? 1.f : 0.f;
        }
        *(float4*)(gpre + (size_t)row * 512 + gc0 + tx * 4) = gp;
        *(float4*)(ggt  + (size_t)row * 512 + gc0 + tx * 4) = gg;
    }
}

// ---------------------------------------------------------------------------
__global__ __launch_bounds__(256) void cls_kernel(
    const u16* __restrict__ feat, const float* __restrict__ w,
    const float* __restrict__ bias, float* __restrict__ out)
{
    __shared__ float ws[5120];
    const int t = threadIdx.x;
    for (int i = t; i < 5120; i += 256) ws[i] = w[i];
    __syncthreads();
    const int lane = t & 63;
    const int row  = blockIdx.x * 4 + (t >> 6);
    float a[10];
    #pragma unroll
    for (int j = 0; j < 10; j++) a[j] = 0.f;
    #pragma unroll
    for (int i = 0; i < 8; i++) {
        int k = i * 64 + lane;
        float f = bf2f(feat[(size_t)row * 512 + k]);
        #pragma unroll
        for (int j = 0; j < 10; j++) a[j] += f * ws[k * 10 + j];
    }
    #pragma unroll
    for (int j = 0; j < 10; j++)
        #pragma unroll
        for (int off = 32; off > 0; off >>= 1)
            a[j] += __shfl_down(a[j], off, 64);
    if (lane == 0) {
        #pragma unroll
        for (int j = 0; j < 10; j++) out[row * 10 + j] = a[j] + bias[j];
    }
}

// ---------------------------------------------------------------------------
extern "C" void kernel_launch(void* const* d_in, const int* in_sizes, int n_in,
                              void* d_out, int out_size, void* d_ws, size_t ws_size,
                              hipStream_t stream)
{
    const float* x      = (const float*)d_in[0];
    const int*   target = (const int*)d_in[1];
    const float* conv_w[13];
    const float* conv_b[13];
    for (int i = 0; i < 13; i++) {
        conv_w[i] = (const float*)d_in[2 + 2 * i];
        conv_b[i] = (const float*)d_in[3 + 2 * i];
    }
    const float* lin1_w = (const float*)d_in[28];
    const float* lin1_b = (const float*)d_in[29];
    const float* lin2_w = (const float*)d_in[30];
    const float* lin2_b = (const float*)d_in[31];
    const float* cls_w  = (const float*)d_in[32];
    const float* cls_b  = (const float*)d_in[33];
    float* out = (float*)d_out;

    static const int cin_arr[13]  = {3, 64, 64, 128, 128, 256, 256, 256, 512, 512, 512, 512, 512};
    static const int cout_arr[13] = {64, 64, 128, 128, 256, 256, 256, 512, 512, 512, 512, 512, 512};

    char* ws = (char*)d_ws;
    size_t off = 0;
    const size_t R0SZ = (size_t)512 * 34 * 34 * 64 * 2;
    const size_t R1SZ = (size_t)512 * 32 * 32 * 64 * 2;
    char* R0raw = ws + off; off += R0SZ;
    char* R1raw = ws + off; off += R1SZ;
    u16* R0 = (u16*)R0raw;
    u16* R1 = (u16*)R1raw;
    float* PA = (float*)(R0raw + 20971520);
    float* PB = (float*)(R1raw + 20971520);
    u16* wt[13];
    for (int i = 1; i < 13; i++) {
        wt[i] = (u16*)(ws + off);
        off += (size_t)cout_arr[i] * 9 * cin_arr[i] * 2;
    }
    u16* wtl1 = (u16*)(ws + off); off += (size_t)256 * 512 * 2;
    u16* wtl2 = (u16*)(ws + off); off += (size_t)128 * 256 * 2;
    u16* hbuf = (u16*)(ws + off); off += (size_t)512 * 256 * 2;
    float* lowbuf = (float*)(ws + off); off += (size_t)512 * 128 * 4;

    for (int i = 1; i < 13; i++) {
        int total = cout_arr[i] * 9 * cin_arr[i];
        repack_w<<<(total + 255) / 256, 256, 0, stream>>>(conv_w[i], wt[i], cin_arr[i], total);
    }
    repack_lin<<<(512 * 256) / 256, 256, 0, stream>>>(lin1_w, wtl1, 512, 256, 512 * 256);
    repack_lin<<<(256 * 128) / 256, 256, 0, stream>>>(lin2_w, wtl2, 256, 128, 256 * 128);

    auto zh = [&](u16* buf, int Hp, int C) {
        int total8 = 512 * Hp * Hp * (C / 8);
        zero_halo<<<(total8 + 255) / 256, 256, 0, stream>>>(buf, Hp, C, total8);
    };
    auto launch_conv = [&](int li, int Hl, u16* inb, u16* outb, float* part,
                           int splitN, int outPad) {
        int Cin = cin_arr[li], Cout = cout_arr[li];
        int M = 512 * Hl * Hl;
        int logW = __builtin_ctz(Hl);
        int logHW = 2 * logW;
        size_t pstride = (size_t)M * Cout;
        if (Cout >= 128) {
            int grid = (M / 128) * (Cout / 128) * splitN;
            conv_gemm<128><<<grid, 256, 0, stream>>>(
                inb, wt[li], conv_b[li], outb, part, pstride,
                Hl, Cin, Cout, logHW, logW, splitN, outPad);
        } else {
            int grid = (M / 128) * (Cout / 64) * splitN;
            conv_gemm<64><<<grid, 256, 0, stream>>>(
                inb, wt[li], conv_b[li], outb, part, pstride,
                Hl, Cin, Cout, logHW, logW, splitN, outPad);
        }
        if (splitN > 1) {
            int MN = M * Cout;
            reduce_split<<<(MN / 4 + 255) / 256, 256, 0, stream>>>(
                part, conv_b[li], outb, MN, Cout, __builtin_ctz(Cout),
                splitN, pstride, Hl, logHW, logW, outPad);
        }
    };
    auto launch_pool = [&](int Hout, int C, u16* inb, u16* outb, int outPad) {
        int total = 512 * Hout * Hout * C;
        pool2<<<(total + 255) / 256, 256, 0, stream>>>(inb, outb, Hout, C, total, outPad);
    };

    zh(R0, 34, 64);
    conv0_kernel<<<512 * 8, 256, 0, stream>>>(x, conv_w[0], conv_b[0], R0);

    launch_conv(1, 32, R0, R1, nullptr, 1, 0);
    zh(R0, 18, 64);
    launch_pool(16, 64, R1, R0, 1);
    zh(R1, 18, 128);
    launch_conv(2, 16, R0, R1, nullptr, 1, 1);
    launch_conv(3, 16, R1, R0, nullptr, 1, 0);
    zh(R1, 10, 128);
    launch_pool(8, 128, R0, R1, 1);
    zh(R0, 10, 256);
    launch_conv(4, 8, R1, R0, nullptr, 1, 1);
    zh(R1, 10, 256);
    launch_conv(5, 8, R0, R1, nullptr, 1, 1);
    launch_conv(6, 8, R1, R0, nullptr, 1, 0);
    zh(R1, 6, 256);
    launch_pool(4, 256, R0, R1, 1);
    zh(R0, 6, 512);
    launch_conv(7, 4, R1, R0, PA, 2, 1);
    zh(R1, 6, 512);
    launch_conv(8, 4, R0, R1, PB, 2, 1);
    launch_conv(9, 4, R1, R0, PA, 2, 0);
    zh(R1, 4, 512);
    launch_pool(2, 512, R0, R1, 1);
    zh(R0, 4, 512);
    launch_conv(10, 2, R1, R0, PA, 8, 1);
    zh(R1, 4, 512);
    launch_conv(11, 2, R0, R1, PB, 8, 1);
    launch_conv(12, 2, R1, R0, PA, 8, 0);
    launch_pool(1, 512, R0, R1, 0);

    gemm64<true, true><<<(512 / 64) * (256 / 64), 256, 0, stream>>>(
        R1, wtl1, lin1_b, hbuf, 512, 256, 512);
    gemm64<false, false><<<(512 / 64) * (128 / 64), 256, 0, stream>>>(
        hbuf, wtl2, lin2_b, lowbuf, 512, 128, 256);
    graph_tile<<<64, 256, 0, stream>>>(lowbuf, target, out + 5120, out + 5120 + 262144);
    cls_kernel<<<128, 256, 0, stream>>>(R1, cls_w, cls_b, out);
}

// Round 8
// 865.418 us; speedup vs baseline: 1.4699x; 1.0666x over previous
//
#include <hip/hip_runtime.h>

typedef unsigned short u16;
typedef __bf16 bf16x8 __attribute__((ext_vector_type(8)));
typedef float floatx4 __attribute__((ext_vector_type(4)));

__device__ inline u16 f2bf(float f) {
    unsigned int u = __float_as_uint(f);
    unsigned int r = (u + 0x7FFFu + ((u >> 16) & 1u)) >> 16;
    return (u16)r;
}
__device__ inline float bf2f(u16 h) {
    return __uint_as_float(((unsigned int)h) << 16);
}

// async global->LDS, 16B per lane. LDS dest must be wave-uniform base + lane*16.
__device__ __forceinline__ void async_copy16(u16* lds, const u16* g) {
    __builtin_amdgcn_global_load_lds(
        (const __attribute__((address_space(1))) unsigned int*)(uintptr_t)g,
        (__attribute__((address_space(3))) unsigned int*)(unsigned int)(uintptr_t)lds,
        16, 0, 0);
}

// ---------------------------------------------------------------------------
// zero the 1-px halo of a padded NHWC buffer [512][Hp][Hp][C]
// ---------------------------------------------------------------------------
__global__ void zero_halo(u16* __restrict__ buf, int Hp, int C, int total8)
{
    int i = blockIdx.x * 256 + threadIdx.x;
    if (i >= total8) return;
    int c8 = i % (C / 8);
    int p  = i / (C / 8);
    int x  = p % Hp; p /= Hp;
    int y  = p % Hp;
    int b  = p / Hp;
    if (y == 0 || y == Hp - 1 || x == 0 || x == Hp - 1) {
        uint4 z = make_uint4(0u, 0u, 0u, 0u);
        *(uint4*)(buf + ((size_t)((b * Hp + y) * Hp + x) * C) + c8 * 8) = z;
    }
}

// ---------------------------------------------------------------------------
// Layer 0: direct conv 3->64, 32x32, output PADDED NHWC [512][34][34][64]
// ---------------------------------------------------------------------------
__global__ __launch_bounds__(256) void conv0_kernel(
    const float* __restrict__ x, const float* __restrict__ w,
    const float* __restrict__ bias, u16* __restrict__ out)
{
    __shared__ __align__(16) float xs[3][6][36];
    const int t  = threadIdx.x;
    const int b  = blockIdx.x >> 3;
    const int y0 = (blockIdx.x & 7) * 4;

    for (int i = t; i < 3 * 6 * 36; i += 256) {
        int ci  = i / 216;
        int rem = i % 216;
        int r   = rem / 36;
        int c   = rem % 36;
        int gy  = y0 - 1 + r;
        int gx  = c - 1;
        float v = 0.f;
        if ((unsigned)gy < 32u && (unsigned)gx < 32u)
            v = x[((b * 3 + ci) * 32 + gy) * 32 + gx];
        xs[ci][r][c] = v;
    }
    const int lane = t & 63;
    const int wv   = t >> 6;
    float wr[27];
    #pragma unroll
    for (int k = 0; k < 27; k++) wr[k] = w[lane * 27 + k];
    const float bz = bias[lane];
    __syncthreads();

    const int y = y0 + wv;
    u16* orow = out + ((size_t)((b * 34 + y + 1) * 34 + 1) * 64) + lane;
    for (int xg = 0; xg < 32; xg += 4) {
        float a0 = bz, a1 = bz, a2 = bz, a3 = bz;
        #pragma unroll
        for (int ci = 0; ci < 3; ci++) {
            #pragma unroll
            for (int rr = 0; rr < 3; rr++) {
                const float* row = &xs[ci][wv + rr][0];
                float4 c03 = *(const float4*)(row + xg);
                float2 c45 = *(const float2*)(row + xg + 4);
                float w0 = wr[ci * 9 + rr * 3 + 0];
                float w1 = wr[ci * 9 + rr * 3 + 1];
                float w2 = wr[ci * 9 + rr * 3 + 2];
                a0 += c03.x * w0 + c03.y * w1 + c03.z * w2;
                a1 += c03.y * w0 + c03.z * w1 + c03.w * w2;
                a2 += c03.z * w0 + c03.w * w1 + c45.x * w2;
                a3 += c03.w * w0 + c45.x * w1 + c45.y * w2;
            }
        }
        orow[(xg + 0) * 64] = f2bf(fmaxf(a0, 0.f));
        orow[(xg + 1) * 64] = f2bf(fmaxf(a1, 0.f));
        orow[(xg + 2) * 64] = f2bf(fmaxf(a2, 0.f));
        orow[(xg + 3) * 64] = f2bf(fmaxf(a3, 0.f));
    }
}

// ---------------------------------------------------------------------------
__global__ void repack_w(const float* __restrict__ w, u16* __restrict__ wt,
                         int Cin, int total)
{
    int i = blockIdx.x * 256 + threadIdx.x;
    if (i >= total) return;
    int ci = i % Cin;
    int rest = i / Cin;
    int s = rest % 9;
    int co = rest / 9;
    wt[i] = f2bf(w[(co * Cin + ci) * 9 + s]);
}

__global__ void repack_lin(const float* __restrict__ w, u16* __restrict__ wt,
                           int K, int N, int total)
{
    int i = blockIdx.x * 256 + threadIdx.x;
    if (i >= total) return;
    int n = i % N, k = i / N;
    wt[(size_t)n * K + k] = f2bf(w[(size_t)k * N + n]);
}

// ---------------------------------------------------------------------------
// Conv shift-GEMM, bf16 MFMA 16x16x32. Padded input, global_load_lds staging
// with XOR-8 swizzle via the global source permutation. Tap/channel offsets
// advanced incrementally (wave-uniform SALU; per-iter VALU = 1 add per DMA).
// poolMode=1: fused 2x2 maxpool epilogue writing pooled padded output.
// ---------------------------------------------------------------------------
template <int BN>
__global__ __launch_bounds__(256) void conv_gemm(
    const u16* __restrict__ in, const u16* __restrict__ wt,
    const float* __restrict__ bias, u16* __restrict__ out,
    float* __restrict__ partial, size_t pstride,
    int H, int Cin, int Cout, int logHW, int logW, int splitN,
    int outPad, int poolMode)
{
    constexpr int BM = 128, BK = 64;
    constexpr int NT   = BN / 32;
    constexpr int NB_A = 4;
    constexpr int NB_B = BN / 32;
    __shared__ u16 As[BM * BK];
    __shared__ u16 Bs[BN * BK];

    const int Nblocks = Cout / BN;
    const int bid  = blockIdx.x;
    const int sp   = bid % splitN;
    const int tile = bid / splitN;
    const int m0 = (tile / Nblocks) * BM;
    const int n0 = (tile % Nblocks) * BN;

    const int t    = threadIdx.x;
    const int lane = t & 63;
    const int wave = t >> 6;
    const int quad = lane >> 4;
    const int l16  = lane & 15;
    const int wm   = wave >> 1;
    const int wn   = wave & 1;
    const int W    = H;
    const int Wp   = H + 2;
    const int HW   = 1 << logHW;
    const int col8 = t & 7;
    const int r0   = t >> 3;
    const int scol = col8 ^ (r0 & 7);

    const int CinB = Cin * 2;           // bytes per pixel's channel row

    // invariant per-thread byte offsets (center tap, kb=0)
    int vA[NB_A];
    #pragma unroll
    for (int j = 0; j < NB_A; j++) {
        int m  = m0 + r0 + 32 * j;
        int b  = m >> logHW;
        int rm = m & (HW - 1);
        int y  = rm >> logW;
        int xx = rm & (W - 1);
        vA[j] = ((b * Wp + y + 1) * Wp + xx + 1) * CinB + scol * 16;
    }
    int vB[NB_B];
    #pragma unroll
    for (int j = 0; j < NB_B; j++)
        vB[j] = (n0 + r0 + 32 * j) * 9 * CinB + scol * 16;

    const int logKB = (Cin == 64) ? 0 : (Cin == 128) ? 1 : (Cin == 256) ? 2 : 3;
    const int KB  = 1 << logKB;
    const int T   = 9 * KB;
    const int len = T / splitN;
    const int it0 = sp * len;

    // incremental uniform offsets (bytes)
    int s0 = it0 >> logKB;
    int c3 = s0 - (s0 / 3) * 3;                         // s0 % 3
    int ta = ((s0 / 3 - 1) * Wp + (c3 - 1)) * CinB;     // tap byte offset
    int kb = (it0 & (KB - 1)) * 128;                    // channel-block byte offset
    int tb = it0 * 128;                                 // B byte offset

    u16* const ldsA = As + t * 8;
    u16* const ldsB = Bs + t * 8;
    const char* const inB = (const char*)in;
    const char* const wtB = (const char*)wt;

    floatx4 acc[4][NT];
    #pragma unroll
    for (int i = 0; i < 4; i++)
        #pragma unroll
        for (int j = 0; j < NT; j++)
            acc[i][j] = (floatx4){0.f, 0.f, 0.f, 0.f};

    const int sw = (l16 & 7) * 8;

    for (int it = 0; it < len; it++) {
        const int ua = ta + kb;
        #pragma unroll
        for (int j = 0; j < NB_A; j++)
            async_copy16(ldsA + j * 2048, (const u16*)(inB + (ua + vA[j])));
        #pragma unroll
        for (int j = 0; j < NB_B; j++)
            async_copy16(ldsB + j * 2048, (const u16*)(wtB + (tb + vB[j])));
        __syncthreads();
        #pragma unroll
        for (int kk = 0; kk < BK; kk += 32) {
            bf16x8 af[4], bfv[NT];
            int cbo = kk + quad * 8;
            #pragma unroll
            for (int mt = 0; mt < 4; mt++)
                af[mt] = *(const bf16x8*)(As + (wm * 64 + mt * 16 + l16) * 64 + (cbo ^ sw));
            #pragma unroll
            for (int nt = 0; nt < NT; nt++)
                bfv[nt] = *(const bf16x8*)(Bs + (wn * (BN / 2) + nt * 16 + l16) * 64 + (cbo ^ sw));
            #pragma unroll
            for (int mt = 0; mt < 4; mt++)
                #pragma unroll
                for (int nt = 0; nt < NT; nt++)
                    acc[mt][nt] = __builtin_amdgcn_mfma_f32_16x16x32_bf16(
                        af[mt], bfv[nt], acc[mt][nt], 0, 0, 0);
        }
        __syncthreads();
        tb += 128;
        kb += 128;
        if (kb == CinB) {
            kb = 0;
            ta += (c3 == 2) ? (Wp - 2) * CinB : CinB;
            c3 = (c3 == 2) ? 0 : c3 + 1;
        }
    }

    if (splitN > 1) {
        float* pout = partial + (size_t)sp * pstride;
        #pragma unroll
        for (int mt = 0; mt < 4; mt++)
            #pragma unroll
            for (int nt = 0; nt < NT; nt++)
                #pragma unroll
                for (int r = 0; r < 4; r++) {
                    int mg = m0 + wm * 64 + mt * 16 + quad * 4 + r;
                    int ng = n0 + wn * (BN / 2) + nt * 16 + l16;
                    pout[(size_t)mg * Cout + ng] = acc[mt][nt][r];
                }
        return;
    }

    if (poolMode) {
        // fused 2x2 maxpool -> pooled PADDED output [B][H/2+2][H/2+2][Cout]
        const int Hpo = (H >> 1) + 2;
        #pragma unroll
        for (int nt = 0; nt < NT; nt++) {
            int ng = n0 + wn * (BN / 2) + nt * 16 + l16;
            float bz = bias[ng];
            if (logW == 5) {            // W=32: y-partner = mt+2, all in-lane
                #pragma unroll
                for (int mt = 0; mt < 2; mt++)
                    #pragma unroll
                    for (int rp = 0; rp < 2; rp++) {
                        float v = fmaxf(
                            fmaxf(acc[mt][nt][2 * rp], acc[mt][nt][2 * rp + 1]),
                            fmaxf(acc[mt + 2][nt][2 * rp], acc[mt + 2][nt][2 * rp + 1]));
                        int m1 = m0 + wm * 64 + mt * 16 + quad * 4 + 2 * rp;
                        int b  = m1 >> logHW;
                        int rm = m1 & (HW - 1);
                        int yp = (rm >> logW) >> 1;
                        int xp = (rm & (W - 1)) >> 1;
                        out[(size_t)((b * Hpo + yp + 1) * Hpo + xp + 1) * Cout + ng] =
                            f2bf(fmaxf(v + bz, 0.f));
                    }
            } else if (logW == 4) {     // W=16: y-partner = mt+1, in-lane
                #pragma unroll
                for (int mtp = 0; mtp < 2; mtp++)
                    #pragma unroll
                    for (int rp = 0; rp < 2; rp++) {
                        int mt = 2 * mtp;
                        float v = fmaxf(
                            fmaxf(acc[mt][nt][2 * rp], acc[mt][nt][2 * rp + 1]),
                            fmaxf(acc[mt + 1][nt][2 * rp], acc[mt + 1][nt][2 * rp + 1]));
                        int m1 = m0 + wm * 64 + mt * 16 + quad * 4 + 2 * rp;
                        int b  = m1 >> logHW;
                        int rm = m1 & (HW - 1);
                        int yp = (rm >> logW) >> 1;
                        int xp = (rm & (W - 1)) >> 1;
                        out[(size_t)((b * Hpo + yp + 1) * Hpo + xp + 1) * Cout + ng] =
                            f2bf(fmaxf(v + bz, 0.f));
                    }
            } else {                    // W=8: y-partner = quad+2 via shfl
                #pragma unroll
                for (int mt = 0; mt < 4; mt++)
                    #pragma unroll
                    for (int rp = 0; rp < 2; rp++) {
                        float a = fmaxf(acc[mt][nt][2 * rp], acc[mt][nt][2 * rp + 1]);
                        float p = __shfl_xor(a, 32, 64);
                        float v = fmaxf(a, p);
                        if (quad < 2) {
                            int m1 = m0 + wm * 64 + mt * 16 + quad * 4 + 2 * rp;
                            int b  = m1 >> logHW;
                            int rm = m1 & (HW - 1);
                            int yp = (rm >> logW) >> 1;
                            int xp = (rm & (W - 1)) >> 1;
                            out[(size_t)((b * Hpo + yp + 1) * Hpo + xp + 1) * Cout + ng] =
                                f2bf(fmaxf(v + bz, 0.f));
                        }
                    }
            }
        }
        return;
    }

    #pragma unroll
    for (int mt = 0; mt < 4; mt++) {
        #pragma unroll
        for (int r = 0; r < 4; r++) {
            int mg = m0 + wm * 64 + mt * 16 + quad * 4 + r;
            size_t obase;
            if (outPad) {
                int b  = mg >> logHW;
                int rm = mg & (HW - 1);
                int y  = rm >> logW;
                int xx = rm & (W - 1);
                obase = (size_t)((b * Wp + y + 1) * Wp + xx + 1) * Cout;
            } else {
                obase = (size_t)mg * Cout;
            }
            #pragma unroll
            for (int nt = 0; nt < NT; nt++) {
                int ng = n0 + wn * (BN / 2) + nt * 16 + l16;
                float v = acc[mt][nt][r] + bias[ng];
                out[obase + ng] = f2bf(fmaxf(v, 0.f));
            }
        }
    }
}

// sum split partials + bias + relu -> bf16 NHWC (padded out optional)
__global__ void reduce_split(const float* __restrict__ partial,
                             const float* __restrict__ bias, u16* __restrict__ out,
                             int MN, int C, int logC, int splitN, size_t pstride,
                             int H, int logHW, int logW, int outPad)
{
    int i4 = (blockIdx.x * 256 + threadIdx.x) * 4;
    if (i4 >= MN) return;
    float4 s = *(const float4*)(partial + i4);
    for (int sp = 1; sp < splitN; sp++) {
        float4 p = *(const float4*)(partial + (size_t)sp * pstride + i4);
        s.x += p.x; s.y += p.y; s.z += p.z; s.w += p.w;
    }
    int n = i4 & (C - 1);
    int m = i4 >> logC;
    size_t obase;
    if (outPad) {
        int Wp = H + 2;
        int b  = m >> logHW;
        int rm = m & ((1 << logHW) - 1);
        int y  = rm >> logW;
        int xx = rm & (H - 1);
        obase = (size_t)((b * Wp + y + 1) * Wp + xx + 1) * C;
    } else {
        obase = (size_t)m * C;
    }
    ushort4 o;
    o.x = f2bf(fmaxf(s.x + bias[n + 0], 0.f));
    o.y = f2bf(fmaxf(s.y + bias[n + 1], 0.f));
    o.z = f2bf(fmaxf(s.z + bias[n + 2], 0.f));
    o.w = f2bf(fmaxf(s.w + bias[n + 3], 0.f));
    *(ushort4*)(out + obase + n) = o;
}

// sum split partials + bias + relu + 2x2 maxpool -> bf16 (padded optional)
__global__ void reduce_pool(const float* __restrict__ partial,
                            const float* __restrict__ bias, u16* __restrict__ out,
                            int total4, int C, int splitN, size_t pstride,
                            int H, int outPad)
{
    int idx = blockIdx.x * 256 + threadIdx.x;
    if (idx >= total4) return;
    int c4 = idx % (C / 4);
    int p  = idx / (C / 4);
    int Ho = H >> 1;
    int xp = p % Ho; p /= Ho;
    int yp = p % Ho;
    int b  = p / Ho;
    int n  = c4 * 4;
    float4 best;
    bool first = true;
    #pragma unroll
    for (int dy = 0; dy < 2; dy++)
        #pragma unroll
        for (int dx = 0; dx < 2; dx++) {
            int m = (b * H + 2 * yp + dy) * H + 2 * xp + dx;
            const float* q = partial + (size_t)m * C + n;
            float4 s = *(const float4*)q;
            for (int sp = 1; sp < splitN; sp++) {
                float4 pp = *(const float4*)(q + (size_t)sp * pstride);
                s.x += pp.x; s.y += pp.y; s.z += pp.z; s.w += pp.w;
            }
            if (first) { best = s; first = false; }
            else {
                best.x = fmaxf(best.x, s.x); best.y = fmaxf(best.y, s.y);
                best.z = fmaxf(best.z, s.z); best.w = fmaxf(best.w, s.w);
            }
        }
    size_t obase;
    if (outPad) {
        int Hpo = Ho + 2;
        obase = (size_t)((b * Hpo + yp + 1) * Hpo + xp + 1) * C;
    } else {
        obase = (size_t)((b * Ho + yp) * Ho + xp) * C;
    }
    ushort4 o;
    o.x = f2bf(fmaxf(best.x + bias[n + 0], 0.f));
    o.y = f2bf(fmaxf(best.y + bias[n + 1], 0.f));
    o.z = f2bf(fmaxf(best.z + bias[n + 2], 0.f));
    o.w = f2bf(fmaxf(best.w + bias[n + 3], 0.f));
    *(ushort4*)(out + obase + n) = o;
}

// ---------------------------------------------------------------------------
// Generic small GEMM: out[M,N] = act(A[M,K](bf16) @ Bt[N,K](bf16)^T + bias)
// ---------------------------------------------------------------------------
template <bool RELU, bool OUTBF>
__global__ __launch_bounds__(256) void gemm64(
    const u16* __restrict__ A, const u16* __restrict__ Bt,
    const float* __restrict__ bias, void* __restrict__ outv,
    int M, int N, int K)
{
    constexpr int LDP = 72;
    __shared__ u16 As[64 * LDP];
    __shared__ u16 Bs[64 * LDP];

    const int nb = N >> 6;
    const int m0 = (blockIdx.x / nb) * 64;
    const int n0 = (blockIdx.x % nb) * 64;
    const int t = threadIdx.x, lane = t & 63, wave = t >> 6;
    const int quad = lane >> 4, l16 = lane & 15;
    const int wm = wave >> 1, wn = wave & 1;
    const int col8 = t & 7, r0 = t >> 3;

    floatx4 acc[2][2];
    #pragma unroll
    for (int i = 0; i < 2; i++)
        #pragma unroll
        for (int j = 0; j < 2; j++)
            acc[i][j] = (floatx4){0.f, 0.f, 0.f, 0.f};

    for (int kb = 0; kb < K; kb += 64) {
        #pragma unroll
        for (int j = 0; j < 2; j++) {
            int row = r0 + 32 * j;
            *(uint4*)(As + row * LDP + col8 * 8) =
                *(const uint4*)(A + (size_t)(m0 + row) * K + kb + col8 * 8);
            *(uint4*)(Bs + row * LDP + col8 * 8) =
                *(const uint4*)(Bt + (size_t)(n0 + row) * K + kb + col8 * 8);
        }
        __syncthreads();
        #pragma unroll
        for (int kk = 0; kk < 64; kk += 32) {
            bf16x8 af[2], bfv[2];
            #pragma unroll
            for (int mt = 0; mt < 2; mt++)
                af[mt] = *(const bf16x8*)(As + (wm * 32 + mt * 16 + l16) * LDP + kk + quad * 8);
            #pragma unroll
            for (int nt = 0; nt < 2; nt++)
                bfv[nt] = *(const bf16x8*)(Bs + (wn * 32 + nt * 16 + l16) * LDP + kk + quad * 8);
            #pragma unroll
            for (int mt = 0; mt < 2; mt++)
                #pragma unroll
                for (int nt = 0; nt < 2; nt++)
                    acc[mt][nt] = __builtin_amdgcn_mfma_f32_16x16x32_bf16(
                        af[mt], bfv[nt], acc[mt][nt], 0, 0, 0);
        }
        __syncthreads();
    }
    #pragma unroll
    for (int mt = 0; mt < 2; mt++) {
        #pragma unroll
        for (int nt = 0; nt < 2; nt++) {
            #pragma unroll
            for (int r = 0; r < 4; r++) {
                int mg = m0 + wm * 32 + mt * 16 + quad * 4 + r;
                int ng = n0 + wn * 32 + nt * 16 + l16;
                float v = acc[mt][nt][r] + bias[ng];
                if (RELU) v = fmaxf(v, 0.f);
                if (OUTBF) ((u16*)outv)[(size_t)mg * N + ng] = f2bf(v);
                else       ((float*)outv)[(size_t)mg * N + ng] = v;
            }
        }
    }
}

// ---------------------------------------------------------------------------
__global__ __launch_bounds__(256) void graph_tile(
    const float* __restrict__ low, const int* __restrict__ target,
    float* __restrict__ gpre, float* __restrict__ ggt)
{
    __shared__ float Al[64 * 132];
    __shared__ float Bl[128 * 68];
    const int t = threadIdx.x;
    const int gr0 = (blockIdx.x >> 3) * 64;
    const int gc0 = (blockIdx.x & 7) * 64;

    #pragma unroll
    for (int j = 0; j < 32; j++) {
        int flat = t + 256 * j;
        int k = flat & 127;
        int rc = flat >> 7;
        Al[rc * 132 + k] = low[(size_t)(gr0 + rc) * 128 + k];
        Bl[k * 68 + rc]  = low[(size_t)(gc0 + rc) * 128 + k];
    }
    __syncthreads();

    const int tx = t & 15, ty = t >> 4;
    float acc[4][4];
    #pragma unroll
    for (int r = 0; r < 4; r++)
        #pragma unroll
        for (int c = 0; c < 4; c++) acc[r][c] = 0.f;

    for (int k = 0; k < 128; k++) {
        float a[4], b[4];
        #pragma unroll
        for (int r = 0; r < 4; r++) a[r] = Al[(ty * 4 + r) * 132 + k];
        #pragma unroll
        for (int c = 0; c < 4; c++) b[c] = Bl[k * 68 + tx * 4 + c];
        #pragma unroll
        for (int r = 0; r < 4; r++)
            #pragma unroll
            for (int c = 0; c < 4; c++) acc[r][c] += a[r] * b[c];
    }
    #pragma unroll
    for (int r = 0; r < 4; r++) {
        int row = gr0 + ty * 4 + r;
        int tr  = target[row];
        float4 gp, gg;
        float* pp = (float*)&gp;
        float* gg_ = (float*)&gg;
        #pragma unroll
        for (int c = 0; c < 4; c++) {
            pp[c]  = 1.f / (1.f + __expf(-acc[r][c]));
            gg_[c] = (tr == target[gc0 + tx * 4 + c]) ? 1.f : 0.f;
        }
        *(float4*)(gpre + (size_t)row * 512 + gc0 + tx * 4) = gp;
        *(float4*)(ggt  + (size_t)row * 512 + gc0 + tx * 4) = gg;
    }
}

// ---------------------------------------------------------------------------
__global__ __launch_bounds__(256) void cls_kernel(
    const u16* __restrict__ feat, const float* __restrict__ w,
    const float* __restrict__ bias, float* __restrict__ out)
{
    __shared__ float ws[5120];
    const int t = threadIdx.x;
    for (int i = t; i < 5120; i += 256) ws[i] = w[i];
    __syncthreads();
    const int lane = t & 63;
    const int row  = blockIdx.x * 4 + (t >> 6);
    float a[10];
    #pragma unroll
    for (int j = 0; j < 10; j++) a[j] = 0.f;
    #pragma unroll
    for (int i = 0; i < 8; i++) {
        int k = i * 64 + lane;
        float f = bf2f(feat[(size_t)row * 512 + k]);
        #pragma unroll
        for (int j = 0; j < 10; j++) a[j] += f * ws[k * 10 + j];
    }
    #pragma unroll
    for (int j = 0; j < 10; j++)
        #pragma unroll
        for (int off = 32; off > 0; off >>= 1)
            a[j] += __shfl_down(a[j], off, 64);
    if (lane == 0) {
        #pragma unroll
        for (int j = 0; j < 10; j++) out[row * 10 + j] = a[j] + bias[j];
    }
}

// ---------------------------------------------------------------------------
extern "C" void kernel_launch(void* const* d_in, const int* in_sizes, int n_in,
                              void* d_out, int out_size, void* d_ws, size_t ws_size,
                              hipStream_t stream)
{
    const float* x      = (const float*)d_in[0];
    const int*   target = (const int*)d_in[1];
    const float* conv_w[13];
    const float* conv_b[13];
    for (int i = 0; i < 13; i++) {
        conv_w[i] = (const float*)d_in[2 + 2 * i];
        conv_b[i] = (const float*)d_in[3 + 2 * i];
    }
    const float* lin1_w = (const float*)d_in[28];
    const float* lin1_b = (const float*)d_in[29];
    const float* lin2_w = (const float*)d_in[30];
    const float* lin2_b = (const float*)d_in[31];
    const float* cls_w  = (const float*)d_in[32];
    const float* cls_b  = (const float*)d_in[33];
    float* out = (float*)d_out;

    static const int cin_arr[13]  = {3, 64, 64, 128, 128, 256, 256, 256, 512, 512, 512, 512, 512};
    static const int cout_arr[13] = {64, 64, 128, 128, 256, 256, 256, 512, 512, 512, 512, 512, 512};

    char* ws = (char*)d_ws;
    size_t off = 0;
    const size_t R0SZ = (size_t)512 * 34 * 34 * 64 * 2;
    const size_t R1SZ = (size_t)512 * 34 * 34 * 64 * 2;
    char* R0raw = ws + off; off += R0SZ;
    char* R1raw = ws + off; off += R1SZ;
    u16* R0 = (u16*)R0raw;
    u16* R1 = (u16*)R1raw;
    float* PA = (float*)(R0raw + 20971520);
    float* PB = (float*)(R1raw + 20971520);
    u16* wt[13];
    for (int i = 1; i < 13; i++) {
        wt[i] = (u16*)(ws + off);
        off += (size_t)cout_arr[i] * 9 * cin_arr[i] * 2;
    }
    u16* wtl1 = (u16*)(ws + off); off += (size_t)256 * 512 * 2;
    u16* wtl2 = (u16*)(ws + off); off += (size_t)128 * 256 * 2;
    u16* hbuf = (u16*)(ws + off); off += (size_t)512 * 256 * 2;
    float* lowbuf = (float*)(ws + off); off += (size_t)512 * 128 * 4;

    for (int i = 1; i < 13; i++) {
        int total = cout_arr[i] * 9 * cin_arr[i];
        repack_w<<<(total + 255) / 256, 256, 0, stream>>>(conv_w[i], wt[i], cin_arr[i], total);
    }
    repack_lin<<<(512 * 256) / 256, 256, 0, stream>>>(lin1_w, wtl1, 512, 256, 512 * 256);
    repack_lin<<<(256 * 128) / 256, 256, 0, stream>>>(lin2_w, wtl2, 256, 128, 256 * 128);

    auto zh = [&](u16* buf, int Hp, int C) {
        int total8 = 512 * Hp * Hp * (C / 8);
        zero_halo<<<(total8 + 255) / 256, 256, 0, stream>>>(buf, Hp, C, total8);
    };
    auto launch_conv = [&](int li, int Hl, u16* inb, u16* outb, float* part,
                           int splitN, int outPad, int poolMode) {
        int Cin = cin_arr[li], Cout = cout_arr[li];
        int M = 512 * Hl * Hl;
        int logW = __builtin_ctz(Hl);
        int logHW = 2 * logW;
        size_t pstride = (size_t)M * Cout;
        if (Cout >= 128) {
            int grid = (M / 128) * (Cout / 128) * splitN;
            conv_gemm<128><<<grid, 256, 0, stream>>>(
                inb, wt[li], conv_b[li], outb, part, pstride,
                Hl, Cin, Cout, logHW, logW, splitN, outPad, poolMode);
        } else {
            int grid = (M / 128) * (Cout / 64) * splitN;
            conv_gemm<64><<<grid, 256, 0, stream>>>(
                inb, wt[li], conv_b[li], outb, part, pstride,
                Hl, Cin, Cout, logHW, logW, splitN, outPad, poolMode);
        }
    };
    auto launch_reduce = [&](int li, int Hl, u16* outb, float* part, int splitN, int outPad) {
        int Cout = cout_arr[li];
        int M = 512 * Hl * Hl;
        int logW = __builtin_ctz(Hl);
        size_t pstride = (size_t)M * Cout;
        int MN = M * Cout;
        reduce_split<<<(MN / 4 + 255) / 256, 256, 0, stream>>>(
            part, conv_b[li], outb, MN, Cout, __builtin_ctz(Cout),
            splitN, pstride, Hl, 2 * logW, logW, outPad);
    };
    auto launch_reduce_pool = [&](int li, int Hl, u16* outb, float* part, int splitN, int outPad) {
        int Cout = cout_arr[li];
        int M = 512 * Hl * Hl;
        size_t pstride = (size_t)M * Cout;
        int total4 = 512 * (Hl / 2) * (Hl / 2) * Cout / 4;
        reduce_pool<<<(total4 + 255) / 256, 256, 0, stream>>>(
            part, conv_b[li], outb, total4, Cout, splitN, pstride, Hl, outPad);
    };

    zh(R0, 34, 64);
    conv0_kernel<<<512 * 8, 256, 0, stream>>>(x, conv_w[0], conv_b[0], R0);

    zh(R1, 18, 64);
    launch_conv(1, 32, R0, R1, nullptr, 1, 0, 1);      // L1 + pool -> R1 p18,64
    zh(R0, 18, 128);
    launch_conv(2, 16, R1, R0, nullptr, 1, 1, 0);      // L2 -> R0 p18,128
    zh(R1, 10, 128);
    launch_conv(3, 16, R0, R1, nullptr, 1, 0, 1);      // L3 + pool -> R1 p10,128
    zh(R0, 10, 256);
    launch_conv(4, 8, R1, R0, nullptr, 1, 1, 0);       // L4 -> R0 p10,256
    zh(R1, 10, 256);
    launch_conv(5, 8, R0, R1, nullptr, 1, 1, 0);       // L5 -> R1 p10,256
    zh(R0, 6, 256);
    launch_conv(6, 8, R1, R0, nullptr, 1, 0, 1);       // L6 + pool -> R0 p6,256
    zh(R1, 6, 512);
    launch_conv(7, 4, R0, R1, PB, 2, 1, 0);            // L7 partials -> PB
    launch_reduce(7, 4, R1, PB, 2, 1);                 //   -> R1 p6,512
    zh(R0, 6, 512);
    launch_conv(8, 4, R1, R0, PA, 2, 1, 0);            // L8 -> PA
    launch_reduce(8, 4, R0, PA, 2, 1);                 //   -> R0 p6,512
    zh(R1, 4, 512);
    launch_conv(9, 4, R0, R1, PB, 2, 0, 0);            // L9 -> PB
    launch_reduce_pool(9, 4, R1, PB, 2, 1);            //   + pool -> R1 p4,512
    zh(R0, 4, 512);
    launch_conv(10, 2, R1, R0, PA, 8, 1, 0);           // L10 -> PA
    launch_reduce(10, 2, R0, PA, 8, 1);                //   -> R0 p4,512
    zh(R1, 4, 512);
    launch_conv(11, 2, R0, R1, PB, 8, 1, 0);           // L11 -> PB
    launch_reduce(11, 2, R1, PB, 8, 1);                //   -> R1 p4,512
    launch_conv(12, 2, R1, R0, PA, 8, 0, 0);           // L12 -> PA
    launch_reduce_pool(12, 2, R0, PA, 8, 0);           //   + pool -> feat = R0 [512,512]

    u16* feat = R0;
    gemm64<true, true><<<(512 / 64) * (256 / 64), 256, 0, stream>>>(
        feat, wtl1, lin1_b, hbuf, 512, 256, 512);
    gemm64<false, false><<<(512 / 64) * (128 / 64), 256, 0, stream>>>(
        hbuf, wtl2, lin2_b, lowbuf, 512, 128, 256);
    graph_tile<<<64, 256, 0, stream>>>(lowbuf, target, out + 5120, out + 5120 + 262144);
    cls_kernel<<<128, 256, 0, stream>>>(feat, cls_w, cls_b, out);
}

// Round 9
// 860.879 us; speedup vs baseline: 1.4776x; 1.0053x over previous
//
#include <hip/hip_runtime.h>

typedef unsigned short u16;
typedef __bf16 bf16x8 __attribute__((ext_vector_type(8)));
typedef float floatx4 __attribute__((ext_vector_type(4)));

__device__ inline u16 f2bf(float f) {
    unsigned int u = __float_as_uint(f);
    unsigned int r = (u + 0x7FFFu + ((u >> 16) & 1u)) >> 16;
    return (u16)r;
}
__device__ inline float bf2f(u16 h) {
    return __uint_as_float(((unsigned int)h) << 16);
}

// async global->LDS, 16B per lane. LDS dest must be wave-uniform base + lane*16.
__device__ __forceinline__ void async_copy16(u16* lds, const u16* g) {
    __builtin_amdgcn_global_load_lds(
        (const __attribute__((address_space(1))) unsigned int*)(uintptr_t)g,
        (__attribute__((address_space(3))) unsigned int*)(unsigned int)(uintptr_t)lds,
        16, 0, 0);
}

// ---------------------------------------------------------------------------
// zero the 1-px halo of a padded NHWC buffer [512][Hp][Hp][C]
// ---------------------------------------------------------------------------
__global__ void zero_halo(u16* __restrict__ buf, int Hp, int C, int total8)
{
    int i = blockIdx.x * 256 + threadIdx.x;
    if (i >= total8) return;
    int c8 = i % (C / 8);
    int p  = i / (C / 8);
    int x  = p % Hp; p /= Hp;
    int y  = p % Hp;
    int b  = p / Hp;
    if (y == 0 || y == Hp - 1 || x == 0 || x == Hp - 1) {
        uint4 z = make_uint4(0u, 0u, 0u, 0u);
        *(uint4*)(buf + ((size_t)((b * Hp + y) * Hp + x) * C) + c8 * 8) = z;
    }
}

// ---------------------------------------------------------------------------
// Layer 0: direct conv 3->64, 32x32, output PADDED NHWC [512][34][34][64]
// ---------------------------------------------------------------------------
__global__ __launch_bounds__(256) void conv0_kernel(
    const float* __restrict__ x, const float* __restrict__ w,
    const float* __restrict__ bias, u16* __restrict__ out)
{
    __shared__ __align__(16) float xs[3][6][36];
    const int t  = threadIdx.x;
    const int b  = blockIdx.x >> 3;
    const int y0 = (blockIdx.x & 7) * 4;

    for (int i = t; i < 3 * 6 * 36; i += 256) {
        int ci  = i / 216;
        int rem = i % 216;
        int r   = rem / 36;
        int c   = rem % 36;
        int gy  = y0 - 1 + r;
        int gx  = c - 1;
        float v = 0.f;
        if ((unsigned)gy < 32u && (unsigned)gx < 32u)
            v = x[((b * 3 + ci) * 32 + gy) * 32 + gx];
        xs[ci][r][c] = v;
    }
    const int lane = t & 63;
    const int wv   = t >> 6;
    float wr[27];
    #pragma unroll
    for (int k = 0; k < 27; k++) wr[k] = w[lane * 27 + k];
    const float bz = bias[lane];
    __syncthreads();

    const int y = y0 + wv;
    u16* orow = out + ((size_t)((b * 34 + y + 1) * 34 + 1) * 64) + lane;
    for (int xg = 0; xg < 32; xg += 4) {
        float a0 = bz, a1 = bz, a2 = bz, a3 = bz;
        #pragma unroll
        for (int ci = 0; ci < 3; ci++) {
            #pragma unroll
            for (int rr = 0; rr < 3; rr++) {
                const float* row = &xs[ci][wv + rr][0];
                float4 c03 = *(const float4*)(row + xg);
                float2 c45 = *(const float2*)(row + xg + 4);
                float w0 = wr[ci * 9 + rr * 3 + 0];
                float w1 = wr[ci * 9 + rr * 3 + 1];
                float w2 = wr[ci * 9 + rr * 3 + 2];
                a0 += c03.x * w0 + c03.y * w1 + c03.z * w2;
                a1 += c03.y * w0 + c03.z * w1 + c03.w * w2;
                a2 += c03.z * w0 + c03.w * w1 + c45.x * w2;
                a3 += c03.w * w0 + c45.x * w1 + c45.y * w2;
            }
        }
        orow[(xg + 0) * 64] = f2bf(fmaxf(a0, 0.f));
        orow[(xg + 1) * 64] = f2bf(fmaxf(a1, 0.f));
        orow[(xg + 2) * 64] = f2bf(fmaxf(a2, 0.f));
        orow[(xg + 3) * 64] = f2bf(fmaxf(a3, 0.f));
    }
}

// ---------------------------------------------------------------------------
__global__ void repack_w(const float* __restrict__ w, u16* __restrict__ wt,
                         int Cin, int total)
{
    int i = blockIdx.x * 256 + threadIdx.x;
    if (i >= total) return;
    int ci = i % Cin;
    int rest = i / Cin;
    int s = rest % 9;
    int co = rest / 9;
    wt[i] = f2bf(w[(co * Cin + ci) * 9 + s]);
}

__global__ void repack_lin(const float* __restrict__ w, u16* __restrict__ wt,
                           int K, int N, int total)
{
    int i = blockIdx.x * 256 + threadIdx.x;
    if (i >= total) return;
    int n = i % N, k = i / N;
    wt[(size_t)n * K + k] = f2bf(w[(size_t)k * N + n]);
}

// ---------------------------------------------------------------------------
// Conv shift-GEMM, bf16 MFMA 16x16x32. Padded input, global_load_lds staging,
// XOR-8 swizzle via global source permutation, incremental SALU offsets,
// fused-pool epilogue option, and XCD-aware tile swizzle: bid%8 -> XCD
// (round-robin heuristic), each XCD owns a contiguous 1/8 of the M range,
// consistent across layers for producer->consumer L2 locality.
// ---------------------------------------------------------------------------
template <int BN>
__global__ __launch_bounds__(256) void conv_gemm(
    const u16* __restrict__ in, const u16* __restrict__ wt,
    const float* __restrict__ bias, u16* __restrict__ out,
    float* __restrict__ partial, size_t pstride,
    int H, int Cin, int Cout, int logHW, int logW, int splitN,
    int outPad, int poolMode)
{
    constexpr int BM = 128, BK = 64;
    constexpr int NT   = BN / 32;
    constexpr int NB_A = 4;
    constexpr int NB_B = BN / 32;
    __shared__ u16 As[BM * BK];
    __shared__ u16 Bs[BN * BK];

    const int Nblocks = Cout / BN;
    // XCD-aware swizzle: grid always divisible by 8 here.
    const int per = gridDim.x >> 3;
    const int bid = (blockIdx.x & 7) * per + (blockIdx.x >> 3);
    const int sp   = bid % splitN;
    const int tile = bid / splitN;
    const int m0 = (tile / Nblocks) * BM;
    const int n0 = (tile % Nblocks) * BN;

    const int t    = threadIdx.x;
    const int lane = t & 63;
    const int wave = t >> 6;
    const int quad = lane >> 4;
    const int l16  = lane & 15;
    const int wm   = wave >> 1;
    const int wn   = wave & 1;
    const int W    = H;
    const int Wp   = H + 2;
    const int HW   = 1 << logHW;
    const int col8 = t & 7;
    const int r0   = t >> 3;
    const int scol = col8 ^ (r0 & 7);

    const int CinB = Cin * 2;

    int vA[NB_A];
    #pragma unroll
    for (int j = 0; j < NB_A; j++) {
        int m  = m0 + r0 + 32 * j;
        int b  = m >> logHW;
        int rm = m & (HW - 1);
        int y  = rm >> logW;
        int xx = rm & (W - 1);
        vA[j] = ((b * Wp + y + 1) * Wp + xx + 1) * CinB + scol * 16;
    }
    int vB[NB_B];
    #pragma unroll
    for (int j = 0; j < NB_B; j++)
        vB[j] = (n0 + r0 + 32 * j) * 9 * CinB + scol * 16;

    const int logKB = (Cin == 64) ? 0 : (Cin == 128) ? 1 : (Cin == 256) ? 2 : 3;
    const int KB  = 1 << logKB;
    const int T   = 9 * KB;
    const int len = T / splitN;
    const int it0 = sp * len;

    int s0 = it0 >> logKB;
    int c3 = s0 - (s0 / 3) * 3;
    int ta = ((s0 / 3 - 1) * Wp + (c3 - 1)) * CinB;
    int kb = (it0 & (KB - 1)) * 128;
    int tb = it0 * 128;

    u16* const ldsA = As + t * 8;
    u16* const ldsB = Bs + t * 8;
    const char* const inB = (const char*)in;
    const char* const wtB = (const char*)wt;

    floatx4 acc[4][NT];
    #pragma unroll
    for (int i = 0; i < 4; i++)
        #pragma unroll
        for (int j = 0; j < NT; j++)
            acc[i][j] = (floatx4){0.f, 0.f, 0.f, 0.f};

    const int sw = (l16 & 7) * 8;

    for (int it = 0; it < len; it++) {
        const int ua = ta + kb;
        #pragma unroll
        for (int j = 0; j < NB_A; j++)
            async_copy16(ldsA + j * 2048, (const u16*)(inB + (ua + vA[j])));
        #pragma unroll
        for (int j = 0; j < NB_B; j++)
            async_copy16(ldsB + j * 2048, (const u16*)(wtB + (tb + vB[j])));
        __syncthreads();
        #pragma unroll
        for (int kk = 0; kk < BK; kk += 32) {
            bf16x8 af[4], bfv[NT];
            int cbo = kk + quad * 8;
            #pragma unroll
            for (int mt = 0; mt < 4; mt++)
                af[mt] = *(const bf16x8*)(As + (wm * 64 + mt * 16 + l16) * 64 + (cbo ^ sw));
            #pragma unroll
            for (int nt = 0; nt < NT; nt++)
                bfv[nt] = *(const bf16x8*)(Bs + (wn * (BN / 2) + nt * 16 + l16) * 64 + (cbo ^ sw));
            #pragma unroll
            for (int mt = 0; mt < 4; mt++)
                #pragma unroll
                for (int nt = 0; nt < NT; nt++)
                    acc[mt][nt] = __builtin_amdgcn_mfma_f32_16x16x32_bf16(
                        af[mt], bfv[nt], acc[mt][nt], 0, 0, 0);
        }
        __syncthreads();
        tb += 128;
        kb += 128;
        if (kb == CinB) {
            kb = 0;
            ta += (c3 == 2) ? (Wp - 2) * CinB : CinB;
            c3 = (c3 == 2) ? 0 : c3 + 1;
        }
    }

    if (splitN > 1) {
        float* pout = partial + (size_t)sp * pstride;
        #pragma unroll
        for (int mt = 0; mt < 4; mt++)
            #pragma unroll
            for (int nt = 0; nt < NT; nt++)
                #pragma unroll
                for (int r = 0; r < 4; r++) {
                    int mg = m0 + wm * 64 + mt * 16 + quad * 4 + r;
                    int ng = n0 + wn * (BN / 2) + nt * 16 + l16;
                    pout[(size_t)mg * Cout + ng] = acc[mt][nt][r];
                }
        return;
    }

    if (poolMode) {
        const int Hpo = (H >> 1) + 2;
        #pragma unroll
        for (int nt = 0; nt < NT; nt++) {
            int ng = n0 + wn * (BN / 2) + nt * 16 + l16;
            float bz = bias[ng];
            if (logW == 5) {
                #pragma unroll
                for (int mt = 0; mt < 2; mt++)
                    #pragma unroll
                    for (int rp = 0; rp < 2; rp++) {
                        float v = fmaxf(
                            fmaxf(acc[mt][nt][2 * rp], acc[mt][nt][2 * rp + 1]),
                            fmaxf(acc[mt + 2][nt][2 * rp], acc[mt + 2][nt][2 * rp + 1]));
                        int m1 = m0 + wm * 64 + mt * 16 + quad * 4 + 2 * rp;
                        int b  = m1 >> logHW;
                        int rm = m1 & (HW - 1);
                        int yp = (rm >> logW) >> 1;
                        int xp = (rm & (W - 1)) >> 1;
                        out[(size_t)((b * Hpo + yp + 1) * Hpo + xp + 1) * Cout + ng] =
                            f2bf(fmaxf(v + bz, 0.f));
                    }
            } else if (logW == 4) {
                #pragma unroll
                for (int mtp = 0; mtp < 2; mtp++)
                    #pragma unroll
                    for (int rp = 0; rp < 2; rp++) {
                        int mt = 2 * mtp;
                        float v = fmaxf(
                            fmaxf(acc[mt][nt][2 * rp], acc[mt][nt][2 * rp + 1]),
                            fmaxf(acc[mt + 1][nt][2 * rp], acc[mt + 1][nt][2 * rp + 1]));
                        int m1 = m0 + wm * 64 + mt * 16 + quad * 4 + 2 * rp;
                        int b  = m1 >> logHW;
                        int rm = m1 & (HW - 1);
                        int yp = (rm >> logW) >> 1;
                        int xp = (rm & (W - 1)) >> 1;
                        out[(size_t)((b * Hpo + yp + 1) * Hpo + xp + 1) * Cout + ng] =
                            f2bf(fmaxf(v + bz, 0.f));
                    }
            } else {
                #pragma unroll
                for (int mt = 0; mt < 4; mt++)
                    #pragma unroll
                    for (int rp = 0; rp < 2; rp++) {
                        float a = fmaxf(acc[mt][nt][2 * rp], acc[mt][nt][2 * rp + 1]);
                        float p = __shfl_xor(a, 32, 64);
                        float v = fmaxf(a, p);
                        if (quad < 2) {
                            int m1 = m0 + wm * 64 + mt * 16 + quad * 4 + 2 * rp;
                            int b  = m1 >> logHW;
                            int rm = m1 & (HW - 1);
                            int yp = (rm >> logW) >> 1;
                            int xp = (rm & (W - 1)) >> 1;
                            out[(size_t)((b * Hpo + yp + 1) * Hpo + xp + 1) * Cout + ng] =
                                f2bf(fmaxf(v + bz, 0.f));
                        }
                    }
            }
        }
        return;
    }

    #pragma unroll
    for (int mt = 0; mt < 4; mt++) {
        #pragma unroll
        for (int r = 0; r < 4; r++) {
            int mg = m0 + wm * 64 + mt * 16 + quad * 4 + r;
            size_t obase;
            if (outPad) {
                int b  = mg >> logHW;
                int rm = mg & (HW - 1);
                int y  = rm >> logW;
                int xx = rm & (W - 1);
                obase = (size_t)((b * Wp + y + 1) * Wp + xx + 1) * Cout;
            } else {
                obase = (size_t)mg * Cout;
            }
            #pragma unroll
            for (int nt = 0; nt < NT; nt++) {
                int ng = n0 + wn * (BN / 2) + nt * 16 + l16;
                float v = acc[mt][nt][r] + bias[ng];
                out[obase + ng] = f2bf(fmaxf(v, 0.f));
            }
        }
    }
}

// sum split partials + bias + relu -> bf16 NHWC (padded out optional)
__global__ void reduce_split(const float* __restrict__ partial,
                             const float* __restrict__ bias, u16* __restrict__ out,
                             int MN, int C, int logC, int splitN, size_t pstride,
                             int H, int logHW, int logW, int outPad)
{
    int i4 = (blockIdx.x * 256 + threadIdx.x) * 4;
    if (i4 >= MN) return;
    float4 s = *(const float4*)(partial + i4);
    for (int sp = 1; sp < splitN; sp++) {
        float4 p = *(const float4*)(partial + (size_t)sp * pstride + i4);
        s.x += p.x; s.y += p.y; s.z += p.z; s.w += p.w;
    }
    int n = i4 & (C - 1);
    int m = i4 >> logC;
    size_t obase;
    if (outPad) {
        int Wp = H + 2;
        int b  = m >> logHW;
        int rm = m & ((1 << logHW) - 1);
        int y  = rm >> logW;
        int xx = rm & (H - 1);
        obase = (size_t)((b * Wp + y + 1) * Wp + xx + 1) * C;
    } else {
        obase = (size_t)m * C;
    }
    ushort4 o;
    o.x = f2bf(fmaxf(s.x + bias[n + 0], 0.f));
    o.y = f2bf(fmaxf(s.y + bias[n + 1], 0.f));
    o.z = f2bf(fmaxf(s.z + bias[n + 2], 0.f));
    o.w = f2bf(fmaxf(s.w + bias[n + 3], 0.f));
    *(ushort4*)(out + obase + n) = o;
}

// sum split partials + bias + relu + 2x2 maxpool -> bf16 (padded optional)
__global__ void reduce_pool(const float* __restrict__ partial,
                            const float* __restrict__ bias, u16* __restrict__ out,
                            int total4, int C, int splitN, size_t pstride,
                            int H, int outPad)
{
    int idx = blockIdx.x * 256 + threadIdx.x;
    if (idx >= total4) return;
    int c4 = idx % (C / 4);
    int p  = idx / (C / 4);
    int Ho = H >> 1;
    int xp = p % Ho; p /= Ho;
    int yp = p % Ho;
    int b  = p / Ho;
    int n  = c4 * 4;
    float4 best;
    bool first = true;
    #pragma unroll
    for (int dy = 0; dy < 2; dy++)
        #pragma unroll
        for (int dx = 0; dx < 2; dx++) {
            int m = (b * H + 2 * yp + dy) * H + 2 * xp + dx;
            const float* q = partial + (size_t)m * C + n;
            float4 s = *(const float4*)q;
            for (int sp = 1; sp < splitN; sp++) {
                float4 pp = *(const float4*)(q + (size_t)sp * pstride);
                s.x += pp.x; s.y += pp.y; s.z += pp.z; s.w += pp.w;
            }
            if (first) { best = s; first = false; }
            else {
                best.x = fmaxf(best.x, s.x); best.y = fmaxf(best.y, s.y);
                best.z = fmaxf(best.z, s.z); best.w = fmaxf(best.w, s.w);
            }
        }
    size_t obase;
    if (outPad) {
        int Hpo = Ho + 2;
        obase = (size_t)((b * Hpo + yp + 1) * Hpo + xp + 1) * C;
    } else {
        obase = (size_t)((b * Ho + yp) * Ho + xp) * C;
    }
    ushort4 o;
    o.x = f2bf(fmaxf(best.x + bias[n + 0], 0.f));
    o.y = f2bf(fmaxf(best.y + bias[n + 1], 0.f));
    o.z = f2bf(fmaxf(best.z + bias[n + 2], 0.f));
    o.w = f2bf(fmaxf(best.w + bias[n + 3], 0.f));
    *(ushort4*)(out + obase + n) = o;
}

// ---------------------------------------------------------------------------
// Generic small GEMM: out[M,N] = act(A[M,K](bf16) @ Bt[N,K](bf16)^T + bias)
// ---------------------------------------------------------------------------
template <bool RELU, bool OUTBF>
__global__ __launch_bounds__(256) void gemm64(
    const u16* __restrict__ A, const u16* __restrict__ Bt,
    const float* __restrict__ bias, void* __restrict__ outv,
    int M, int N, int K)
{
    constexpr int LDP = 72;
    __shared__ u16 As[64 * LDP];
    __shared__ u16 Bs[64 * LDP];

    const int nb = N >> 6;
    const int m0 = (blockIdx.x / nb) * 64;
    const int n0 = (blockIdx.x % nb) * 64;
    const int t = threadIdx.x, lane = t & 63, wave = t >> 6;
    const int quad = lane >> 4, l16 = lane & 15;
    const int wm = wave >> 1, wn = wave & 1;
    const int col8 = t & 7, r0 = t >> 3;

    floatx4 acc[2][2];
    #pragma unroll
    for (int i = 0; i < 2; i++)
        #pragma unroll
        for (int j = 0; j < 2; j++)
            acc[i][j] = (floatx4){0.f, 0.f, 0.f, 0.f};

    for (int kb = 0; kb < K; kb += 64) {
        #pragma unroll
        for (int j = 0; j < 2; j++) {
            int row = r0 + 32 * j;
            *(uint4*)(As + row * LDP + col8 * 8) =
                *(const uint4*)(A + (size_t)(m0 + row) * K + kb + col8 * 8);
            *(uint4*)(Bs + row * LDP + col8 * 8) =
                *(const uint4*)(Bt + (size_t)(n0 + row) * K + kb + col8 * 8);
        }
        __syncthreads();
        #pragma unroll
        for (int kk = 0; kk < 64; kk += 32) {
            bf16x8 af[2], bfv[2];
            #pragma unroll
            for (int mt = 0; mt < 2; mt++)
                af[mt] = *(const bf16x8*)(As + (wm * 32 + mt * 16 + l16) * LDP + kk + quad * 8);
            #pragma unroll
            for (int nt = 0; nt < 2; nt++)
                bfv[nt] = *(const bf16x8*)(Bs + (wn * 32 + nt * 16 + l16) * LDP + kk + quad * 8);
            #pragma unroll
            for (int mt = 0; mt < 2; mt++)
                #pragma unroll
                for (int nt = 0; nt < 2; nt++)
                    acc[mt][nt] = __builtin_amdgcn_mfma_f32_16x16x32_bf16(
                        af[mt], bfv[nt], acc[mt][nt], 0, 0, 0);
        }
        __syncthreads();
    }
    #pragma unroll
    for (int mt = 0; mt < 2; mt++) {
        #pragma unroll
        for (int nt = 0; nt < 2; nt++) {
            #pragma unroll
            for (int r = 0; r < 4; r++) {
                int mg = m0 + wm * 32 + mt * 16 + quad * 4 + r;
                int ng = n0 + wn * 32 + nt * 16 + l16;
                float v = acc[mt][nt][r] + bias[ng];
                if (RELU) v = fmaxf(v, 0.f);
                if (OUTBF) ((u16*)outv)[(size_t)mg * N + ng] = f2bf(v);
                else       ((float*)outv)[(size_t)mg * N + ng] = v;
            }
        }
    }
}

// ---------------------------------------------------------------------------
__global__ __launch_bounds__(256) void graph_tile(
    const float* __restrict__ low, const int* __restrict__ target,
    float* __restrict__ gpre, float* __restrict__ ggt)
{
    __shared__ float Al[64 * 132];
    __shared__ float Bl[128 * 68];
    const int t = threadIdx.x;
    const int gr0 = (blockIdx.x >> 3) * 64;
    const int gc0 = (blockIdx.x & 7) * 64;

    #pragma unroll
    for (int j = 0; j < 32; j++) {
        int flat = t + 256 * j;
        int k = flat & 127;
        int rc = flat >> 7;
        Al[rc * 132 + k] = low[(size_t)(gr0 + rc) * 128 + k];
        Bl[k * 68 + rc]  = low[(size_t)(gc0 + rc) * 128 + k];
    }
    __syncthreads();

    const int tx = t & 15, ty = t >> 4;
    float acc[4][4];
    #pragma unroll
    for (int r = 0; r < 4; r++)
        #pragma unroll
        for (int c = 0; c < 4; c++) acc[r][c] = 0.f;

    for (int k = 0; k < 128; k++) {
        float a[4], b[4];
        #pragma unroll
        for (int r = 0; r < 4; r++) a[r] = Al[(ty * 4 + r) * 132 + k];
        #pragma unroll
        for (int c = 0; c < 4; c++) b[c] = Bl[k * 68 + tx * 4 + c];
        #pragma unroll
        for (int r = 0; r < 4; r++)
            #pragma unroll
            for (int c = 0; c < 4; c++) acc[r][c] += a[r] * b[c];
    }
    #pragma unroll
    for (int r = 0; r < 4; r++) {
        int row = gr0 + ty * 4 + r;
        int tr  = target[row];
        float4 gp, gg;
        float* pp = (float*)&gp;
        float* gg_ = (float*)&gg;
        #pragma unroll
        for (int c = 0; c < 4; c++) {
            pp[c]  = 1.f / (1.f + __expf(-acc[r][c]));
            gg_[c] = (tr == target[gc0 + tx * 4 + c]) ? 1.f : 0.f;
        }
        *(float4*)(gpre + (size_t)row * 512 + gc0 + tx * 4) = gp;
        *(float4*)(ggt  + (size_t)row * 512 + gc0 + tx * 4) = gg;
    }
}

// ---------------------------------------------------------------------------
__global__ __launch_bounds__(256) void cls_kernel(
    const u16* __restrict__ feat, const float* __restrict__ w,
    const float* __restrict__ bias, float* __restrict__ out)
{
    __shared__ float ws[5120];
    const int t = threadIdx.x;
    for (int i = t; i < 5120; i += 256) ws[i] = w[i];
    __syncthreads();
    const int lane = t & 63;
    const int row  = blockIdx.x * 4 + (t >> 6);
    float a[10];
    #pragma unroll
    for (int j = 0; j < 10; j++) a[j] = 0.f;
    #pragma unroll
    for (int i = 0; i < 8; i++) {
        int k = i * 64 + lane;
        float f = bf2f(feat[(size_t)row * 512 + k]);
        #pragma unroll
        for (int j = 0; j < 10; j++) a[j] += f * ws[k * 10 + j];
    }
    #pragma unroll
    for (int j = 0; j < 10; j++)
        #pragma unroll
        for (int off = 32; off > 0; off >>= 1)
            a[j] += __shfl_down(a[j], off, 64);
    if (lane == 0) {
        #pragma unroll
        for (int j = 0; j < 10; j++) out[row * 10 + j] = a[j] + bias[j];
    }
}

// ---------------------------------------------------------------------------
extern "C" void kernel_launch(void* const* d_in, const int* in_sizes, int n_in,
                              void* d_out, int out_size, void* d_ws, size_t ws_size,
                              hipStream_t stream)
{
    const float* x      = (const float*)d_in[0];
    const int*   target = (const int*)d_in[1];
    const float* conv_w[13];
    const float* conv_b[13];
    for (int i = 0; i < 13; i++) {
        conv_w[i] = (const float*)d_in[2 + 2 * i];
        conv_b[i] = (const float*)d_in[3 + 2 * i];
    }
    const float* lin1_w = (const float*)d_in[28];
    const float* lin1_b = (const float*)d_in[29];
    const float* lin2_w = (const float*)d_in[30];
    const float* lin2_b = (const float*)d_in[31];
    const float* cls_w  = (const float*)d_in[32];
    const float* cls_b  = (const float*)d_in[33];
    float* out = (float*)d_out;

    static const int cin_arr[13]  = {3, 64, 64, 128, 128, 256, 256, 256, 512, 512, 512, 512, 512};
    static const int cout_arr[13] = {64, 64, 128, 128, 256, 256, 256, 512, 512, 512, 512, 512, 512};

    char* ws = (char*)d_ws;
    size_t off = 0;
    const size_t R0SZ = (size_t)512 * 34 * 34 * 64 * 2;
    const size_t R1SZ = (size_t)512 * 34 * 34 * 64 * 2;
    char* R0raw = ws + off; off += R0SZ;
    char* R1raw = ws + off; off += R1SZ;
    u16* R0 = (u16*)R0raw;
    u16* R1 = (u16*)R1raw;
    float* PA = (float*)(R0raw + 20971520);
    float* PB = (float*)(R1raw + 20971520);
    u16* wt[13];
    for (int i = 1; i < 13; i++) {
        wt[i] = (u16*)(ws + off);
        off += (size_t)cout_arr[i] * 9 * cin_arr[i] * 2;
    }
    u16* wtl1 = (u16*)(ws + off); off += (size_t)256 * 512 * 2;
    u16* wtl2 = (u16*)(ws + off); off += (size_t)128 * 256 * 2;
    u16* hbuf = (u16*)(ws + off); off += (size_t)512 * 256 * 2;
    float* lowbuf = (float*)(ws + off); off += (size_t)512 * 128 * 4;

    for (int i = 1; i < 13; i++) {
        int total = cout_arr[i] * 9 * cin_arr[i];
        repack_w<<<(total + 255) / 256, 256, 0, stream>>>(conv_w[i], wt[i], cin_arr[i], total);
    }
    repack_lin<<<(512 * 256) / 256, 256, 0, stream>>>(lin1_w, wtl1, 512, 256, 512 * 256);
    repack_lin<<<(256 * 128) / 256, 256, 0, stream>>>(lin2_w, wtl2, 256, 128, 256 * 128);

    auto zh = [&](u16* buf, int Hp, int C) {
        int total8 = 512 * Hp * Hp * (C / 8);
        zero_halo<<<(total8 + 255) / 256, 256, 0, stream>>>(buf, Hp, C, total8);
    };
    auto launch_conv = [&](int li, int Hl, u16* inb, u16* outb, float* part,
                           int splitN, int outPad, int poolMode) {
        int Cin = cin_arr[li], Cout = cout_arr[li];
        int M = 512 * Hl * Hl;
        int logW = __builtin_ctz(Hl);
        int logHW = 2 * logW;
        size_t pstride = (size_t)M * Cout;
        if (Cout >= 128) {
            int grid = (M / 128) * (Cout / 128) * splitN;
            conv_gemm<128><<<grid, 256, 0, stream>>>(
                inb, wt[li], conv_b[li], outb, part, pstride,
                Hl, Cin, Cout, logHW, logW, splitN, outPad, poolMode);
        } else {
            int grid = (M / 128) * (Cout / 64) * splitN;
            conv_gemm<64><<<grid, 256, 0, stream>>>(
                inb, wt[li], conv_b[li], outb, part, pstride,
                Hl, Cin, Cout, logHW, logW, splitN, outPad, poolMode);
        }
    };
    auto launch_reduce = [&](int li, int Hl, u16* outb, float* part, int splitN, int outPad) {
        int Cout = cout_arr[li];
        int M = 512 * Hl * Hl;
        int logW = __builtin_ctz(Hl);
        size_t pstride = (size_t)M * Cout;
        int MN = M * Cout;
        reduce_split<<<(MN / 4 + 255) / 256, 256, 0, stream>>>(
            part, conv_b[li], outb, MN, Cout, __builtin_ctz(Cout),
            splitN, pstride, Hl, 2 * logW, logW, outPad);
    };
    auto launch_reduce_pool = [&](int li, int Hl, u16* outb, float* part, int splitN, int outPad) {
        int Cout = cout_arr[li];
        int M = 512 * Hl * Hl;
        size_t pstride = (size_t)M * Cout;
        int total4 = 512 * (Hl / 2) * (Hl / 2) * Cout / 4;
        reduce_pool<<<(total4 + 255) / 256, 256, 0, stream>>>(
            part, conv_b[li], outb, total4, Cout, splitN, pstride, Hl, outPad);
    };

    zh(R0, 34, 64);
    conv0_kernel<<<512 * 8, 256, 0, stream>>>(x, conv_w[0], conv_b[0], R0);

    zh(R1, 18, 64);
    launch_conv(1, 32, R0, R1, nullptr, 1, 0, 1);      // L1 + pool -> R1 p18,64
    zh(R0, 18, 128);
    launch_conv(2, 16, R1, R0, nullptr, 1, 1, 0);      // L2 -> R0 p18,128
    zh(R1, 10, 128);
    launch_conv(3, 16, R0, R1, nullptr, 1, 0, 1);      // L3 + pool -> R1 p10,128
    zh(R0, 10, 256);
    launch_conv(4, 8, R1, R0, nullptr, 1, 1, 0);       // L4 -> R0 p10,256
    zh(R1, 10, 256);
    launch_conv(5, 8, R0, R1, nullptr, 1, 1, 0);       // L5 -> R1 p10,256
    zh(R0, 6, 256);
    launch_conv(6, 8, R1, R0, nullptr, 1, 0, 1);       // L6 + pool -> R0 p6,256
    zh(R1, 6, 512);
    launch_conv(7, 4, R0, R1, PB, 2, 1, 0);            // L7 partials -> PB
    launch_reduce(7, 4, R1, PB, 2, 1);                 //   -> R1 p6,512
    zh(R0, 6, 512);
    launch_conv(8, 4, R1, R0, PA, 2, 1, 0);            // L8 -> PA
    launch_reduce(8, 4, R0, PA, 2, 1);                 //   -> R0 p6,512
    zh(R1, 4, 512);
    launch_conv(9, 4, R0, R1, PB, 2, 0, 0);            // L9 -> PB
    launch_reduce_pool(9, 4, R1, PB, 2, 1);            //   + pool -> R1 p4,512
    zh(R0, 4, 512);
    launch_conv(10, 2, R1, R0, PA, 8, 1, 0);           // L10 -> PA
    launch_reduce(10, 2, R0, PA, 8, 1);                //   -> R0 p4,512
    zh(R1, 4, 512);
    launch_conv(11, 2, R0, R1, PB, 8, 1, 0);           // L11 -> PB
    launch_reduce(11, 2, R1, PB, 8, 1);                //   -> R1 p4,512
    launch_conv(12, 2, R1, R0, PA, 8, 0, 0);           // L12 -> PA
    launch_reduce_pool(12, 2, R0, PA, 8, 0);           //   + pool -> feat = R0 [512,512]

    u16* feat = R0;
    gemm64<true, true><<<(512 / 64) * (256 / 64), 256, 0, stream>>>(
        feat, wtl1, lin1_b, hbuf, 512, 256, 512);
    gemm64<false, false><<<(512 / 64) * (128 / 64), 256, 0, stream>>>(
        hbuf, wtl2, lin2_b, lowbuf, 512, 128, 256);
    graph_tile<<<64, 256, 0, stream>>>(lowbuf, target, out + 5120, out + 5120 + 262144);
    cls_kernel<<<128, 256, 0, stream>>>(feat, cls_w, cls_b, out);
}

// Round 10
// 858.924 us; speedup vs baseline: 1.4810x; 1.0023x over previous
//
#include <hip/hip_runtime.h>

typedef unsigned short u16;
typedef __bf16 bf16x8 __attribute__((ext_vector_type(8)));
typedef float floatx4 __attribute__((ext_vector_type(4)));

__device__ inline u16 f2bf(float f) {
    unsigned int u = __float_as_uint(f);
    unsigned int r = (u + 0x7FFFu + ((u >> 16) & 1u)) >> 16;
    return (u16)r;
}
__device__ inline float bf2f(u16 h) {
    return __uint_as_float(((unsigned int)h) << 16);
}

// async global->LDS, 16B per lane. LDS dest must be wave-uniform base + lane*16.
__device__ __forceinline__ void async_copy16(u16* lds, const u16* g) {
    __builtin_amdgcn_global_load_lds(
        (const __attribute__((address_space(1))) unsigned int*)(uintptr_t)g,
        (__attribute__((address_space(3))) unsigned int*)(unsigned int)(uintptr_t)lds,
        16, 0, 0);
}

// ---------------------------------------------------------------------------
// zero ONLY the 1-px halo ring of a padded NHWC buffer [512][Hp][Hp][C]
// total8 = 512 * (4*Hp-4) * C/8
// ---------------------------------------------------------------------------
__global__ void zero_halo(u16* __restrict__ buf, int Hp, int C, int total8)
{
    int i = blockIdx.x * 256 + threadIdx.x;
    if (i >= total8) return;
    int c8 = i % (C / 8);
    int p  = i / (C / 8);
    int ring = 4 * Hp - 4;
    int h = p % ring;
    int b = p / ring;
    int y, x;
    if (h < Hp)              { y = 0;              x = h; }
    else if (h < 2 * Hp)     { y = Hp - 1;         x = h - Hp; }
    else if (h < 3 * Hp - 2) { y = h - 2 * Hp + 1; x = 0; }
    else                     { y = h - 3 * Hp + 3; x = Hp - 1; }
    uint4 z = make_uint4(0u, 0u, 0u, 0u);
    *(uint4*)(buf + ((size_t)((b * Hp + y) * Hp + x) * C) + c8 * 8) = z;
}

// ---------------------------------------------------------------------------
// Layer 0: direct conv 3->64, 32x32, output PADDED NHWC [512][34][34][64]
// ---------------------------------------------------------------------------
__global__ __launch_bounds__(256) void conv0_kernel(
    const float* __restrict__ x, const float* __restrict__ w,
    const float* __restrict__ bias, u16* __restrict__ out)
{
    __shared__ __align__(16) float xs[3][6][36];
    const int t  = threadIdx.x;
    const int b  = blockIdx.x >> 3;
    const int y0 = (blockIdx.x & 7) * 4;

    for (int i = t; i < 3 * 6 * 36; i += 256) {
        int ci  = i / 216;
        int rem = i % 216;
        int r   = rem / 36;
        int c   = rem % 36;
        int gy  = y0 - 1 + r;
        int gx  = c - 1;
        float v = 0.f;
        if ((unsigned)gy < 32u && (unsigned)gx < 32u)
            v = x[((b * 3 + ci) * 32 + gy) * 32 + gx];
        xs[ci][r][c] = v;
    }
    const int lane = t & 63;
    const int wv   = t >> 6;
    float wr[27];
    #pragma unroll
    for (int k = 0; k < 27; k++) wr[k] = w[lane * 27 + k];
    const float bz = bias[lane];
    __syncthreads();

    const int y = y0 + wv;
    u16* orow = out + ((size_t)((b * 34 + y + 1) * 34 + 1) * 64) + lane;
    for (int xg = 0; xg < 32; xg += 4) {
        float a0 = bz, a1 = bz, a2 = bz, a3 = bz;
        #pragma unroll
        for (int ci = 0; ci < 3; ci++) {
            #pragma unroll
            for (int rr = 0; rr < 3; rr++) {
                const float* row = &xs[ci][wv + rr][0];
                float4 c03 = *(const float4*)(row + xg);
                float2 c45 = *(const float2*)(row + xg + 4);
                float w0 = wr[ci * 9 + rr * 3 + 0];
                float w1 = wr[ci * 9 + rr * 3 + 1];
                float w2 = wr[ci * 9 + rr * 3 + 2];
                a0 += c03.x * w0 + c03.y * w1 + c03.z * w2;
                a1 += c03.y * w0 + c03.z * w1 + c03.w * w2;
                a2 += c03.z * w0 + c03.w * w1 + c45.x * w2;
                a3 += c03.w * w0 + c45.x * w1 + c45.y * w2;
            }
        }
        orow[(xg + 0) * 64] = f2bf(fmaxf(a0, 0.f));
        orow[(xg + 1) * 64] = f2bf(fmaxf(a1, 0.f));
        orow[(xg + 2) * 64] = f2bf(fmaxf(a2, 0.f));
        orow[(xg + 3) * 64] = f2bf(fmaxf(a3, 0.f));
    }
}

// ---------------------------------------------------------------------------
__global__ void repack_w(const float* __restrict__ w, u16* __restrict__ wt,
                         int Cin, int total)
{
    int i = blockIdx.x * 256 + threadIdx.x;
    if (i >= total) return;
    int ci = i % Cin;
    int rest = i / Cin;
    int s = rest % 9;
    int co = rest / 9;
    wt[i] = f2bf(w[(co * Cin + ci) * 9 + s]);
}

__global__ void repack_lin(const float* __restrict__ w, u16* __restrict__ wt,
                           int K, int N, int total)
{
    int i = blockIdx.x * 256 + threadIdx.x;
    if (i >= total) return;
    int n = i % N, k = i / N;
    wt[(size_t)n * K + k] = f2bf(w[(size_t)k * N + n]);
}

// ---------------------------------------------------------------------------
// Conv shift-GEMM, bf16 MFMA 16x16x32. Padded input, global_load_lds staging,
// XOR-8 swizzle via global source permutation, incremental SALU offsets,
// fused-pool epilogue (W=32/16/8/4 variants), XCD-aware tile swizzle.
// ---------------------------------------------------------------------------
template <int BN>
__global__ __launch_bounds__(256) void conv_gemm(
    const u16* __restrict__ in, const u16* __restrict__ wt,
    const float* __restrict__ bias, u16* __restrict__ out,
    float* __restrict__ partial, size_t pstride,
    int H, int Cin, int Cout, int logHW, int logW, int splitN,
    int outPad, int poolMode)
{
    constexpr int BM = 128, BK = 64;
    constexpr int NT   = BN / 32;
    constexpr int NB_A = 4;
    constexpr int NB_B = BN / 32;
    __shared__ u16 As[BM * BK];
    __shared__ u16 Bs[BN * BK];

    const int Nblocks = Cout / BN;
    const int per = gridDim.x >> 3;
    const int bid = (blockIdx.x & 7) * per + (blockIdx.x >> 3);
    const int sp   = bid % splitN;
    const int tile = bid / splitN;
    const int m0 = (tile / Nblocks) * BM;
    const int n0 = (tile % Nblocks) * BN;

    const int t    = threadIdx.x;
    const int lane = t & 63;
    const int wave = t >> 6;
    const int quad = lane >> 4;
    const int l16  = lane & 15;
    const int wm   = wave >> 1;
    const int wn   = wave & 1;
    const int W    = H;
    const int Wp   = H + 2;
    const int HW   = 1 << logHW;
    const int col8 = t & 7;
    const int r0   = t >> 3;
    const int scol = col8 ^ (r0 & 7);

    const int CinB = Cin * 2;

    int vA[NB_A];
    #pragma unroll
    for (int j = 0; j < NB_A; j++) {
        int m  = m0 + r0 + 32 * j;
        int b  = m >> logHW;
        int rm = m & (HW - 1);
        int y  = rm >> logW;
        int xx = rm & (W - 1);
        vA[j] = ((b * Wp + y + 1) * Wp + xx + 1) * CinB + scol * 16;
    }
    int vB[NB_B];
    #pragma unroll
    for (int j = 0; j < NB_B; j++)
        vB[j] = (n0 + r0 + 32 * j) * 9 * CinB + scol * 16;

    const int logKB = (Cin == 64) ? 0 : (Cin == 128) ? 1 : (Cin == 256) ? 2 : 3;
    const int KB  = 1 << logKB;
    const int T   = 9 * KB;
    const int len = T / splitN;
    const int it0 = sp * len;

    int s0 = it0 >> logKB;
    int c3 = s0 - (s0 / 3) * 3;
    int ta = ((s0 / 3 - 1) * Wp + (c3 - 1)) * CinB;
    int kb = (it0 & (KB - 1)) * 128;
    int tb = it0 * 128;

    u16* const ldsA = As + t * 8;
    u16* const ldsB = Bs + t * 8;
    const char* const inB = (const char*)in;
    const char* const wtB = (const char*)wt;

    floatx4 acc[4][NT];
    #pragma unroll
    for (int i = 0; i < 4; i++)
        #pragma unroll
        for (int j = 0; j < NT; j++)
            acc[i][j] = (floatx4){0.f, 0.f, 0.f, 0.f};

    const int sw = (l16 & 7) * 8;

    for (int it = 0; it < len; it++) {
        const int ua = ta + kb;
        #pragma unroll
        for (int j = 0; j < NB_A; j++)
            async_copy16(ldsA + j * 2048, (const u16*)(inB + (ua + vA[j])));
        #pragma unroll
        for (int j = 0; j < NB_B; j++)
            async_copy16(ldsB + j * 2048, (const u16*)(wtB + (tb + vB[j])));
        __syncthreads();
        #pragma unroll
        for (int kk = 0; kk < BK; kk += 32) {
            bf16x8 af[4], bfv[NT];
            int cbo = kk + quad * 8;
            #pragma unroll
            for (int mt = 0; mt < 4; mt++)
                af[mt] = *(const bf16x8*)(As + (wm * 64 + mt * 16 + l16) * 64 + (cbo ^ sw));
            #pragma unroll
            for (int nt = 0; nt < NT; nt++)
                bfv[nt] = *(const bf16x8*)(Bs + (wn * (BN / 2) + nt * 16 + l16) * 64 + (cbo ^ sw));
            #pragma unroll
            for (int mt = 0; mt < 4; mt++)
                #pragma unroll
                for (int nt = 0; nt < NT; nt++)
                    acc[mt][nt] = __builtin_amdgcn_mfma_f32_16x16x32_bf16(
                        af[mt], bfv[nt], acc[mt][nt], 0, 0, 0);
        }
        __syncthreads();
        tb += 128;
        kb += 128;
        if (kb == CinB) {
            kb = 0;
            ta += (c3 == 2) ? (Wp - 2) * CinB : CinB;
            c3 = (c3 == 2) ? 0 : c3 + 1;
        }
    }

    if (splitN > 1) {
        float* pout = partial + (size_t)sp * pstride;
        #pragma unroll
        for (int mt = 0; mt < 4; mt++)
            #pragma unroll
            for (int nt = 0; nt < NT; nt++)
                #pragma unroll
                for (int r = 0; r < 4; r++) {
                    int mg = m0 + wm * 64 + mt * 16 + quad * 4 + r;
                    int ng = n0 + wn * (BN / 2) + nt * 16 + l16;
                    pout[(size_t)mg * Cout + ng] = acc[mt][nt][r];
                }
        return;
    }

    if (poolMode) {
        const int Hpo = (H >> 1) + 2;
        #pragma unroll
        for (int nt = 0; nt < NT; nt++) {
            int ng = n0 + wn * (BN / 2) + nt * 16 + l16;
            float bz = bias[ng];
            if (logW == 5) {            // W=32: y-partner = mt+2, in-lane
                #pragma unroll
                for (int mt = 0; mt < 2; mt++)
                    #pragma unroll
                    for (int rp = 0; rp < 2; rp++) {
                        float v = fmaxf(
                            fmaxf(acc[mt][nt][2 * rp], acc[mt][nt][2 * rp + 1]),
                            fmaxf(acc[mt + 2][nt][2 * rp], acc[mt + 2][nt][2 * rp + 1]));
                        int m1 = m0 + wm * 64 + mt * 16 + quad * 4 + 2 * rp;
                        int b  = m1 >> logHW;
                        int rm = m1 & (HW - 1);
                        int yp = (rm >> logW) >> 1;
                        int xp = (rm & (W - 1)) >> 1;
                        out[(size_t)((b * Hpo + yp + 1) * Hpo + xp + 1) * Cout + ng] =
                            f2bf(fmaxf(v + bz, 0.f));
                    }
            } else if (logW == 4) {     // W=16: y-partner = mt+1, in-lane
                #pragma unroll
                for (int mtp = 0; mtp < 2; mtp++)
                    #pragma unroll
                    for (int rp = 0; rp < 2; rp++) {
                        int mt = 2 * mtp;
                        float v = fmaxf(
                            fmaxf(acc[mt][nt][2 * rp], acc[mt][nt][2 * rp + 1]),
                            fmaxf(acc[mt + 1][nt][2 * rp], acc[mt + 1][nt][2 * rp + 1]));
                        int m1 = m0 + wm * 64 + mt * 16 + quad * 4 + 2 * rp;
                        int b  = m1 >> logHW;
                        int rm = m1 & (HW - 1);
                        int yp = (rm >> logW) >> 1;
                        int xp = (rm & (W - 1)) >> 1;
                        out[(size_t)((b * Hpo + yp + 1) * Hpo + xp + 1) * Cout + ng] =
                            f2bf(fmaxf(v + bz, 0.f));
                    }
            } else if (logW == 3) {     // W=8: y-partner = quad+2 via shfl32
                #pragma unroll
                for (int mt = 0; mt < 4; mt++)
                    #pragma unroll
                    for (int rp = 0; rp < 2; rp++) {
                        float a = fmaxf(acc[mt][nt][2 * rp], acc[mt][nt][2 * rp + 1]);
                        float p = __shfl_xor(a, 32, 64);
                        float v = fmaxf(a, p);
                        if (quad < 2) {
                            int m1 = m0 + wm * 64 + mt * 16 + quad * 4 + 2 * rp;
                            int b  = m1 >> logHW;
                            int rm = m1 & (HW - 1);
                            int yp = (rm >> logW) >> 1;
                            int xp = (rm & (W - 1)) >> 1;
                            out[(size_t)((b * Hpo + yp + 1) * Hpo + xp + 1) * Cout + ng] =
                                f2bf(fmaxf(v + bz, 0.f));
                        }
                    }
            } else {                    // W=4: y-partner = quad^1 via shfl16
                #pragma unroll
                for (int mt = 0; mt < 4; mt++)
                    #pragma unroll
                    for (int rp = 0; rp < 2; rp++) {
                        float a = fmaxf(acc[mt][nt][2 * rp], acc[mt][nt][2 * rp + 1]);
                        float p = __shfl_xor(a, 16, 64);
                        float v = fmaxf(a, p);
                        if (!(quad & 1)) {
                            int m1 = m0 + wm * 64 + mt * 16 + quad * 4 + 2 * rp;
                            int b  = m1 >> logHW;
                            int rm = m1 & (HW - 1);
                            int yp = (rm >> logW) >> 1;
                            int xp = (rm & (W - 1)) >> 1;
                            out[(size_t)((b * Hpo + yp + 1) * Hpo + xp + 1) * Cout + ng] =
                                f2bf(fmaxf(v + bz, 0.f));
                        }
                    }
            }
        }
        return;
    }

    #pragma unroll
    for (int mt = 0; mt < 4; mt++) {
        #pragma unroll
        for (int r = 0; r < 4; r++) {
            int mg = m0 + wm * 64 + mt * 16 + quad * 4 + r;
            size_t obase;
            if (outPad) {
                int b  = mg >> logHW;
                int rm = mg & (HW - 1);
                int y  = rm >> logW;
                int xx = rm & (W - 1);
                obase = (size_t)((b * Wp + y + 1) * Wp + xx + 1) * Cout;
            } else {
                obase = (size_t)mg * Cout;
            }
            #pragma unroll
            for (int nt = 0; nt < NT; nt++) {
                int ng = n0 + wn * (BN / 2) + nt * 16 + l16;
                float v = acc[mt][nt][r] + bias[ng];
                out[obase + ng] = f2bf(fmaxf(v, 0.f));
            }
        }
    }
}

// sum split partials + bias + relu -> bf16 NHWC (padded out optional)
__global__ void reduce_split(const float* __restrict__ partial,
                             const float* __restrict__ bias, u16* __restrict__ out,
                             int MN, int C, int logC, int splitN, size_t pstride,
                             int H, int logHW, int logW, int outPad)
{
    int i4 = (blockIdx.x * 256 + threadIdx.x) * 4;
    if (i4 >= MN) return;
    float4 s = *(const float4*)(partial + i4);
    for (int sp = 1; sp < splitN; sp++) {
        float4 p = *(const float4*)(partial + (size_t)sp * pstride + i4);
        s.x += p.x; s.y += p.y; s.z += p.z; s.w += p.w;
    }
    int n = i4 & (C - 1);
    int m = i4 >> logC;
    size_t obase;
    if (outPad) {
        int Wp = H + 2;
        int b  = m >> logHW;
        int rm = m & ((1 << logHW) - 1);
        int y  = rm >> logW;
        int xx = rm & (H - 1);
        obase = (size_t)((b * Wp + y + 1) * Wp + xx + 1) * C;
    } else {
        obase = (size_t)m * C;
    }
    ushort4 o;
    o.x = f2bf(fmaxf(s.x + bias[n + 0], 0.f));
    o.y = f2bf(fmaxf(s.y + bias[n + 1], 0.f));
    o.z = f2bf(fmaxf(s.z + bias[n + 2], 0.f));
    o.w = f2bf(fmaxf(s.w + bias[n + 3], 0.f));
    *(ushort4*)(out + obase + n) = o;
}

// sum split partials + bias + relu + 2x2 maxpool -> bf16 (padded optional)
__global__ void reduce_pool(const float* __restrict__ partial,
                            const float* __restrict__ bias, u16* __restrict__ out,
                            int total4, int C, int splitN, size_t pstride,
                            int H, int outPad)
{
    int idx = blockIdx.x * 256 + threadIdx.x;
    if (idx >= total4) return;
    int c4 = idx % (C / 4);
    int p  = idx / (C / 4);
    int Ho = H >> 1;
    int xp = p % Ho; p /= Ho;
    int yp = p % Ho;
    int b  = p / Ho;
    int n  = c4 * 4;
    float4 best;
    bool first = true;
    #pragma unroll
    for (int dy = 0; dy < 2; dy++)
        #pragma unroll
        for (int dx = 0; dx < 2; dx++) {
            int m = (b * H + 2 * yp + dy) * H + 2 * xp + dx;
            const float* q = partial + (size_t)m * C + n;
            float4 s = *(const float4*)q;
            for (int sp = 1; sp < splitN; sp++) {
                float4 pp = *(const float4*)(q + (size_t)sp * pstride);
                s.x += pp.x; s.y += pp.y; s.z += pp.z; s.w += pp.w;
            }
            if (first) { best = s; first = false; }
            else {
                best.x = fmaxf(best.x, s.x); best.y = fmaxf(best.y, s.y);
                best.z = fmaxf(best.z, s.z); best.w = fmaxf(best.w, s.w);
            }
        }
    size_t obase;
    if (outPad) {
        int Hpo = Ho + 2;
        obase = (size_t)((b * Hpo + yp + 1) * Hpo + xp + 1) * C;
    } else {
        obase = (size_t)((b * Ho + yp) * Ho + xp) * C;
    }
    ushort4 o;
    o.x = f2bf(fmaxf(best.x + bias[n + 0], 0.f));
    o.y = f2bf(fmaxf(best.y + bias[n + 1], 0.f));
    o.z = f2bf(fmaxf(best.z + bias[n + 2], 0.f));
    o.w = f2bf(fmaxf(best.w + bias[n + 3], 0.f));
    *(ushort4*)(out + obase + n) = o;
}

// ---------------------------------------------------------------------------
// Generic small GEMM: out[M,N] = act(A[M,K](bf16) @ Bt[N,K](bf16)^T + bias)
// ---------------------------------------------------------------------------
template <bool RELU, bool OUTBF>
__global__ __launch_bounds__(256) void gemm64(
    const u16* __restrict__ A, const u16* __restrict__ Bt,
    const float* __restrict__ bias, void* __restrict__ outv,
    int M, int N, int K)
{
    constexpr int LDP = 72;
    __shared__ u16 As[64 * LDP];
    __shared__ u16 Bs[64 * LDP];

    const int nb = N >> 6;
    const int m0 = (blockIdx.x / nb) * 64;
    const int n0 = (blockIdx.x % nb) * 64;
    const int t = threadIdx.x, lane = t & 63, wave = t >> 6;
    const int quad = lane >> 4, l16 = lane & 15;
    const int wm = wave >> 1, wn = wave & 1;
    const int col8 = t & 7, r0 = t >> 3;

    floatx4 acc[2][2];
    #pragma unroll
    for (int i = 0; i < 2; i++)
        #pragma unroll
        for (int j = 0; j < 2; j++)
            acc[i][j] = (floatx4){0.f, 0.f, 0.f, 0.f};

    for (int kb = 0; kb < K; kb += 64) {
        #pragma unroll
        for (int j = 0; j < 2; j++) {
            int row = r0 + 32 * j;
            *(uint4*)(As + row * LDP + col8 * 8) =
                *(const uint4*)(A + (size_t)(m0 + row) * K + kb + col8 * 8);
            *(uint4*)(Bs + row * LDP + col8 * 8) =
                *(const uint4*)(Bt + (size_t)(n0 + row) * K + kb + col8 * 8);
        }
        __syncthreads();
        #pragma unroll
        for (int kk = 0; kk < 64; kk += 32) {
            bf16x8 af[2], bfv[2];
            #pragma unroll
            for (int mt = 0; mt < 2; mt++)
                af[mt] = *(const bf16x8*)(As + (wm * 32 + mt * 16 + l16) * LDP + kk + quad * 8);
            #pragma unroll
            for (int nt = 0; nt < 2; nt++)
                bfv[nt] = *(const bf16x8*)(Bs + (wn * 32 + nt * 16 + l16) * LDP + kk + quad * 8);
            #pragma unroll
            for (int mt = 0; mt < 2; mt++)
                #pragma unroll
                for (int nt = 0; nt < 2; nt++)
                    acc[mt][nt] = __builtin_amdgcn_mfma_f32_16x16x32_bf16(
                        af[mt], bfv[nt], acc[mt][nt], 0, 0, 0);
        }
        __syncthreads();
    }
    #pragma unroll
    for (int mt = 0; mt < 2; mt++) {
        #pragma unroll
        for (int nt = 0; nt < 2; nt++) {
            #pragma unroll
            for (int r = 0; r < 4; r++) {
                int mg = m0 + wm * 32 + mt * 16 + quad * 4 + r;
                int ng = n0 + wn * 32 + nt * 16 + l16;
                float v = acc[mt][nt][r] + bias[ng];
                if (RELU) v = fmaxf(v, 0.f);
                if (OUTBF) ((u16*)outv)[(size_t)mg * N + ng] = f2bf(v);
                else       ((float*)outv)[(size_t)mg * N + ng] = v;
            }
        }
    }
}

// ---------------------------------------------------------------------------
__global__ __launch_bounds__(256) void graph_tile(
    const float* __restrict__ low, const int* __restrict__ target,
    float* __restrict__ gpre, float* __restrict__ ggt)
{
    __shared__ float Al[64 * 132];
    __shared__ float Bl[128 * 68];
    const int t = threadIdx.x;
    const int gr0 = (blockIdx.x >> 3) * 64;
    const int gc0 = (blockIdx.x & 7) * 64;

    #pragma unroll
    for (int j = 0; j < 32; j++) {
        int flat = t + 256 * j;
        int k = flat & 127;
        int rc = flat >> 7;
        Al[rc * 132 + k] = low[(size_t)(gr0 + rc) * 128 + k];
        Bl[k * 68 + rc]  = low[(size_t)(gc0 + rc) * 128 + k];
    }
    __syncthreads();

    const int tx = t & 15, ty = t >> 4;
    float acc[4][4];
    #pragma unroll
    for (int r = 0; r < 4; r++)
        #pragma unroll
        for (int c = 0; c < 4; c++) acc[r][c] = 0.f;

    for (int k = 0; k < 128; k++) {
        float a[4], b[4];
        #pragma unroll
        for (int r = 0; r < 4; r++) a[r] = Al[(ty * 4 + r) * 132 + k];
        #pragma unroll
        for (int c = 0; c < 4; c++) b[c] = Bl[k * 68 + tx * 4 + c];
        #pragma unroll
        for (int r = 0; r < 4; r++)
            #pragma unroll
            for (int c = 0; c < 4; c++) acc[r][c] += a[r] * b[c];
    }
    #pragma unroll
    for (int r = 0; r < 4; r++) {
        int row = gr0 + ty * 4 + r;
        int tr  = target[row];
        float4 gp, gg;
        float* pp = (float*)&gp;
        float* gg_ = (float*)&gg;
        #pragma unroll
        for (int c = 0; c < 4; c++) {
            pp[c]  = 1.f / (1.f + __expf(-acc[r][c]));
            gg_[c] = (tr == target[gc0 + tx * 4 + c]) ? 1.f : 0.f;
        }
        *(float4*)(gpre + (size_t)row * 512 + gc0 + tx * 4) = gp;
        *(float4*)(ggt  + (size_t)row * 512 + gc0 + tx * 4) = gg;
    }
}

// ---------------------------------------------------------------------------
__global__ __launch_bounds__(256) void cls_kernel(
    const u16* __restrict__ feat, const float* __restrict__ w,
    const float* __restrict__ bias, float* __restrict__ out)
{
    __shared__ float ws[5120];
    const int t = threadIdx.x;
    for (int i = t; i < 5120; i += 256) ws[i] = w[i];
    __syncthreads();
    const int lane = t & 63;
    const int row  = blockIdx.x * 4 + (t >> 6);
    float a[10];
    #pragma unroll
    for (int j = 0; j < 10; j++) a[j] = 0.f;
    #pragma unroll
    for (int i = 0; i < 8; i++) {
        int k = i * 64 + lane;
        float f = bf2f(feat[(size_t)row * 512 + k]);
        #pragma unroll
        for (int j = 0; j < 10; j++) a[j] += f * ws[k * 10 + j];
    }
    #pragma unroll
    for (int j = 0; j < 10; j++)
        #pragma unroll
        for (int off = 32; off > 0; off >>= 1)
            a[j] += __shfl_down(a[j], off, 64);
    if (lane == 0) {
        #pragma unroll
        for (int j = 0; j < 10; j++) out[row * 10 + j] = a[j] + bias[j];
    }
}

// ---------------------------------------------------------------------------
extern "C" void kernel_launch(void* const* d_in, const int* in_sizes, int n_in,
                              void* d_out, int out_size, void* d_ws, size_t ws_size,
                              hipStream_t stream)
{
    const float* x      = (const float*)d_in[0];
    const int*   target = (const int*)d_in[1];
    const float* conv_w[13];
    const float* conv_b[13];
    for (int i = 0; i < 13; i++) {
        conv_w[i] = (const float*)d_in[2 + 2 * i];
        conv_b[i] = (const float*)d_in[3 + 2 * i];
    }
    const float* lin1_w = (const float*)d_in[28];
    const float* lin1_b = (const float*)d_in[29];
    const float* lin2_w = (const float*)d_in[30];
    const float* lin2_b = (const float*)d_in[31];
    const float* cls_w  = (const float*)d_in[32];
    const float* cls_b  = (const float*)d_in[33];
    float* out = (float*)d_out;

    static const int cin_arr[13]  = {3, 64, 64, 128, 128, 256, 256, 256, 512, 512, 512, 512, 512};
    static const int cout_arr[13] = {64, 64, 128, 128, 256, 256, 256, 512, 512, 512, 512, 512, 512};

    char* ws = (char*)d_ws;
    size_t off = 0;
    const size_t R0SZ = (size_t)512 * 34 * 34 * 64 * 2;
    const size_t R1SZ = (size_t)512 * 34 * 34 * 64 * 2;
    char* R0raw = ws + off; off += R0SZ;
    char* R1raw = ws + off; off += R1SZ;
    u16* R0 = (u16*)R0raw;
    u16* R1 = (u16*)R1raw;
    float* PA = (float*)(R0raw + 20971520);
    float* PB = (float*)(R1raw + 20971520);
    u16* wt[13];
    for (int i = 1; i < 13; i++) {
        wt[i] = (u16*)(ws + off);
        off += (size_t)cout_arr[i] * 9 * cin_arr[i] * 2;
    }
    u16* wtl1 = (u16*)(ws + off); off += (size_t)256 * 512 * 2;
    u16* wtl2 = (u16*)(ws + off); off += (size_t)128 * 256 * 2;
    u16* hbuf = (u16*)(ws + off); off += (size_t)512 * 256 * 2;
    float* lowbuf = (float*)(ws + off); off += (size_t)512 * 128 * 4;

    for (int i = 1; i < 13; i++) {
        int total = cout_arr[i] * 9 * cin_arr[i];
        repack_w<<<(total + 255) / 256, 256, 0, stream>>>(conv_w[i], wt[i], cin_arr[i], total);
    }
    repack_lin<<<(512 * 256) / 256, 256, 0, stream>>>(lin1_w, wtl1, 512, 256, 512 * 256);
    repack_lin<<<(256 * 128) / 256, 256, 0, stream>>>(lin2_w, wtl2, 256, 128, 256 * 128);

    auto zh = [&](u16* buf, int Hp, int C) {
        int total8 = 512 * (4 * Hp - 4) * (C / 8);
        zero_halo<<<(total8 + 255) / 256, 256, 0, stream>>>(buf, Hp, C, total8);
    };
    auto launch_conv = [&](int li, int Hl, int bn, u16* inb, u16* outb, float* part,
                           int splitN, int outPad, int poolMode) {
        int Cin = cin_arr[li], Cout = cout_arr[li];
        int M = 512 * Hl * Hl;
        int logW = __builtin_ctz(Hl);
        int logHW = 2 * logW;
        size_t pstride = (size_t)M * Cout;
        int grid = (M / 128) * (Cout / bn) * splitN;
        if (bn == 128) {
            conv_gemm<128><<<grid, 256, 0, stream>>>(
                inb, wt[li], conv_b[li], outb, part, pstride,
                Hl, Cin, Cout, logHW, logW, splitN, outPad, poolMode);
        } else {
            conv_gemm<64><<<grid, 256, 0, stream>>>(
                inb, wt[li], conv_b[li], outb, part, pstride,
                Hl, Cin, Cout, logHW, logW, splitN, outPad, poolMode);
        }
    };
    auto launch_reduce = [&](int li, int Hl, u16* outb, float* part, int splitN, int outPad) {
        int Cout = cout_arr[li];
        int M = 512 * Hl * Hl;
        int logW = __builtin_ctz(Hl);
        size_t pstride = (size_t)M * Cout;
        int MN = M * Cout;
        reduce_split<<<(MN / 4 + 255) / 256, 256, 0, stream>>>(
            part, conv_b[li], outb, MN, Cout, __builtin_ctz(Cout),
            splitN, pstride, Hl, 2 * logW, logW, outPad);
    };
    auto launch_reduce_pool = [&](int li, int Hl, u16* outb, float* part, int splitN, int outPad) {
        int Cout = cout_arr[li];
        int M = 512 * Hl * Hl;
        size_t pstride = (size_t)M * Cout;
        int total4 = 512 * (Hl / 2) * (Hl / 2) * Cout / 4;
        reduce_pool<<<(total4 + 255) / 256, 256, 0, stream>>>(
            part, conv_b[li], outb, total4, Cout, splitN, pstride, Hl, outPad);
    };

    zh(R0, 34, 64);
    conv0_kernel<<<512 * 8, 256, 0, stream>>>(x, conv_w[0], conv_b[0], R0);

    zh(R1, 18, 64);
    launch_conv(1, 32, 64, R0, R1, nullptr, 1, 0, 1);   // L1 + pool -> R1 p18,64
    zh(R0, 18, 128);
    launch_conv(2, 16, 128, R1, R0, nullptr, 1, 1, 0);  // L2 -> R0 p18,128
    zh(R1, 10, 128);
    launch_conv(3, 16, 128, R0, R1, nullptr, 1, 0, 1);  // L3 + pool -> R1 p10,128
    zh(R0, 10, 256);
    launch_conv(4, 8, 128, R1, R0, nullptr, 1, 1, 0);   // L4 -> R0 p10,256
    zh(R1, 10, 256);
    launch_conv(5, 8, 128, R0, R1, nullptr, 1, 1, 0);   // L5 -> R1 p10,256
    zh(R0, 6, 256);
    launch_conv(6, 8, 128, R1, R0, nullptr, 1, 0, 1);   // L6 + pool -> R0 p6,256
    zh(R1, 6, 512);
    launch_conv(7, 4, 64, R0, R1, nullptr, 1, 1, 0);    // L7 direct -> R1 p6,512
    zh(R0, 6, 512);
    launch_conv(8, 4, 64, R1, R0, nullptr, 1, 1, 0);    // L8 direct -> R0 p6,512
    zh(R1, 4, 512);
    launch_conv(9, 4, 64, R0, R1, nullptr, 1, 0, 1);    // L9 + pool -> R1 p4,512
    zh(R0, 4, 512);
    launch_conv(10, 2, 64, R1, R0, PA, 4, 1, 0);        // L10 -> PA (split4)
    launch_reduce(10, 2, R0, PA, 4, 1);                 //   -> R0 p4,512
    zh(R1, 4, 512);
    launch_conv(11, 2, 64, R0, R1, PB, 4, 1, 0);        // L11 -> PB
    launch_reduce(11, 2, R1, PB, 4, 1);                 //   -> R1 p4,512
    launch_conv(12, 2, 64, R1, R0, PA, 4, 0, 0);        // L12 -> PA
    launch_reduce_pool(12, 2, R0, PA, 4, 0);            //   + pool -> feat = R0 [512,512]

    u16* feat = R0;
    gemm64<true, true><<<(512 / 64) * (256 / 64), 256, 0, stream>>>(
        feat, wtl1, lin1_b, hbuf, 512, 256, 512);
    gemm64<false, false><<<(512 / 64) * (128 / 64), 256, 0, stream>>>(
        hbuf, wtl2, lin2_b, lowbuf, 512, 128, 256);
    graph_tile<<<64, 256, 0, stream>>>(lowbuf, target, out + 5120, out + 5120 + 262144);
    cls_kernel<<<128, 256, 0, stream>>>(feat, cls_w, cls_b, out);
}

// Round 11
// 825.543 us; speedup vs baseline: 1.5409x; 1.0404x over previous
//
#include <hip/hip_runtime.h>

typedef unsigned short u16;
typedef __bf16 bf16x8 __attribute__((ext_vector_type(8)));
typedef float floatx4 __attribute__((ext_vector_type(4)));

__device__ inline u16 f2bf(float f) {
    unsigned int u = __float_as_uint(f);
    unsigned int r = (u + 0x7FFFu + ((u >> 16) & 1u)) >> 16;
    return (u16)r;
}
__device__ inline float bf2f(u16 h) {
    return __uint_as_float(((unsigned int)h) << 16);
}

// async global->LDS, 16B per lane. LDS dest must be wave-uniform base + lane*16.
__device__ __forceinline__ void async_copy16(u16* lds, const u16* g) {
    __builtin_amdgcn_global_load_lds(
        (const __attribute__((address_space(1))) unsigned int*)(uintptr_t)g,
        (__attribute__((address_space(3))) unsigned int*)(unsigned int)(uintptr_t)lds,
        16, 0, 0);
}

// ---------------------------------------------------------------------------
// zero ONLY the 1-px halo ring of a padded NHWC buffer [512][Hp][Hp][C]
// ---------------------------------------------------------------------------
__global__ void zero_halo(u16* __restrict__ buf, int Hp, int C, int total8)
{
    int i = blockIdx.x * 256 + threadIdx.x;
    if (i >= total8) return;
    int c8 = i % (C / 8);
    int p  = i / (C / 8);
    int ring = 4 * Hp - 4;
    int h = p % ring;
    int b = p / ring;
    int y, x;
    if (h < Hp)              { y = 0;              x = h; }
    else if (h < 2 * Hp)     { y = Hp - 1;         x = h - Hp; }
    else if (h < 3 * Hp - 2) { y = h - 2 * Hp + 1; x = 0; }
    else                     { y = h - 3 * Hp + 3; x = Hp - 1; }
    uint4 z = make_uint4(0u, 0u, 0u, 0u);
    *(uint4*)(buf + ((size_t)((b * Hp + y) * Hp + x) * C) + c8 * 8) = z;
}

// ---------------------------------------------------------------------------
// Layer 0: direct conv 3->64, 32x32, output PADDED NHWC [512][34][34][64]
// ---------------------------------------------------------------------------
__global__ __launch_bounds__(256) void conv0_kernel(
    const float* __restrict__ x, const float* __restrict__ w,
    const float* __restrict__ bias, u16* __restrict__ out)
{
    __shared__ __align__(16) float xs[3][6][36];
    const int t  = threadIdx.x;
    const int b  = blockIdx.x >> 3;
    const int y0 = (blockIdx.x & 7) * 4;

    for (int i = t; i < 3 * 6 * 36; i += 256) {
        int ci  = i / 216;
        int rem = i % 216;
        int r   = rem / 36;
        int c   = rem % 36;
        int gy  = y0 - 1 + r;
        int gx  = c - 1;
        float v = 0.f;
        if ((unsigned)gy < 32u && (unsigned)gx < 32u)
            v = x[((b * 3 + ci) * 32 + gy) * 32 + gx];
        xs[ci][r][c] = v;
    }
    const int lane = t & 63;
    const int wv   = t >> 6;
    float wr[27];
    #pragma unroll
    for (int k = 0; k < 27; k++) wr[k] = w[lane * 27 + k];
    const float bz = bias[lane];
    __syncthreads();

    const int y = y0 + wv;
    u16* orow = out + ((size_t)((b * 34 + y + 1) * 34 + 1) * 64) + lane;
    for (int xg = 0; xg < 32; xg += 4) {
        float a0 = bz, a1 = bz, a2 = bz, a3 = bz;
        #pragma unroll
        for (int ci = 0; ci < 3; ci++) {
            #pragma unroll
            for (int rr = 0; rr < 3; rr++) {
                const float* row = &xs[ci][wv + rr][0];
                float4 c03 = *(const float4*)(row + xg);
                float2 c45 = *(const float2*)(row + xg + 4);
                float w0 = wr[ci * 9 + rr * 3 + 0];
                float w1 = wr[ci * 9 + rr * 3 + 1];
                float w2 = wr[ci * 9 + rr * 3 + 2];
                a0 += c03.x * w0 + c03.y * w1 + c03.z * w2;
                a1 += c03.y * w0 + c03.z * w1 + c03.w * w2;
                a2 += c03.z * w0 + c03.w * w1 + c45.x * w2;
                a3 += c03.w * w0 + c45.x * w1 + c45.y * w2;
            }
        }
        orow[(xg + 0) * 64] = f2bf(fmaxf(a0, 0.f));
        orow[(xg + 1) * 64] = f2bf(fmaxf(a1, 0.f));
        orow[(xg + 2) * 64] = f2bf(fmaxf(a2, 0.f));
        orow[(xg + 3) * 64] = f2bf(fmaxf(a3, 0.f));
    }
}

// ---------------------------------------------------------------------------
__global__ void repack_w(const float* __restrict__ w, u16* __restrict__ wt,
                         int Cin, int total)
{
    int i = blockIdx.x * 256 + threadIdx.x;
    if (i >= total) return;
    int ci = i % Cin;
    int rest = i / Cin;
    int s = rest % 9;
    int co = rest / 9;
    wt[i] = f2bf(w[(co * Cin + ci) * 9 + s]);
}

__global__ void repack_lin(const float* __restrict__ w, u16* __restrict__ wt,
                           int K, int N, int total)
{
    int i = blockIdx.x * 256 + threadIdx.x;
    if (i >= total) return;
    int n = i % N, k = i / N;
    wt[(size_t)n * K + k] = f2bf(w[(size_t)k * N + n]);
}

// ---------------------------------------------------------------------------
// Conv shift-GEMM, bf16 MFMA 16x16x32. Padded input, global_load_lds staging,
// XOR-8 swizzle via global source permutation, incremental SALU offsets,
// fused-pool epilogue (W=32/16/8/4), XCD-aware tile swizzle, optional split-K.
// ---------------------------------------------------------------------------
template <int BN>
__global__ __launch_bounds__(256) void conv_gemm(
    const u16* __restrict__ in, const u16* __restrict__ wt,
    const float* __restrict__ bias, u16* __restrict__ out,
    float* __restrict__ partial, size_t pstride,
    int H, int Cin, int Cout, int logHW, int logW, int splitN,
    int outPad, int poolMode)
{
    constexpr int BM = 128, BK = 64;
    constexpr int NT   = BN / 32;
    constexpr int NB_A = 4;
    constexpr int NB_B = BN / 32;
    __shared__ u16 As[BM * BK];
    __shared__ u16 Bs[BN * BK];

    const int Nblocks = Cout / BN;
    const int per = gridDim.x >> 3;
    const int bid = (blockIdx.x & 7) * per + (blockIdx.x >> 3);
    const int sp   = bid % splitN;
    const int tile = bid / splitN;
    const int m0 = (tile / Nblocks) * BM;
    const int n0 = (tile % Nblocks) * BN;

    const int t    = threadIdx.x;
    const int lane = t & 63;
    const int wave = t >> 6;
    const int quad = lane >> 4;
    const int l16  = lane & 15;
    const int wm   = wave >> 1;
    const int wn   = wave & 1;
    const int W    = H;
    const int Wp   = H + 2;
    const int HW   = 1 << logHW;
    const int col8 = t & 7;
    const int r0   = t >> 3;
    const int scol = col8 ^ (r0 & 7);

    const int CinB = Cin * 2;

    int vA[NB_A];
    #pragma unroll
    for (int j = 0; j < NB_A; j++) {
        int m  = m0 + r0 + 32 * j;
        int b  = m >> logHW;
        int rm = m & (HW - 1);
        int y  = rm >> logW;
        int xx = rm & (W - 1);
        vA[j] = ((b * Wp + y + 1) * Wp + xx + 1) * CinB + scol * 16;
    }
    int vB[NB_B];
    #pragma unroll
    for (int j = 0; j < NB_B; j++)
        vB[j] = (n0 + r0 + 32 * j) * 9 * CinB + scol * 16;

    const int logKB = (Cin == 64) ? 0 : (Cin == 128) ? 1 : (Cin == 256) ? 2 : 3;
    const int KB  = 1 << logKB;
    const int T   = 9 * KB;
    const int len = T / splitN;
    const int it0 = sp * len;

    int s0 = it0 >> logKB;
    int c3 = s0 - (s0 / 3) * 3;
    int ta = ((s0 / 3 - 1) * Wp + (c3 - 1)) * CinB;
    int kb = (it0 & (KB - 1)) * 128;
    int tb = it0 * 128;

    u16* const ldsA = As + t * 8;
    u16* const ldsB = Bs + t * 8;
    const char* const inB = (const char*)in;
    const char* const wtB = (const char*)wt;

    floatx4 acc[4][NT];
    #pragma unroll
    for (int i = 0; i < 4; i++)
        #pragma unroll
        for (int j = 0; j < NT; j++)
            acc[i][j] = (floatx4){0.f, 0.f, 0.f, 0.f};

    const int sw = (l16 & 7) * 8;

    for (int it = 0; it < len; it++) {
        const int ua = ta + kb;
        #pragma unroll
        for (int j = 0; j < NB_A; j++)
            async_copy16(ldsA + j * 2048, (const u16*)(inB + (ua + vA[j])));
        #pragma unroll
        for (int j = 0; j < NB_B; j++)
            async_copy16(ldsB + j * 2048, (const u16*)(wtB + (tb + vB[j])));
        __syncthreads();
        #pragma unroll
        for (int kk = 0; kk < BK; kk += 32) {
            bf16x8 af[4], bfv[NT];
            int cbo = kk + quad * 8;
            #pragma unroll
            for (int mt = 0; mt < 4; mt++)
                af[mt] = *(const bf16x8*)(As + (wm * 64 + mt * 16 + l16) * 64 + (cbo ^ sw));
            #pragma unroll
            for (int nt = 0; nt < NT; nt++)
                bfv[nt] = *(const bf16x8*)(Bs + (wn * (BN / 2) + nt * 16 + l16) * 64 + (cbo ^ sw));
            #pragma unroll
            for (int mt = 0; mt < 4; mt++)
                #pragma unroll
                for (int nt = 0; nt < NT; nt++)
                    acc[mt][nt] = __builtin_amdgcn_mfma_f32_16x16x32_bf16(
                        af[mt], bfv[nt], acc[mt][nt], 0, 0, 0);
        }
        __syncthreads();
        tb += 128;
        kb += 128;
        if (kb == CinB) {
            kb = 0;
            ta += (c3 == 2) ? (Wp - 2) * CinB : CinB;
            c3 = (c3 == 2) ? 0 : c3 + 1;
        }
    }

    if (splitN > 1) {
        float* pout = partial + (size_t)sp * pstride;
        #pragma unroll
        for (int mt = 0; mt < 4; mt++)
            #pragma unroll
            for (int nt = 0; nt < NT; nt++)
                #pragma unroll
                for (int r = 0; r < 4; r++) {
                    int mg = m0 + wm * 64 + mt * 16 + quad * 4 + r;
                    int ng = n0 + wn * (BN / 2) + nt * 16 + l16;
                    pout[(size_t)mg * Cout + ng] = acc[mt][nt][r];
                }
        return;
    }

    if (poolMode) {
        const int Hpo = (H >> 1) + 2;
        #pragma unroll
        for (int nt = 0; nt < NT; nt++) {
            int ng = n0 + wn * (BN / 2) + nt * 16 + l16;
            float bz = bias[ng];
            if (logW == 5) {
                #pragma unroll
                for (int mt = 0; mt < 2; mt++)
                    #pragma unroll
                    for (int rp = 0; rp < 2; rp++) {
                        float v = fmaxf(
                            fmaxf(acc[mt][nt][2 * rp], acc[mt][nt][2 * rp + 1]),
                            fmaxf(acc[mt + 2][nt][2 * rp], acc[mt + 2][nt][2 * rp + 1]));
                        int m1 = m0 + wm * 64 + mt * 16 + quad * 4 + 2 * rp;
                        int b  = m1 >> logHW;
                        int rm = m1 & (HW - 1);
                        int yp = (rm >> logW) >> 1;
                        int xp = (rm & (W - 1)) >> 1;
                        out[(size_t)((b * Hpo + yp + 1) * Hpo + xp + 1) * Cout + ng] =
                            f2bf(fmaxf(v + bz, 0.f));
                    }
            } else if (logW == 4) {
                #pragma unroll
                for (int mtp = 0; mtp < 2; mtp++)
                    #pragma unroll
                    for (int rp = 0; rp < 2; rp++) {
                        int mt = 2 * mtp;
                        float v = fmaxf(
                            fmaxf(acc[mt][nt][2 * rp], acc[mt][nt][2 * rp + 1]),
                            fmaxf(acc[mt + 1][nt][2 * rp], acc[mt + 1][nt][2 * rp + 1]));
                        int m1 = m0 + wm * 64 + mt * 16 + quad * 4 + 2 * rp;
                        int b  = m1 >> logHW;
                        int rm = m1 & (HW - 1);
                        int yp = (rm >> logW) >> 1;
                        int xp = (rm & (W - 1)) >> 1;
                        out[(size_t)((b * Hpo + yp + 1) * Hpo + xp + 1) * Cout + ng] =
                            f2bf(fmaxf(v + bz, 0.f));
                    }
            } else if (logW == 3) {
                #pragma unroll
                for (int mt = 0; mt < 4; mt++)
                    #pragma unroll
                    for (int rp = 0; rp < 2; rp++) {
                        float a = fmaxf(acc[mt][nt][2 * rp], acc[mt][nt][2 * rp + 1]);
                        float p = __shfl_xor(a, 32, 64);
                        float v = fmaxf(a, p);
                        if (quad < 2) {
                            int m1 = m0 + wm * 64 + mt * 16 + quad * 4 + 2 * rp;
                            int b  = m1 >> logHW;
                            int rm = m1 & (HW - 1);
                            int yp = (rm >> logW) >> 1;
                            int xp = (rm & (W - 1)) >> 1;
                            out[(size_t)((b * Hpo + yp + 1) * Hpo + xp + 1) * Cout + ng] =
                                f2bf(fmaxf(v + bz, 0.f));
                        }
                    }
            } else {
                #pragma unroll
                for (int mt = 0; mt < 4; mt++)
                    #pragma unroll
                    for (int rp = 0; rp < 2; rp++) {
                        float a = fmaxf(acc[mt][nt][2 * rp], acc[mt][nt][2 * rp + 1]);
                        float p = __shfl_xor(a, 16, 64);
                        float v = fmaxf(a, p);
                        if (!(quad & 1)) {
                            int m1 = m0 + wm * 64 + mt * 16 + quad * 4 + 2 * rp;
                            int b  = m1 >> logHW;
                            int rm = m1 & (HW - 1);
                            int yp = (rm >> logW) >> 1;
                            int xp = (rm & (W - 1)) >> 1;
                            out[(size_t)((b * Hpo + yp + 1) * Hpo + xp + 1) * Cout + ng] =
                                f2bf(fmaxf(v + bz, 0.f));
                        }
                    }
            }
        }
        return;
    }

    #pragma unroll
    for (int mt = 0; mt < 4; mt++) {
        #pragma unroll
        for (int r = 0; r < 4; r++) {
            int mg = m0 + wm * 64 + mt * 16 + quad * 4 + r;
            size_t obase;
            if (outPad) {
                int b  = mg >> logHW;
                int rm = mg & (HW - 1);
                int y  = rm >> logW;
                int xx = rm & (W - 1);
                obase = (size_t)((b * Wp + y + 1) * Wp + xx + 1) * Cout;
            } else {
                obase = (size_t)mg * Cout;
            }
            #pragma unroll
            for (int nt = 0; nt < NT; nt++) {
                int ng = n0 + wn * (BN / 2) + nt * 16 + l16;
                float v = acc[mt][nt][r] + bias[ng];
                out[obase + ng] = f2bf(fmaxf(v, 0.f));
            }
        }
    }
}

// sum split partials + bias + relu -> bf16 NHWC (padded out optional)
__global__ void reduce_split(const float* __restrict__ partial,
                             const float* __restrict__ bias, u16* __restrict__ out,
                             int MN, int C, int logC, int splitN, size_t pstride,
                             int H, int logHW, int logW, int outPad)
{
    int i4 = (blockIdx.x * 256 + threadIdx.x) * 4;
    if (i4 >= MN) return;
    float4 s = *(const float4*)(partial + i4);
    for (int sp = 1; sp < splitN; sp++) {
        float4 p = *(const float4*)(partial + (size_t)sp * pstride + i4);
        s.x += p.x; s.y += p.y; s.z += p.z; s.w += p.w;
    }
    int n = i4 & (C - 1);
    int m = i4 >> logC;
    size_t obase;
    if (outPad) {
        int Wp = H + 2;
        int b  = m >> logHW;
        int rm = m & ((1 << logHW) - 1);
        int y  = rm >> logW;
        int xx = rm & (H - 1);
        obase = (size_t)((b * Wp + y + 1) * Wp + xx + 1) * C;
    } else {
        obase = (size_t)m * C;
    }
    ushort4 o;
    o.x = f2bf(fmaxf(s.x + bias[n + 0], 0.f));
    o.y = f2bf(fmaxf(s.y + bias[n + 1], 0.f));
    o.z = f2bf(fmaxf(s.z + bias[n + 2], 0.f));
    o.w = f2bf(fmaxf(s.w + bias[n + 3], 0.f));
    *(ushort4*)(out + obase + n) = o;
}

// sum split partials + bias + relu + 2x2 maxpool -> bf16 (padded optional)
__global__ void reduce_pool(const float* __restrict__ partial,
                            const float* __restrict__ bias, u16* __restrict__ out,
                            int total4, int C, int splitN, size_t pstride,
                            int H, int outPad)
{
    int idx = blockIdx.x * 256 + threadIdx.x;
    if (idx >= total4) return;
    int c4 = idx % (C / 4);
    int p  = idx / (C / 4);
    int Ho = H >> 1;
    int xp = p % Ho; p /= Ho;
    int yp = p % Ho;
    int b  = p / Ho;
    int n  = c4 * 4;
    float4 best;
    bool first = true;
    #pragma unroll
    for (int dy = 0; dy < 2; dy++)
        #pragma unroll
        for (int dx = 0; dx < 2; dx++) {
            int m = (b * H + 2 * yp + dy) * H + 2 * xp + dx;
            const float* q = partial + (size_t)m * C + n;
            float4 s = *(const float4*)q;
            for (int sp = 1; sp < splitN; sp++) {
                float4 pp = *(const float4*)(q + (size_t)sp * pstride);
                s.x += pp.x; s.y += pp.y; s.z += pp.z; s.w += pp.w;
            }
            if (first) { best = s; first = false; }
            else {
                best.x = fmaxf(best.x, s.x); best.y = fmaxf(best.y, s.y);
                best.z = fmaxf(best.z, s.z); best.w = fmaxf(best.w, s.w);
            }
        }
    size_t obase;
    if (outPad) {
        int Hpo = Ho + 2;
        obase = (size_t)((b * Hpo + yp + 1) * Hpo + xp + 1) * C;
    } else {
        obase = (size_t)((b * Ho + yp) * Ho + xp) * C;
    }
    ushort4 o;
    o.x = f2bf(fmaxf(best.x + bias[n + 0], 0.f));
    o.y = f2bf(fmaxf(best.y + bias[n + 1], 0.f));
    o.z = f2bf(fmaxf(best.z + bias[n + 2], 0.f));
    o.w = f2bf(fmaxf(best.w + bias[n + 3], 0.f));
    *(ushort4*)(out + obase + n) = o;
}

// ---------------------------------------------------------------------------
// Generic small GEMM: out[M,N] = act(A[M,K](bf16) @ Bt[N,K](bf16)^T + bias)
// ---------------------------------------------------------------------------
template <bool RELU, bool OUTBF>
__global__ __launch_bounds__(256) void gemm64(
    const u16* __restrict__ A, const u16* __restrict__ Bt,
    const float* __restrict__ bias, void* __restrict__ outv,
    int M, int N, int K)
{
    constexpr int LDP = 72;
    __shared__ u16 As[64 * LDP];
    __shared__ u16 Bs[64 * LDP];

    const int nb = N >> 6;
    const int m0 = (blockIdx.x / nb) * 64;
    const int n0 = (blockIdx.x % nb) * 64;
    const int t = threadIdx.x, lane = t & 63, wave = t >> 6;
    const int quad = lane >> 4, l16 = lane & 15;
    const int wm = wave >> 1, wn = wave & 1;
    const int col8 = t & 7, r0 = t >> 3;

    floatx4 acc[2][2];
    #pragma unroll
    for (int i = 0; i < 2; i++)
        #pragma unroll
        for (int j = 0; j < 2; j++)
            acc[i][j] = (floatx4){0.f, 0.f, 0.f, 0.f};

    for (int kb = 0; kb < K; kb += 64) {
        #pragma unroll
        for (int j = 0; j < 2; j++) {
            int row = r0 + 32 * j;
            *(uint4*)(As + row * LDP + col8 * 8) =
                *(const uint4*)(A + (size_t)(m0 + row) * K + kb + col8 * 8);
            *(uint4*)(Bs + row * LDP + col8 * 8) =
                *(const uint4*)(Bt + (size_t)(n0 + row) * K + kb + col8 * 8);
        }
        __syncthreads();
        #pragma unroll
        for (int kk = 0; kk < 64; kk += 32) {
            bf16x8 af[2], bfv[2];
            #pragma unroll
            for (int mt = 0; mt < 2; mt++)
                af[mt] = *(const bf16x8*)(As + (wm * 32 + mt * 16 + l16) * LDP + kk + quad * 8);
            #pragma unroll
            for (int nt = 0; nt < 2; nt++)
                bfv[nt] = *(const bf16x8*)(Bs + (wn * 32 + nt * 16 + l16) * LDP + kk + quad * 8);
            #pragma unroll
            for (int mt = 0; mt < 2; mt++)
                #pragma unroll
                for (int nt = 0; nt < 2; nt++)
                    acc[mt][nt] = __builtin_amdgcn_mfma_f32_16x16x32_bf16(
                        af[mt], bfv[nt], acc[mt][nt], 0, 0, 0);
        }
        __syncthreads();
    }
    #pragma unroll
    for (int mt = 0; mt < 2; mt++) {
        #pragma unroll
        for (int nt = 0; nt < 2; nt++) {
            #pragma unroll
            for (int r = 0; r < 4; r++) {
                int mg = m0 + wm * 32 + mt * 16 + quad * 4 + r;
                int ng = n0 + wn * 32 + nt * 16 + l16;
                float v = acc[mt][nt][r] + bias[ng];
                if (RELU) v = fmaxf(v, 0.f);
                if (OUTBF) ((u16*)outv)[(size_t)mg * N + ng] = f2bf(v);
                else       ((float*)outv)[(size_t)mg * N + ng] = v;
            }
        }
    }
}

// ---------------------------------------------------------------------------
__global__ __launch_bounds__(256) void graph_tile(
    const float* __restrict__ low, const int* __restrict__ target,
    float* __restrict__ gpre, float* __restrict__ ggt)
{
    __shared__ float Al[64 * 132];
    __shared__ float Bl[128 * 68];
    const int t = threadIdx.x;
    const int gr0 = (blockIdx.x >> 3) * 64;
    const int gc0 = (blockIdx.x & 7) * 64;

    #pragma unroll
    for (int j = 0; j < 32; j++) {
        int flat = t + 256 * j;
        int k = flat & 127;
        int rc = flat >> 7;
        Al[rc * 132 + k] = low[(size_t)(gr0 + rc) * 128 + k];
        Bl[k * 68 + rc]  = low[(size_t)(gc0 + rc) * 128 + k];
    }
    __syncthreads();

    const int tx = t & 15, ty = t >> 4;
    float acc[4][4];
    #pragma unroll
    for (int r = 0; r < 4; r++)
        #pragma unroll
        for (int c = 0; c < 4; c++) acc[r][c] = 0.f;

    for (int k = 0; k < 128; k++) {
        float a[4], b[4];
        #pragma unroll
        for (int r = 0; r < 4; r++) a[r] = Al[(ty * 4 + r) * 132 + k];
        #pragma unroll
        for (int c = 0; c < 4; c++) b[c] = Bl[k * 68 + tx * 4 + c];
        #pragma unroll
        for (int r = 0; r < 4; r++)
            #pragma unroll
            for (int c = 0; c < 4; c++) acc[r][c] += a[r] * b[c];
    }
    #pragma unroll
    for (int r = 0; r < 4; r++) {
        int row = gr0 + ty * 4 + r;
        int tr  = target[row];
        float4 gp, gg;
        float* pp = (float*)&gp;
        float* gg_ = (float*)&gg;
        #pragma unroll
        for (int c = 0; c < 4; c++) {
            pp[c]  = 1.f / (1.f + __expf(-acc[r][c]));
            gg_[c] = (tr == target[gc0 + tx * 4 + c]) ? 1.f : 0.f;
        }
        *(float4*)(gpre + (size_t)row * 512 + gc0 + tx * 4) = gp;
        *(float4*)(ggt  + (size_t)row * 512 + gc0 + tx * 4) = gg;
    }
}

// ---------------------------------------------------------------------------
__global__ __launch_bounds__(256) void cls_kernel(
    const u16* __restrict__ feat, const float* __restrict__ w,
    const float* __restrict__ bias, float* __restrict__ out)
{
    __shared__ float ws[5120];
    const int t = threadIdx.x;
    for (int i = t; i < 5120; i += 256) ws[i] = w[i];
    __syncthreads();
    const int lane = t & 63;
    const int row  = blockIdx.x * 4 + (t >> 6);
    float a[10];
    #pragma unroll
    for (int j = 0; j < 10; j++) a[j] = 0.f;
    #pragma unroll
    for (int i = 0; i < 8; i++) {
        int k = i * 64 + lane;
        float f = bf2f(feat[(size_t)row * 512 + k]);
        #pragma unroll
        for (int j = 0; j < 10; j++) a[j] += f * ws[k * 10 + j];
    }
    #pragma unroll
    for (int j = 0; j < 10; j++)
        #pragma unroll
        for (int off = 32; off > 0; off >>= 1)
            a[j] += __shfl_down(a[j], off, 64);
    if (lane == 0) {
        #pragma unroll
        for (int j = 0; j < 10; j++) out[row * 10 + j] = a[j] + bias[j];
    }
}

// ---------------------------------------------------------------------------
extern "C" void kernel_launch(void* const* d_in, const int* in_sizes, int n_in,
                              void* d_out, int out_size, void* d_ws, size_t ws_size,
                              hipStream_t stream)
{
    const float* x      = (const float*)d_in[0];
    const int*   target = (const int*)d_in[1];
    const float* conv_w[13];
    const float* conv_b[13];
    for (int i = 0; i < 13; i++) {
        conv_w[i] = (const float*)d_in[2 + 2 * i];
        conv_b[i] = (const float*)d_in[3 + 2 * i];
    }
    const float* lin1_w = (const float*)d_in[28];
    const float* lin1_b = (const float*)d_in[29];
    const float* lin2_w = (const float*)d_in[30];
    const float* lin2_b = (const float*)d_in[31];
    const float* cls_w  = (const float*)d_in[32];
    const float* cls_b  = (const float*)d_in[33];
    float* out = (float*)d_out;

    static const int cin_arr[13]  = {3, 64, 64, 128, 128, 256, 256, 256, 512, 512, 512, 512, 512};
    static const int cout_arr[13] = {64, 64, 128, 128, 256, 256, 256, 512, 512, 512, 512, 512, 512};

    char* ws = (char*)d_ws;
    size_t off = 0;
    const size_t R0SZ = (size_t)512 * 34 * 34 * 64 * 2;
    const size_t R1SZ = (size_t)512 * 34 * 34 * 64 * 2;
    char* R0raw = ws + off; off += R0SZ;
    char* R1raw = ws + off; off += R1SZ;
    u16* R0 = (u16*)R0raw;
    u16* R1 = (u16*)R1raw;
    float* PA = (float*)(R0raw + 20971520);
    float* PB = (float*)(R1raw + 20971520);
    u16* wt[13];
    for (int i = 1; i < 13; i++) {
        wt[i] = (u16*)(ws + off);
        off += (size_t)cout_arr[i] * 9 * cin_arr[i] * 2;
    }
    u16* wtl1 = (u16*)(ws + off); off += (size_t)256 * 512 * 2;
    u16* wtl2 = (u16*)(ws + off); off += (size_t)128 * 256 * 2;
    u16* hbuf = (u16*)(ws + off); off += (size_t)512 * 256 * 2;
    float* lowbuf = (float*)(ws + off); off += (size_t)512 * 128 * 4;

    for (int i = 1; i < 13; i++) {
        int total = cout_arr[i] * 9 * cin_arr[i];
        repack_w<<<(total + 255) / 256, 256, 0, stream>>>(conv_w[i], wt[i], cin_arr[i], total);
    }
    repack_lin<<<(512 * 256) / 256, 256, 0, stream>>>(lin1_w, wtl1, 512, 256, 512 * 256);
    repack_lin<<<(256 * 128) / 256, 256, 0, stream>>>(lin2_w, wtl2, 256, 128, 256 * 128);

    auto zh = [&](u16* buf, int Hp, int C) {
        int total8 = 512 * (4 * Hp - 4) * (C / 8);
        zero_halo<<<(total8 + 255) / 256, 256, 0, stream>>>(buf, Hp, C, total8);
    };
    auto launch_conv = [&](int li, int Hl, int bn, u16* inb, u16* outb, float* part,
                           int splitN, int outPad, int poolMode) {
        int Cin = cin_arr[li], Cout = cout_arr[li];
        int M = 512 * Hl * Hl;
        int logW = __builtin_ctz(Hl);
        int logHW = 2 * logW;
        size_t pstride = (size_t)M * Cout;
        int grid = (M / 128) * (Cout / bn) * splitN;
        if (bn == 128) {
            conv_gemm<128><<<grid, 256, 0, stream>>>(
                inb, wt[li], conv_b[li], outb, part, pstride,
                Hl, Cin, Cout, logHW, logW, splitN, outPad, poolMode);
        } else {
            conv_gemm<64><<<grid, 256, 0, stream>>>(
                inb, wt[li], conv_b[li], outb, part, pstride,
                Hl, Cin, Cout, logHW, logW, splitN, outPad, poolMode);
        }
    };
    auto launch_reduce = [&](int li, int Hl, u16* outb, float* part, int splitN, int outPad) {
        int Cout = cout_arr[li];
        int M = 512 * Hl * Hl;
        int logW = __builtin_ctz(Hl);
        size_t pstride = (size_t)M * Cout;
        int MN = M * Cout;
        reduce_split<<<(MN / 4 + 255) / 256, 256, 0, stream>>>(
            part, conv_b[li], outb, MN, Cout, __builtin_ctz(Cout),
            splitN, pstride, Hl, 2 * logW, logW, outPad);
    };
    auto launch_reduce_pool = [&](int li, int Hl, u16* outb, float* part, int splitN, int outPad) {
        int Cout = cout_arr[li];
        int M = 512 * Hl * Hl;
        size_t pstride = (size_t)M * Cout;
        int total4 = 512 * (Hl / 2) * (Hl / 2) * Cout / 4;
        reduce_pool<<<(total4 + 255) / 256, 256, 0, stream>>>(
            part, conv_b[li], outb, total4, Cout, splitN, pstride, Hl, outPad);
    };

    zh(R0, 34, 64);
    conv0_kernel<<<512 * 8, 256, 0, stream>>>(x, conv_w[0], conv_b[0], R0);

    zh(R1, 18, 64);
    launch_conv(1, 32, 64, R0, R1, nullptr, 1, 0, 1);   // L1 + pool -> R1 p18,64
    zh(R0, 18, 128);
    launch_conv(2, 16, 128, R1, R0, nullptr, 1, 1, 0);  // L2 -> R0 p18,128
    zh(R1, 10, 128);
    launch_conv(3, 16, 128, R0, R1, nullptr, 1, 0, 1);  // L3 + pool -> R1 p10,128
    zh(R0, 10, 256);
    launch_conv(4, 8, 128, R1, R0, nullptr, 1, 1, 0);   // L4 -> R0 p10,256
    zh(R1, 10, 256);
    launch_conv(5, 8, 128, R0, R1, nullptr, 1, 1, 0);   // L5 -> R1 p10,256
    zh(R0, 6, 256);
    launch_conv(6, 8, 128, R1, R0, nullptr, 1, 0, 1);   // L6 + pool -> R0 p6,256
    zh(R1, 6, 512);
    launch_conv(7, 4, 128, R0, R1, PB, 2, 1, 0);        // L7 -> PB (split2, BN=128)
    launch_reduce(7, 4, R1, PB, 2, 1);                  //   -> R1 p6,512
    zh(R0, 6, 512);
    launch_conv(8, 4, 128, R1, R0, PA, 2, 1, 0);        // L8 -> PA
    launch_reduce(8, 4, R0, PA, 2, 1);                  //   -> R0 p6,512
    zh(R1, 4, 512);
    launch_conv(9, 4, 128, R0, R1, PB, 2, 0, 0);        // L9 -> PB
    launch_reduce_pool(9, 4, R1, PB, 2, 1);             //   + pool -> R1 p4,512
    zh(R0, 4, 512);
    launch_conv(10, 2, 64, R1, R0, PA, 4, 1, 0);        // L10 -> PA (split4)
    launch_reduce(10, 2, R0, PA, 4, 1);                 //   -> R0 p4,512
    zh(R1, 4, 512);
    launch_conv(11, 2, 64, R0, R1, PB, 4, 1, 0);        // L11 -> PB
    launch_reduce(11, 2, R1, PB, 4, 1);                 //   -> R1 p4,512
    launch_conv(12, 2, 64, R1, R0, PA, 4, 0, 0);        // L12 -> PA
    launch_reduce_pool(12, 2, R0, PA, 4, 0);            //   + pool -> feat = R0 [512,512]

    u16* feat = R0;
    gemm64<true, true><<<(512 / 64) * (256 / 64), 256, 0, stream>>>(
        feat, wtl1, lin1_b, hbuf, 512, 256, 512);
    gemm64<false, false><<<(512 / 64) * (128 / 64), 256, 0, stream>>>(
        hbuf, wtl2, lin2_b, lowbuf, 512, 128, 256);
    graph_tile<<<64, 256, 0, stream>>>(lowbuf, target, out + 5120, out + 5120 + 262144);
    cls_kernel<<<128, 256, 0, stream>>>(feat, cls_w, cls_b, out);
}

// Round 12
// 822.181 us; speedup vs baseline: 1.5472x; 1.0041x over previous
//
#include <hip/hip_runtime.h>

typedef unsigned short u16;
typedef __bf16 bf16x8 __attribute__((ext_vector_type(8)));
typedef float floatx4 __attribute__((ext_vector_type(4)));

__device__ inline u16 f2bf(float f) {
    return __builtin_bit_cast(u16, (__bf16)f);   // v_cvt RNE, 1 op
}
__device__ inline float bf2f(u16 h) {
    return __uint_as_float(((unsigned int)h) << 16);
}

// async global->LDS, 16B per lane. LDS dest must be wave-uniform base + lane*16.
__device__ __forceinline__ void async_copy16(u16* lds, const u16* g) {
    __builtin_amdgcn_global_load_lds(
        (const __attribute__((address_space(1))) unsigned int*)(uintptr_t)g,
        (__attribute__((address_space(3))) unsigned int*)(unsigned int)(uintptr_t)lds,
        16, 0, 0);
}

// ---------------------------------------------------------------------------
// zero ONLY the 1-px halo ring of a padded NHWC buffer [512][Hp][Hp][C]
// ---------------------------------------------------------------------------
__global__ void zero_halo(u16* __restrict__ buf, int Hp, int C, int total8)
{
    int i = blockIdx.x * 256 + threadIdx.x;
    if (i >= total8) return;
    int c8 = i % (C / 8);
    int p  = i / (C / 8);
    int ring = 4 * Hp - 4;
    int h = p % ring;
    int b = p / ring;
    int y, x;
    if (h < Hp)              { y = 0;              x = h; }
    else if (h < 2 * Hp)     { y = Hp - 1;         x = h - Hp; }
    else if (h < 3 * Hp - 2) { y = h - 2 * Hp + 1; x = 0; }
    else                     { y = h - 3 * Hp + 3; x = Hp - 1; }
    uint4 z = make_uint4(0u, 0u, 0u, 0u);
    *(uint4*)(buf + ((size_t)((b * Hp + y) * Hp + x) * C) + c8 * 8) = z;
}

// ---------------------------------------------------------------------------
// Layer 0: direct conv 3->64, 32x32, output PADDED NHWC [512][34][34][64]
// ---------------------------------------------------------------------------
__global__ __launch_bounds__(256) void conv0_kernel(
    const float* __restrict__ x, const float* __restrict__ w,
    const float* __restrict__ bias, u16* __restrict__ out)
{
    __shared__ __align__(16) float xs[3][6][36];
    const int t  = threadIdx.x;
    const int b  = blockIdx.x >> 3;
    const int y0 = (blockIdx.x & 7) * 4;

    for (int i = t; i < 3 * 6 * 36; i += 256) {
        int ci  = i / 216;
        int rem = i % 216;
        int r   = rem / 36;
        int c   = rem % 36;
        int gy  = y0 - 1 + r;
        int gx  = c - 1;
        float v = 0.f;
        if ((unsigned)gy < 32u && (unsigned)gx < 32u)
            v = x[((b * 3 + ci) * 32 + gy) * 32 + gx];
        xs[ci][r][c] = v;
    }
    const int lane = t & 63;
    const int wv   = t >> 6;
    float wr[27];
    #pragma unroll
    for (int k = 0; k < 27; k++) wr[k] = w[lane * 27 + k];
    const float bz = bias[lane];
    __syncthreads();

    const int y = y0 + wv;
    u16* orow = out + ((size_t)((b * 34 + y + 1) * 34 + 1) * 64) + lane;
    for (int xg = 0; xg < 32; xg += 4) {
        float a0 = bz, a1 = bz, a2 = bz, a3 = bz;
        #pragma unroll
        for (int ci = 0; ci < 3; ci++) {
            #pragma unroll
            for (int rr = 0; rr < 3; rr++) {
                const float* row = &xs[ci][wv + rr][0];
                float4 c03 = *(const float4*)(row + xg);
                float2 c45 = *(const float2*)(row + xg + 4);
                float w0 = wr[ci * 9 + rr * 3 + 0];
                float w1 = wr[ci * 9 + rr * 3 + 1];
                float w2 = wr[ci * 9 + rr * 3 + 2];
                a0 += c03.x * w0 + c03.y * w1 + c03.z * w2;
                a1 += c03.y * w0 + c03.z * w1 + c03.w * w2;
                a2 += c03.z * w0 + c03.w * w1 + c45.x * w2;
                a3 += c03.w * w0 + c45.x * w1 + c45.y * w2;
            }
        }
        orow[(xg + 0) * 64] = f2bf(fmaxf(a0, 0.f));
        orow[(xg + 1) * 64] = f2bf(fmaxf(a1, 0.f));
        orow[(xg + 2) * 64] = f2bf(fmaxf(a2, 0.f));
        orow[(xg + 3) * 64] = f2bf(fmaxf(a3, 0.f));
    }
}

// ---------------------------------------------------------------------------
// Merged weight repack: 12 conv layers ([Cout][Cin][3][3] f32 -> [Cout][9][Cin]
// bf16) + 2 linear transposes ([K][N] f32 -> [N][K] bf16) in one launch.
// ---------------------------------------------------------------------------
struct RepackArgs {
    const float* src[14];
    u16* dst[14];
    int p1[14];        // Cin (conv) or K (lin)
    int p2[14];        // 0 (conv) or N (lin)
    int total[14];
    int startBlk[15];
    int nseg;
};

__global__ void repack_all(RepackArgs a)
{
    int blk = blockIdx.x;
    int s = 0;
    #pragma unroll 1
    while (s + 1 < a.nseg && blk >= a.startBlk[s + 1]) s++;
    int i = (blk - a.startBlk[s]) * 256 + threadIdx.x;
    if (i >= a.total[s]) return;
    const float* src = a.src[s];
    u16* dst = a.dst[s];
    if (a.p2[s] == 0) {
        int Cin = a.p1[s];
        int ci = i % Cin;
        int rest = i / Cin;
        int sh = rest % 9;
        int co = rest / 9;
        dst[i] = f2bf(src[(co * Cin + ci) * 9 + sh]);
    } else {
        int N = a.p2[s], K = a.p1[s];
        int n = i % N, k = i / N;
        dst[(size_t)n * K + k] = f2bf(src[(size_t)k * N + n]);
    }
}

// ---------------------------------------------------------------------------
// Conv shift-GEMM, bf16 MFMA 16x16x32. Padded input, global_load_lds staging,
// XOR-8 swizzle via global source permutation, incremental SALU offsets,
// fused-pool epilogue, XCD-aware tile swizzle, optional split-K.
// BM=128: 4 waves 2x2 (wave cols = BN/2). BM=256: 4 waves 4x1 (wave cols = BN).
// ---------------------------------------------------------------------------
template <int BM, int BN>
__global__ __launch_bounds__(256) void conv_gemm(
    const u16* __restrict__ in, const u16* __restrict__ wt,
    const float* __restrict__ bias, u16* __restrict__ out,
    float* __restrict__ partial, size_t pstride,
    int H, int Cin, int Cout, int logHW, int logW, int splitN,
    int outPad, int poolMode)
{
    constexpr int BK = 64;
    constexpr int WC = (BM == 256) ? BN : (BN / 2);   // wave cols
    constexpr int NT = WC / 16;
    constexpr int NB_A = BM / 32;
    constexpr int NB_B = BN / 32;
    __shared__ u16 As[BM * BK];
    __shared__ u16 Bs[BN * BK];

    const int Nblocks = Cout / BN;
    const int per = gridDim.x >> 3;
    const int bid = (blockIdx.x & 7) * per + (blockIdx.x >> 3);
    const int sp   = bid % splitN;
    const int tile = bid / splitN;
    const int m0 = (tile / Nblocks) * BM;
    const int n0 = (tile % Nblocks) * BN;

    const int t    = threadIdx.x;
    const int lane = t & 63;
    const int wave = t >> 6;
    const int quad = lane >> 4;
    const int l16  = lane & 15;
    const int wm   = (BM == 256) ? wave : (wave >> 1);
    const int wn   = (BM == 256) ? 0 : (wave & 1);
    const int W    = H;
    const int Wp   = H + 2;
    const int HW   = 1 << logHW;
    const int col8 = t & 7;
    const int r0   = t >> 3;
    const int scol = col8 ^ (r0 & 7);

    const int CinB = Cin * 2;

    int vA[NB_A];
    #pragma unroll
    for (int j = 0; j < NB_A; j++) {
        int m  = m0 + r0 + 32 * j;
        int b  = m >> logHW;
        int rm = m & (HW - 1);
        int y  = rm >> logW;
        int xx = rm & (W - 1);
        vA[j] = ((b * Wp + y + 1) * Wp + xx + 1) * CinB + scol * 16;
    }
    int vB[NB_B];
    #pragma unroll
    for (int j = 0; j < NB_B; j++)
        vB[j] = (n0 + r0 + 32 * j) * 9 * CinB + scol * 16;

    const int logKB = (Cin == 64) ? 0 : (Cin == 128) ? 1 : (Cin == 256) ? 2 : 3;
    const int KB  = 1 << logKB;
    const int T   = 9 * KB;
    const int len = T / splitN;
    const int it0 = sp * len;

    int s0 = it0 >> logKB;
    int c3 = s0 - (s0 / 3) * 3;
    int ta = ((s0 / 3 - 1) * Wp + (c3 - 1)) * CinB;
    int kb = (it0 & (KB - 1)) * 128;
    int tb = it0 * 128;

    u16* const ldsA = As + t * 8;
    u16* const ldsB = Bs + t * 8;
    const char* const inB = (const char*)in;
    const char* const wtB = (const char*)wt;

    floatx4 acc[4][NT];
    #pragma unroll
    for (int i = 0; i < 4; i++)
        #pragma unroll
        for (int j = 0; j < NT; j++)
            acc[i][j] = (floatx4){0.f, 0.f, 0.f, 0.f};

    const int sw = (l16 & 7) * 8;

    for (int it = 0; it < len; it++) {
        const int ua = ta + kb;
        #pragma unroll
        for (int j = 0; j < NB_A; j++)
            async_copy16(ldsA + j * 2048, (const u16*)(inB + (ua + vA[j])));
        #pragma unroll
        for (int j = 0; j < NB_B; j++)
            async_copy16(ldsB + j * 2048, (const u16*)(wtB + (tb + vB[j])));
        __syncthreads();
        #pragma unroll
        for (int kk = 0; kk < BK; kk += 32) {
            bf16x8 af[4], bfv[NT];
            int cbo = kk + quad * 8;
            #pragma unroll
            for (int mt = 0; mt < 4; mt++)
                af[mt] = *(const bf16x8*)(As + (wm * 64 + mt * 16 + l16) * 64 + (cbo ^ sw));
            #pragma unroll
            for (int nt = 0; nt < NT; nt++)
                bfv[nt] = *(const bf16x8*)(Bs + (wn * WC + nt * 16 + l16) * 64 + (cbo ^ sw));
            #pragma unroll
            for (int mt = 0; mt < 4; mt++)
                #pragma unroll
                for (int nt = 0; nt < NT; nt++)
                    acc[mt][nt] = __builtin_amdgcn_mfma_f32_16x16x32_bf16(
                        af[mt], bfv[nt], acc[mt][nt], 0, 0, 0);
        }
        __syncthreads();
        tb += 128;
        kb += 128;
        if (kb == CinB) {
            kb = 0;
            ta += (c3 == 2) ? (Wp - 2) * CinB : CinB;
            c3 = (c3 == 2) ? 0 : c3 + 1;
        }
    }

    const int ngb = n0 + wn * WC + l16;

    if (splitN > 1) {
        float* pout = partial + (size_t)sp * pstride;
        #pragma unroll
        for (int mt = 0; mt < 4; mt++)
            #pragma unroll
            for (int r = 0; r < 4; r++) {
                int mg = m0 + wm * 64 + mt * 16 + quad * 4 + r;
                float* op = pout + (size_t)mg * Cout + ngb;
                #pragma unroll
                for (int nt = 0; nt < NT; nt++)
                    op[nt * 16] = acc[mt][nt][r];
            }
        return;
    }

    float bzv[NT];
    #pragma unroll
    for (int nt = 0; nt < NT; nt++) bzv[nt] = bias[ngb + nt * 16];

    if (poolMode) {
        const int Hpo = (H >> 1) + 2;
        if (logW == 5) {            // W=32: y-partner = mt+2, in-lane
            #pragma unroll
            for (int mt = 0; mt < 2; mt++)
                #pragma unroll
                for (int rp = 0; rp < 2; rp++) {
                    int m1 = m0 + wm * 64 + mt * 16 + quad * 4 + 2 * rp;
                    int b  = m1 >> logHW;
                    int rm = m1 & (HW - 1);
                    int yp = (rm >> logW) >> 1;
                    int xp = (rm & (W - 1)) >> 1;
                    u16* op = out + (size_t)((b * Hpo + yp + 1) * Hpo + xp + 1) * Cout + ngb;
                    #pragma unroll
                    for (int nt = 0; nt < NT; nt++) {
                        float v = fmaxf(
                            fmaxf(acc[mt][nt][2 * rp], acc[mt][nt][2 * rp + 1]),
                            fmaxf(acc[mt + 2][nt][2 * rp], acc[mt + 2][nt][2 * rp + 1]));
                        op[nt * 16] = f2bf(fmaxf(v + bzv[nt], 0.f));
                    }
                }
        } else if (logW == 4) {     // W=16: y-partner = mt+1, in-lane
            #pragma unroll
            for (int mtp = 0; mtp < 2; mtp++)
                #pragma unroll
                for (int rp = 0; rp < 2; rp++) {
                    int mt = 2 * mtp;
                    int m1 = m0 + wm * 64 + mt * 16 + quad * 4 + 2 * rp;
                    int b  = m1 >> logHW;
                    int rm = m1 & (HW - 1);
                    int yp = (rm >> logW) >> 1;
                    int xp = (rm & (W - 1)) >> 1;
                    u16* op = out + (size_t)((b * Hpo + yp + 1) * Hpo + xp + 1) * Cout + ngb;
                    #pragma unroll
                    for (int nt = 0; nt < NT; nt++) {
                        float v = fmaxf(
                            fmaxf(acc[mt][nt][2 * rp], acc[mt][nt][2 * rp + 1]),
                            fmaxf(acc[mt + 1][nt][2 * rp], acc[mt + 1][nt][2 * rp + 1]));
                        op[nt * 16] = f2bf(fmaxf(v + bzv[nt], 0.f));
                    }
                }
        } else {                    // W=8: y-partner = quad+2 via shfl32
            #pragma unroll
            for (int mt = 0; mt < 4; mt++)
                #pragma unroll
                for (int rp = 0; rp < 2; rp++) {
                    int m1 = m0 + wm * 64 + mt * 16 + quad * 4 + 2 * rp;
                    int b  = m1 >> logHW;
                    int rm = m1 & (HW - 1);
                    int yp = (rm >> logW) >> 1;
                    int xp = (rm & (W - 1)) >> 1;
                    u16* op = out + (size_t)((b * Hpo + yp + 1) * Hpo + xp + 1) * Cout + ngb;
                    #pragma unroll
                    for (int nt = 0; nt < NT; nt++) {
                        float a = fmaxf(acc[mt][nt][2 * rp], acc[mt][nt][2 * rp + 1]);
                        float p = __shfl_xor(a, 32, 64);
                        float v = fmaxf(a, p);
                        if (quad < 2)
                            op[nt * 16] = f2bf(fmaxf(v + bzv[nt], 0.f));
                    }
                }
        }
        return;
    }

    #pragma unroll
    for (int mt = 0; mt < 4; mt++) {
        #pragma unroll
        for (int r = 0; r < 4; r++) {
            int mg = m0 + wm * 64 + mt * 16 + quad * 4 + r;
            size_t obase;
            if (outPad) {
                int b  = mg >> logHW;
                int rm = mg & (HW - 1);
                int y  = rm >> logW;
                int xx = rm & (W - 1);
                obase = (size_t)((b * Wp + y + 1) * Wp + xx + 1) * Cout;
            } else {
                obase = (size_t)mg * Cout;
            }
            u16* op = out + obase + ngb;
            #pragma unroll
            for (int nt = 0; nt < NT; nt++)
                op[nt * 16] = f2bf(fmaxf(acc[mt][nt][r] + bzv[nt], 0.f));
        }
    }
}

// sum split partials + bias + relu -> bf16 NHWC (padded out optional)
__global__ void reduce_split(const float* __restrict__ partial,
                             const float* __restrict__ bias, u16* __restrict__ out,
                             int MN, int C, int logC, int splitN, size_t pstride,
                             int H, int logHW, int logW, int outPad)
{
    int i4 = (blockIdx.x * 256 + threadIdx.x) * 4;
    if (i4 >= MN) return;
    float4 s = *(const float4*)(partial + i4);
    for (int sp = 1; sp < splitN; sp++) {
        float4 p = *(const float4*)(partial + (size_t)sp * pstride + i4);
        s.x += p.x; s.y += p.y; s.z += p.z; s.w += p.w;
    }
    int n = i4 & (C - 1);
    int m = i4 >> logC;
    size_t obase;
    if (outPad) {
        int Wp = H + 2;
        int b  = m >> logHW;
        int rm = m & ((1 << logHW) - 1);
        int y  = rm >> logW;
        int xx = rm & (H - 1);
        obase = (size_t)((b * Wp + y + 1) * Wp + xx + 1) * C;
    } else {
        obase = (size_t)m * C;
    }
    ushort4 o;
    o.x = f2bf(fmaxf(s.x + bias[n + 0], 0.f));
    o.y = f2bf(fmaxf(s.y + bias[n + 1], 0.f));
    o.z = f2bf(fmaxf(s.z + bias[n + 2], 0.f));
    o.w = f2bf(fmaxf(s.w + bias[n + 3], 0.f));
    *(ushort4*)(out + obase + n) = o;
}

// sum split partials + bias + relu + 2x2 maxpool -> bf16 (padded optional)
__global__ void reduce_pool(const float* __restrict__ partial,
                            const float* __restrict__ bias, u16* __restrict__ out,
                            int total4, int C, int splitN, size_t pstride,
                            int H, int outPad)
{
    int idx = blockIdx.x * 256 + threadIdx.x;
    if (idx >= total4) return;
    int c4 = idx % (C / 4);
    int p  = idx / (C / 4);
    int Ho = H >> 1;
    int xp = p % Ho; p /= Ho;
    int yp = p % Ho;
    int b  = p / Ho;
    int n  = c4 * 4;
    float4 best;
    bool first = true;
    #pragma unroll
    for (int dy = 0; dy < 2; dy++)
        #pragma unroll
        for (int dx = 0; dx < 2; dx++) {
            int m = (b * H + 2 * yp + dy) * H + 2 * xp + dx;
            const float* q = partial + (size_t)m * C + n;
            float4 s = *(const float4*)q;
            for (int sp = 1; sp < splitN; sp++) {
                float4 pp = *(const float4*)(q + (size_t)sp * pstride);
                s.x += pp.x; s.y += pp.y; s.z += pp.z; s.w += pp.w;
            }
            if (first) { best = s; first = false; }
            else {
                best.x = fmaxf(best.x, s.x); best.y = fmaxf(best.y, s.y);
                best.z = fmaxf(best.z, s.z); best.w = fmaxf(best.w, s.w);
            }
        }
    size_t obase;
    if (outPad) {
        int Hpo = Ho + 2;
        obase = (size_t)((b * Hpo + yp + 1) * Hpo + xp + 1) * C;
    } else {
        obase = (size_t)((b * Ho + yp) * Ho + xp) * C;
    }
    ushort4 o;
    o.x = f2bf(fmaxf(best.x + bias[n + 0], 0.f));
    o.y = f2bf(fmaxf(best.y + bias[n + 1], 0.f));
    o.z = f2bf(fmaxf(best.z + bias[n + 2], 0.f));
    o.w = f2bf(fmaxf(best.w + bias[n + 3], 0.f));
    *(ushort4*)(out + obase + n) = o;
}

// ---------------------------------------------------------------------------
// Generic small GEMM: out[M,N] = act(A[M,K](bf16) @ Bt[N,K](bf16)^T + bias)
// ---------------------------------------------------------------------------
template <bool RELU, bool OUTBF>
__global__ __launch_bounds__(256) void gemm64(
    const u16* __restrict__ A, const u16* __restrict__ Bt,
    const float* __restrict__ bias, void* __restrict__ outv,
    int M, int N, int K)
{
    constexpr int LDP = 72;
    __shared__ u16 As[64 * LDP];
    __shared__ u16 Bs[64 * LDP];

    const int nb = N >> 6;
    const int m0 = (blockIdx.x / nb) * 64;
    const int n0 = (blockIdx.x % nb) * 64;
    const int t = threadIdx.x, lane = t & 63, wave = t >> 6;
    const int quad = lane >> 4, l16 = lane & 15;
    const int wm = wave >> 1, wn = wave & 1;
    const int col8 = t & 7, r0 = t >> 3;

    floatx4 acc[2][2];
    #pragma unroll
    for (int i = 0; i < 2; i++)
        #pragma unroll
        for (int j = 0; j < 2; j++)
            acc[i][j] = (floatx4){0.f, 0.f, 0.f, 0.f};

    for (int kb = 0; kb < K; kb += 64) {
        #pragma unroll
        for (int j = 0; j < 2; j++) {
            int row = r0 + 32 * j;
            *(uint4*)(As + row * LDP + col8 * 8) =
                *(const uint4*)(A + (size_t)(m0 + row) * K + kb + col8 * 8);
            *(uint4*)(Bs + row * LDP + col8 * 8) =
                *(const uint4*)(Bt + (size_t)(n0 + row) * K + kb + col8 * 8);
        }
        __syncthreads();
        #pragma unroll
        for (int kk = 0; kk < 64; kk += 32) {
            bf16x8 af[2], bfv[2];
            #pragma unroll
            for (int mt = 0; mt < 2; mt++)
                af[mt] = *(const bf16x8*)(As + (wm * 32 + mt * 16 + l16) * LDP + kk + quad * 8);
            #pragma unroll
            for (int nt = 0; nt < 2; nt++)
                bfv[nt] = *(const bf16x8*)(Bs + (wn * 32 + nt * 16 + l16) * LDP + kk + quad * 8);
            #pragma unroll
            for (int mt = 0; mt < 2; mt++)
                #pragma unroll
                for (int nt = 0; nt < 2; nt++)
                    acc[mt][nt] = __builtin_amdgcn_mfma_f32_16x16x32_bf16(
                        af[mt], bfv[nt], acc[mt][nt], 0, 0, 0);
        }
        __syncthreads();
    }
    #pragma unroll
    for (int mt = 0; mt < 2; mt++) {
        #pragma unroll
        for (int nt = 0; nt < 2; nt++) {
            #pragma unroll
            for (int r = 0; r < 4; r++) {
                int mg = m0 + wm * 32 + mt * 16 + quad * 4 + r;
                int ng = n0 + wn * 32 + nt * 16 + l16;
                float v = acc[mt][nt][r] + bias[ng];
                if (RELU) v = fmaxf(v, 0.f);
                if (OUTBF) ((u16*)outv)[(size_t)mg * N + ng] = f2bf(v);
                else       ((float*)outv)[(size_t)mg * N + ng] = v;
            }
        }
    }
}

// ---------------------------------------------------------------------------
__global__ __launch_bounds__(256) void graph_tile(
    const float* __restrict__ low, const int* __restrict__ target,
    float* __restrict__ gpre, float* __restrict__ ggt)
{
    __shared__ float Al[64 * 132];
    __shared__ float Bl[128 * 68];
    const int t = threadIdx.x;
    const int gr0 = (blockIdx.x >> 3) * 64;
    const int gc0 = (blockIdx.x & 7) * 64;

    #pragma unroll
    for (int j = 0; j < 32; j++) {
        int flat = t + 256 * j;
        int k = flat & 127;
        int rc = flat >> 7;
        Al[rc * 132 + k] = low[(size_t)(gr0 + rc) * 128 + k];
        Bl[k * 68 + rc]  = low[(size_t)(gc0 + rc) * 128 + k];
    }
    __syncthreads();

    const int tx = t & 15, ty = t >> 4;
    float acc[4][4];
    #pragma unroll
    for (int r = 0; r < 4; r++)
        #pragma unroll
        for (int c = 0; c < 4; c++) acc[r][c] = 0.f;

    for (int k = 0; k < 128; k++) {
        float a[4], b[4];
        #pragma unroll
        for (int r = 0; r < 4; r++) a[r] = Al[(ty * 4 + r) * 132 + k];
        #pragma unroll
        for (int c = 0; c < 4; c++) b[c] = Bl[k * 68 + tx * 4 + c];
        #pragma unroll
        for (int r = 0; r < 4; r++)
            #pragma unroll
            for (int c = 0; c < 4; c++) acc[r][c] += a[r] * b[c];
    }
    #pragma unroll
    for (int r = 0; r < 4; r++) {
        int row = gr0 + ty * 4 + r;
        int tr  = target[row];
        float4 gp, gg;
        float* pp = (float*)&gp;
        float* gg_ = (float*)&gg;
        #pragma unroll
        for (int c = 0; c < 4; c++) {
            pp[c]  = 1.f / (1.f + __expf(-acc[r][c]));
            gg_[c] = (tr == target[gc0 + tx * 4 + c]) ? 1.f : 0.f;
        }
        *(float4*)(gpre + (size_t)row * 512 + gc0 + tx * 4) = gp;
        *(float4*)(ggt  + (size_t)row * 512 + gc0 + tx * 4) = gg;
    }
}

// ---------------------------------------------------------------------------
__global__ __launch_bounds__(256) void cls_kernel(
    const u16* __restrict__ feat, const float* __restrict__ w,
    const float* __restrict__ bias, float* __restrict__ out)
{
    __shared__ float ws[5120];
    const int t = threadIdx.x;
    for (int i = t; i < 5120; i += 256) ws[i] = w[i];
    __syncthreads();
    const int lane = t & 63;
    const int row  = blockIdx.x * 4 + (t >> 6);
    float a[10];
    #pragma unroll
    for (int j = 0; j < 10; j++) a[j] = 0.f;
    #pragma unroll
    for (int i = 0; i < 8; i++) {
        int k = i * 64 + lane;
        float f = bf2f(feat[(size_t)row * 512 + k]);
        #pragma unroll
        for (int j = 0; j < 10; j++) a[j] += f * ws[k * 10 + j];
    }
    #pragma unroll
    for (int j = 0; j < 10; j++)
        #pragma unroll
        for (int off = 32; off > 0; off >>= 1)
            a[j] += __shfl_down(a[j], off, 64);
    if (lane == 0) {
        #pragma unroll
        for (int j = 0; j < 10; j++) out[row * 10 + j] = a[j] + bias[j];
    }
}

// ---------------------------------------------------------------------------
extern "C" void kernel_launch(void* const* d_in, const int* in_sizes, int n_in,
                              void* d_out, int out_size, void* d_ws, size_t ws_size,
                              hipStream_t stream)
{
    const float* x      = (const float*)d_in[0];
    const int*   target = (const int*)d_in[1];
    const float* conv_w[13];
    const float* conv_b[13];
    for (int i = 0; i < 13; i++) {
        conv_w[i] = (const float*)d_in[2 + 2 * i];
        conv_b[i] = (const float*)d_in[3 + 2 * i];
    }
    const float* lin1_w = (const float*)d_in[28];
    const float* lin1_b = (const float*)d_in[29];
    const float* lin2_w = (const float*)d_in[30];
    const float* lin2_b = (const float*)d_in[31];
    const float* cls_w  = (const float*)d_in[32];
    const float* cls_b  = (const float*)d_in[33];
    float* out = (float*)d_out;

    static const int cin_arr[13]  = {3, 64, 64, 128, 128, 256, 256, 256, 512, 512, 512, 512, 512};
    static const int cout_arr[13] = {64, 64, 128, 128, 256, 256, 256, 512, 512, 512, 512, 512, 512};

    char* ws = (char*)d_ws;
    size_t off = 0;
    const size_t R0SZ = (size_t)512 * 34 * 34 * 64 * 2;
    const size_t R1SZ = (size_t)512 * 34 * 34 * 64 * 2;
    char* R0raw = ws + off; off += R0SZ;
    char* R1raw = ws + off; off += R1SZ;
    u16* R0 = (u16*)R0raw;
    u16* R1 = (u16*)R1raw;
    float* PA = (float*)(R0raw + 20971520);
    float* PB = (float*)(R1raw + 20971520);
    u16* wt[13];
    for (int i = 1; i < 13; i++) {
        wt[i] = (u16*)(ws + off);
        off += (size_t)cout_arr[i] * 9 * cin_arr[i] * 2;
    }
    u16* wtl1 = (u16*)(ws + off); off += (size_t)256 * 512 * 2;
    u16* wtl2 = (u16*)(ws + off); off += (size_t)128 * 256 * 2;
    u16* hbuf = (u16*)(ws + off); off += (size_t)512 * 256 * 2;
    float* lowbuf = (float*)(ws + off); off += (size_t)512 * 128 * 4;

    // ---- single merged repack launch (12 conv + 2 lin) ----
    RepackArgs ra;
    int nb = 0, blk = 0;
    ra.startBlk[0] = 0;
    for (int i = 1; i < 13; i++) {
        ra.src[nb] = conv_w[i];
        ra.dst[nb] = wt[i];
        ra.p1[nb] = cin_arr[i];
        ra.p2[nb] = 0;
        ra.total[nb] = cout_arr[i] * 9 * cin_arr[i];
        blk += (ra.total[nb] + 255) / 256;
        nb++; ra.startBlk[nb] = blk;
    }
    ra.src[nb] = lin1_w; ra.dst[nb] = wtl1; ra.p1[nb] = 512; ra.p2[nb] = 256;
    ra.total[nb] = 512 * 256; blk += (512 * 256 + 255) / 256;
    nb++; ra.startBlk[nb] = blk;
    ra.src[nb] = lin2_w; ra.dst[nb] = wtl2; ra.p1[nb] = 256; ra.p2[nb] = 128;
    ra.total[nb] = 256 * 128; blk += (256 * 128 + 255) / 256;
    nb++; ra.startBlk[nb] = blk;
    ra.nseg = nb;
    repack_all<<<blk, 256, 0, stream>>>(ra);

    auto zh = [&](u16* buf, int Hp, int C) {
        int total8 = 512 * (4 * Hp - 4) * (C / 8);
        zero_halo<<<(total8 + 255) / 256, 256, 0, stream>>>(buf, Hp, C, total8);
    };
    auto launch_conv = [&](int li, int Hl, int bm, int bn, u16* inb, u16* outb,
                           float* part, int splitN, int outPad, int poolMode) {
        int Cin = cin_arr[li], Cout = cout_arr[li];
        int M = 512 * Hl * Hl;
        int logW = __builtin_ctz(Hl);
        int logHW = 2 * logW;
        size_t pstride = (size_t)M * Cout;
        int grid = (M / bm) * (Cout / bn) * splitN;
        if (bm == 256) {
            conv_gemm<256, 64><<<grid, 256, 0, stream>>>(
                inb, wt[li], conv_b[li], outb, part, pstride,
                Hl, Cin, Cout, logHW, logW, splitN, outPad, poolMode);
        } else if (bn == 128) {
            conv_gemm<128, 128><<<grid, 256, 0, stream>>>(
                inb, wt[li], conv_b[li], outb, part, pstride,
                Hl, Cin, Cout, logHW, logW, splitN, outPad, poolMode);
        } else {
            conv_gemm<128, 64><<<grid, 256, 0, stream>>>(
                inb, wt[li], conv_b[li], outb, part, pstride,
                Hl, Cin, Cout, logHW, logW, splitN, outPad, poolMode);
        }
    };
    auto launch_reduce = [&](int li, int Hl, u16* outb, float* part, int splitN, int outPad) {
        int Cout = cout_arr[li];
        int M = 512 * Hl * Hl;
        int logW = __builtin_ctz(Hl);
        size_t pstride = (size_t)M * Cout;
        int MN = M * Cout;
        reduce_split<<<(MN / 4 + 255) / 256, 256, 0, stream>>>(
            part, conv_b[li], outb, MN, Cout, __builtin_ctz(Cout),
            splitN, pstride, Hl, 2 * logW, logW, outPad);
    };
    auto launch_reduce_pool = [&](int li, int Hl, u16* outb, float* part, int splitN, int outPad) {
        int Cout = cout_arr[li];
        int M = 512 * Hl * Hl;
        size_t pstride = (size_t)M * Cout;
        int total4 = 512 * (Hl / 2) * (Hl / 2) * Cout / 4;
        reduce_pool<<<(total4 + 255) / 256, 256, 0, stream>>>(
            part, conv_b[li], outb, total4, Cout, splitN, pstride, Hl, outPad);
    };

    zh(R0, 34, 64);
    conv0_kernel<<<512 * 8, 256, 0, stream>>>(x, conv_w[0], conv_b[0], R0);

    zh(R1, 18, 64);
    launch_conv(1, 32, 256, 64, R0, R1, nullptr, 1, 0, 1);   // L1 + pool (BM=256)
    zh(R0, 18, 128);
    launch_conv(2, 16, 128, 128, R1, R0, nullptr, 1, 1, 0);  // L2
    zh(R1, 10, 128);
    launch_conv(3, 16, 128, 128, R0, R1, nullptr, 1, 0, 1);  // L3 + pool
    zh(R0, 10, 256);
    launch_conv(4, 8, 128, 128, R1, R0, nullptr, 1, 1, 0);   // L4
    zh(R1, 10, 256);
    launch_conv(5, 8, 128, 128, R0, R1, nullptr, 1, 1, 0);   // L5
    zh(R0, 6, 256);
    launch_conv(6, 8, 128, 128, R1, R0, nullptr, 1, 0, 1);   // L6 + pool
    zh(R1, 6, 512);
    launch_conv(7, 4, 128, 128, R0, R1, PB, 2, 1, 0);        // L7 split2
    launch_reduce(7, 4, R1, PB, 2, 1);
    zh(R0, 6, 512);
    launch_conv(8, 4, 128, 128, R1, R0, PA, 2, 1, 0);        // L8 split2
    launch_reduce(8, 4, R0, PA, 2, 1);
    zh(R1, 4, 512);
    launch_conv(9, 4, 128, 128, R0, R1, PB, 2, 0, 0);        // L9 split2
    launch_reduce_pool(9, 4, R1, PB, 2, 1);
    zh(R0, 4, 512);
    launch_conv(10, 2, 128, 64, R1, R0, PA, 4, 1, 0);        // L10 split4
    launch_reduce(10, 2, R0, PA, 4, 1);
    zh(R1, 4, 512);
    launch_conv(11, 2, 128, 64, R0, R1, PB, 4, 1, 0);        // L11 split4
    launch_reduce(11, 2, R1, PB, 4, 1);
    launch_conv(12, 2, 128, 64, R1, R0, PA, 4, 0, 0);        // L12 split4
    launch_reduce_pool(12, 2, R0, PA, 4, 0);                 // feat = R0 [512,512]

    u16* feat = R0;
    gemm64<true, true><<<(512 / 64) * (256 / 64), 256, 0, stream>>>(
        feat, wtl1, lin1_b, hbuf, 512, 256, 512);
    gemm64<false, false><<<(512 / 64) * (128 / 64), 256, 0, stream>>>(
        hbuf, wtl2, lin2_b, lowbuf, 512, 128, 256);
    graph_tile<<<64, 256, 0, stream>>>(lowbuf, target, out + 5120, out + 5120 + 262144);
    cls_kernel<<<128, 256, 0, stream>>>(feat, cls_w, cls_b, out);
}